// Round 1
// baseline (5106.319 us; speedup 1.0000x reference)
//
#include <hip/hip_runtime.h>

#define NLEFT  100000
#define NRIGHT 100000
#define NTOT   200000
#define NEDGE  1000000
#define HD     64
#define BNEPS  1e-5f

// ---------------- helpers ----------------

__device__ inline void atomicMaxF(float* a, float v) {
  // works for any sign; storage initialized to -inf (0xff800000)
  if (v >= 0.f) atomicMax((int*)a, __float_as_int(v));
  else          atomicMin((unsigned int*)a, __float_as_uint(v));
}

// ---------------- init: d_out = xs, zero stats, zero counts ----------------

__global__ __launch_bounds__(256) void init_kernel(const float* __restrict__ xs,
                                                   float* __restrict__ out,
                                                   float* __restrict__ st, int nst,
                                                   int* __restrict__ cl, int* __restrict__ cr) {
  size_t total = (size_t)NTOT * HD;
  for (size_t i = (size_t)blockIdx.x * blockDim.x + threadIdx.x; i < total;
       i += (size_t)gridDim.x * blockDim.x) {
    out[i] = xs[i];
    if (i < (size_t)nst)    st[i] = 0.f;
    if (i < (size_t)NLEFT)  cl[i] = 0;
    if (i < (size_t)NRIGHT) cr[i] = 0;
  }
}

__global__ __launch_bounds__(256) void count_kernel(const int* __restrict__ src,
                                                    const int* __restrict__ dst,
                                                    int* __restrict__ cl, int* __restrict__ cr) {
  for (int e = blockIdx.x * blockDim.x + threadIdx.x; e < NEDGE;
       e += gridDim.x * blockDim.x) {
    atomicAdd(&cl[src[e]], 1);
    atomicAdd(&cr[dst[e]], 1);
  }
}

// ---------------- gscatter: init / scatter / finalize ----------------

__global__ __launch_bounds__(256) void ginit_kernel(float* __restrict__ info, int nseg) {
  size_t total = (size_t)nseg * 192;
  float ninf = __int_as_float(0xff800000);
  for (size_t i = (size_t)blockIdx.x * blockDim.x + threadIdx.x; i < total;
       i += (size_t)gridDim.x * blockDim.x) {
    int c = (int)(i % 192);
    info[i] = (c < 128) ? 0.f : ninf;
  }
}

// one wave per edge; lane = column
__global__ __launch_bounds__(256) void gscatter_kernel(const float* __restrict__ mat,
                                                       const int* __restrict__ gidx,
                                                       const int* __restrict__ sidx,
                                                       float* __restrict__ info) {
  int lane = threadIdx.x & 63;
  int w  = blockIdx.x * (blockDim.x >> 6) + (threadIdx.x >> 6);
  int nw = gridDim.x * (blockDim.x >> 6);
  for (int e = w; e < NEDGE; e += nw) {
    int g = gidx[e];
    int s = sidx[e];
    float v = mat[(size_t)g * HD + lane];
    atomicAdd(&info[(size_t)s * 192 + lane], v);
    atomicMaxF(&info[(size_t)s * 192 + 128 + lane], v);
  }
}

__global__ __launch_bounds__(256) void gfin_kernel(float* __restrict__ info,
                                                   const int* __restrict__ cnt, int nseg) {
  size_t total = (size_t)nseg * HD;
  for (size_t i = (size_t)blockIdx.x * blockDim.x + threadIdx.x; i < total;
       i += (size_t)gridDim.x * blockDim.x) {
    int n = (int)(i >> 6);
    int c = (int)(i & 63);
    int ct = cnt[n];
    float inv = 1.f / fmaxf((float)ct, 1.f);
    size_t base = (size_t)n * 192;
    info[base + 64 + c] = info[base + c] * inv;
    if (ct == 0) info[base + 128 + c] = 0.f;
  }
}

// ---------------- generic matmul  Y[M,N] = X[M,K] @ W[K,N] + B ----------------
// weights + row tile staged in LDS; 4 cols/thread via float4 LDS reads.
// In-place (Y==X) is safe: each block stages its rows before writing them.

template <int K, int N>
__global__ __launch_bounds__(256) void mm_kernel(const float* __restrict__ X,
                                                 const float* __restrict__ W,
                                                 const float* __restrict__ Bv,
                                                 float* __restrict__ Y, int M) {
  constexpr int NPT = 4;
  constexpr int TPR = N / NPT;       // threads per row
  constexpr int RPB = 256 / TPR;     // rows per block tile
  constexpr int LDK = K + 4;         // pad to dodge bank conflicts
  __shared__ float wl[K * N];
  __shared__ float bl[N];
  __shared__ float xl[RPB * LDK];
  for (int i = threadIdx.x; i < K * N; i += 256) wl[i] = W[i];
  for (int i = threadIdx.x; i < N; i += 256)     bl[i] = Bv[i];
  int tiles = (M + RPB - 1) / RPB;
  for (int t = blockIdx.x; t < tiles; t += gridDim.x) {
    int r0 = t * RPB;
    __syncthreads();
    for (int i = threadIdx.x; i < RPB * K; i += 256) {
      int r = i / K, c = i - r * K;
      int row = r0 + r;
      xl[r * LDK + c] = (row < M) ? X[(size_t)row * K + c] : 0.f;
    }
    __syncthreads();
    int lr  = threadIdx.x / TPR;
    int cg  = (threadIdx.x % TPR) * NPT;
    int row = r0 + lr;
    float a0 = bl[cg], a1 = bl[cg + 1], a2 = bl[cg + 2], a3 = bl[cg + 3];
#pragma unroll 16
    for (int k = 0; k < K; k++) {
      float xv = xl[lr * LDK + k];
      float4 wv = *reinterpret_cast<const float4*>(&wl[k * N + cg]);
      a0 += xv * wv.x; a1 += xv * wv.y; a2 += xv * wv.z; a3 += xv * wv.w;
    }
    if (row < M) {
      float4 o = make_float4(a0, a1, a2, a3);
      *reinterpret_cast<float4*>(&Y[(size_t)row * N + cg]) = o;
    }
  }
}

// ---------------- out-mlp first matmul with virtual concat h (K=128,N=64) ----------------

__global__ __launch_bounds__(256) void mmh_kernel(const float* __restrict__ x32,
                                                  const float* __restrict__ ri,
                                                  const float* __restrict__ li,
                                                  const float* __restrict__ rli,
                                                  const float* __restrict__ W,
                                                  const float* __restrict__ Bv,
                                                  float* __restrict__ Y) {
  constexpr int K = 128, N = 64, NPT = 4, TPR = 16, RPB = 16, LDK = K + 4;
  __shared__ float wl[K * N];
  __shared__ float bl[N];
  __shared__ float xl[RPB * LDK];
  for (int i = threadIdx.x; i < K * N; i += 256) wl[i] = W[i];
  for (int i = threadIdx.x; i < N; i += 256)     bl[i] = Bv[i];
  const int M = NTOT;
  int tiles = (M + RPB - 1) / RPB;
  for (int t = blockIdx.x; t < tiles; t += gridDim.x) {
    int r0 = t * RPB;
    __syncthreads();
    for (int i = threadIdx.x; i < RPB * K; i += 256) {
      int r = i / K, c = i - r * K;
      int row = r0 + r;
      float v = 0.f;
      if (row < M) {
        int cb = c >> 5, cc = c & 31;
        if (row < NLEFT) {
          // [x | ri | x | x]
          v = (cb == 1) ? ri[(size_t)row * 32 + cc] : x32[(size_t)row * 32 + cc];
        } else {
          int rr = row - NLEFT;
          if (cb <= 1)      v = x32[(size_t)row * 32 + cc];   // [x | x(right) | li | rli]
          else if (cb == 2) v = li[(size_t)rr * 32 + cc];
          else              v = rli[(size_t)rr * 32 + cc];
        }
      }
      xl[r * LDK + c] = v;
    }
    __syncthreads();
    int lr  = threadIdx.x / TPR;
    int cg  = (threadIdx.x % TPR) * NPT;
    int row = r0 + lr;
    float a0 = bl[cg], a1 = bl[cg + 1], a2 = bl[cg + 2], a3 = bl[cg + 3];
#pragma unroll 16
    for (int k = 0; k < K; k++) {
      float xv = xl[lr * LDK + k];
      float4 wv = *reinterpret_cast<const float4*>(&wl[k * N + cg]);
      a0 += xv * wv.x; a1 += xv * wv.y; a2 += xv * wv.z; a3 += xv * wv.w;
    }
    if (row < M) {
      float4 o = make_float4(a0, a1, a2, a3);
      *reinterpret_cast<float4*>(&Y[(size_t)row * N + cg]) = o;
    }
  }
}

// ---------------- batchnorm: stats (sum, sumsq) + normalize(+relu)(+residual add) ----------------

template <int C>
__global__ __launch_bounds__(256) void stats_kernel(const float* __restrict__ X, int M,
                                                    float* __restrict__ st) {
  constexpr int RPI = 256 / C;
  int col = threadIdx.x & (C - 1);
  float s = 0.f, s2 = 0.f;
  for (int row = blockIdx.x * RPI + threadIdx.x / C; row < M; row += gridDim.x * RPI) {
    float v = X[(size_t)row * C + col];
    s += v; s2 += v * v;
  }
  __shared__ float r1[256], r2[256];
  r1[threadIdx.x] = s; r2[threadIdx.x] = s2;
  __syncthreads();
  if (threadIdx.x < C) {
    float ts = 0.f, ts2 = 0.f;
#pragma unroll
    for (int i = 0; i < RPI; i++) { ts += r1[col + i * C]; ts2 += r2[col + i * C]; }
    atomicAdd(&st[col], ts);
    atomicAdd(&st[C + col], ts2);
  }
}

template <int C, bool ADD>
__global__ __launch_bounds__(256) void norm_kernel(float* __restrict__ X, int M,
                                                   const float* __restrict__ st,
                                                   float* __restrict__ D) {
  __shared__ float mean[C], scal[C];
  if (threadIdx.x < C) {
    float m = st[threadIdx.x] / (float)M;
    float v = st[C + threadIdx.x] / (float)M - m * m;
    mean[threadIdx.x] = m;
    scal[threadIdx.x] = rsqrtf(fmaxf(v, 0.f) + BNEPS);
  }
  __syncthreads();
  size_t total = (size_t)M * C;
  for (size_t i = (size_t)blockIdx.x * 256 + threadIdx.x; i < total;
       i += (size_t)gridDim.x * 256) {
    int c = (int)(i & (C - 1));
    float y = (X[i] - mean[c]) * scal[c];
    y = y > 0.f ? y : 0.f;
    if (ADD) D[i] += y; else X[i] = y;
  }
}

// ---------------- orchestration ----------------

static inline int tiles_of(int M, int RPB) { return (M + RPB - 1) / RPB; }

extern "C" void kernel_launch(void* const* d_in, const int* in_sizes, int n_in,
                              void* d_out, int out_size, void* d_ws, size_t ws_size,
                              hipStream_t stream) {
  const float* xs      = (const float*)d_in[0];
  const float* nn1_w1  = (const float*)d_in[1];
  const float* nn1_b1  = (const float*)d_in[2];
  const float* nn1_w2  = (const float*)d_in[3];
  const float* nn1_b2  = (const float*)d_in[4];
  const float* nn2_w1  = (const float*)d_in[5];
  const float* nn2_b1  = (const float*)d_in[6];
  const float* nn2_w2  = (const float*)d_in[7];
  const float* nn2_b2  = (const float*)d_in[8];
  const float* l1_w    = (const float*)d_in[9];
  const float* l1_b    = (const float*)d_in[10];
  const float* l2_w    = (const float*)d_in[11];
  const float* l2_b    = (const float*)d_in[12];
  const float* l3_w    = (const float*)d_in[13];
  const float* l3_b    = (const float*)d_in[14];
  const float* l4_w    = (const float*)d_in[15];
  const float* l4_b    = (const float*)d_in[16];
  const float* out_w1  = (const float*)d_in[17];
  const float* out_b1  = (const float*)d_in[18];
  const float* out_w2  = (const float*)d_in[19];
  const float* out_b2  = (const float*)d_in[20];
  const int*   src     = (const int*)d_in[21];
  const int*   dst     = (const int*)d_in[22];

  float* out = (float*)d_out;

  // workspace carve (floats)
  float* ws    = (float*)d_ws;
  float* info  = ws;                                    // 100000*192 = 19.2M
  float* t1    = info  + (size_t)NLEFT * 192;           // 200000*64  = 12.8M
  float* rin   = t1    + (size_t)NTOT * 64;             // 100000*64  = 6.4M
  float* x32   = rin   + (size_t)NLEFT * 64;            // 200000*32  = 6.4M
  float* ri32  = x32   + (size_t)NTOT * 32;             // 100000*32
  float* li32  = ri32  + (size_t)NLEFT * 32;            // 100000*32
  float* rli32 = li32  + (size_t)NRIGHT * 32;           // 100000*32
  float* stats = rli32 + (size_t)NRIGHT * 32;           // 20*128
  int*   cntL  = (int*)(stats + 20 * 128);              // 100000
  int*   cntR  = cntL + NLEFT;                          // 100000

  dim3 B(256);

  init_kernel<<<2048, B, 0, stream>>>(xs, out, stats, 20 * 128, cntL, cntR);
  count_kernel<<<2048, B, 0, stream>>>(src, dst, cntL, cntR);

  int slot = 0;
  auto ST = [&](int s) { return stats + (size_t)s * 128; };

  auto bn64 = [&](float* buf, int M) {
    stats_kernel<64><<<1024, B, 0, stream>>>(buf, M, ST(slot));
    norm_kernel<64, false><<<2048, B, 0, stream>>>(buf, M, ST(slot), nullptr);
    slot++;
  };
  auto bn32 = [&](float* buf, int M) {
    stats_kernel<32><<<1024, B, 0, stream>>>(buf, M, ST(slot));
    norm_kernel<32, false><<<2048, B, 0, stream>>>(buf, M, ST(slot), nullptr);
    slot++;
  };

  for (int l = 0; l < 2; l++) {
    const float* p_nn1_w1 = nn1_w1 + (size_t)l * 64 * 64;
    const float* p_nn1_b1 = nn1_b1 + (size_t)l * 64;
    const float* p_nn1_w2 = nn1_w2 + (size_t)l * 64 * 64;
    const float* p_nn1_b2 = nn1_b2 + (size_t)l * 64;
    const float* p_nn2_w1 = nn2_w1 + (size_t)l * 192 * 64;
    const float* p_nn2_b1 = nn2_b1 + (size_t)l * 64;
    const float* p_nn2_w2 = nn2_w2 + (size_t)l * 64 * 64;
    const float* p_nn2_b2 = nn2_b2 + (size_t)l * 64;
    const float* p_l1_w   = l1_w   + (size_t)l * 64 * 32;
    const float* p_l1_b   = l1_b   + (size_t)l * 32;
    const float* p_l2_w   = l2_w   + (size_t)l * 192 * 32;
    const float* p_l2_b   = l2_b   + (size_t)l * 32;
    const float* p_l3_w   = l3_w   + (size_t)l * 192 * 32;
    const float* p_l3_b   = l3_b   + (size_t)l * 32;
    const float* p_l4_w   = l4_w   + (size_t)l * 192 * 32;
    const float* p_l4_b   = l4_b   + (size_t)l * 32;
    const float* p_out_w1 = out_w1 + (size_t)l * 128 * 64;
    const float* p_out_b1 = out_b1 + (size_t)l * 64;
    const float* p_out_w2 = out_w2 + (size_t)l * 64 * 64;
    const float* p_out_b2 = out_b2 + (size_t)l * 64;

    // a) right_info = gscatter(xs_right[dst], src, NLEFT)
    ginit_kernel<<<2048, B, 0, stream>>>(info, NLEFT);
    gscatter_kernel<<<4096, B, 0, stream>>>(out + (size_t)NLEFT * 64, dst, src, info);
    gfin_kernel<<<2048, B, 0, stream>>>(info, cntL, NLEFT);

    // b) ri = lin_bn_relu(right_info, l2)
    mm_kernel<192, 32><<<tiles_of(NLEFT, 32), B, 0, stream>>>(info, p_l2_w, p_l2_b, ri32, NLEFT);
    bn32(ri32, NLEFT);

    // c) right_info_new = mlp2(right_info, nn2)
    mm_kernel<192, 64><<<tiles_of(NLEFT, 16), B, 0, stream>>>(info, p_nn2_w1, p_nn2_b1, rin, NLEFT);
    bn64(rin, NLEFT);
    mm_kernel<64, 64><<<tiles_of(NLEFT, 16), B, 0, stream>>>(rin, p_nn2_w2, p_nn2_b2, rin, NLEFT);
    bn64(rin, NLEFT);

    // d) rl_info = gscatter(right_info_new[src], dst, NRIGHT)   (reuse info)
    ginit_kernel<<<2048, B, 0, stream>>>(info, NRIGHT);
    gscatter_kernel<<<4096, B, 0, stream>>>(rin, src, dst, info);
    gfin_kernel<<<2048, B, 0, stream>>>(info, cntR, NRIGHT);

    // e) rli = lin_bn_relu(rl_info, l4)
    mm_kernel<192, 32><<<tiles_of(NRIGHT, 32), B, 0, stream>>>(info, p_l4_w, p_l4_b, rli32, NRIGHT);
    bn32(rli32, NRIGHT);

    // f) x_left_new = mlp2(xs, nn1)  (full NTOT rows; BN over all rows)
    mm_kernel<64, 64><<<tiles_of(NTOT, 16), B, 0, stream>>>(out, p_nn1_w1, p_nn1_b1, t1, NTOT);
    bn64(t1, NTOT);
    mm_kernel<64, 64><<<tiles_of(NTOT, 16), B, 0, stream>>>(t1, p_nn1_w2, p_nn1_b2, t1, NTOT);
    bn64(t1, NTOT);

    // g) left_info = gscatter(x_left_new[src], dst, NRIGHT)   (reuse info)
    ginit_kernel<<<2048, B, 0, stream>>>(info, NRIGHT);
    gscatter_kernel<<<4096, B, 0, stream>>>(t1, src, dst, info);
    gfin_kernel<<<2048, B, 0, stream>>>(info, cntR, NRIGHT);

    // h) li = lin_bn_relu(left_info, l3)
    mm_kernel<192, 32><<<tiles_of(NRIGHT, 32), B, 0, stream>>>(info, p_l3_w, p_l3_b, li32, NRIGHT);
    bn32(li32, NRIGHT);

    // i) x = lin_bn_relu(xs, l1)  (NTOT rows)
    mm_kernel<64, 32><<<tiles_of(NTOT, 32), B, 0, stream>>>(out, p_l1_w, p_l1_b, x32, NTOT);
    bn32(x32, NTOT);

    // j) out-mlp on virtual h, then residual add into d_out
    mmh_kernel<<<tiles_of(NTOT, 16), B, 0, stream>>>(x32, ri32, li32, rli32, p_out_w1, p_out_b1, t1);
    bn64(t1, NTOT);
    mm_kernel<64, 64><<<tiles_of(NTOT, 16), B, 0, stream>>>(t1, p_out_w2, p_out_b2, t1, NTOT);
    // final BN + relu + residual add into out
    stats_kernel<64><<<1024, B, 0, stream>>>(t1, NTOT, ST(slot));
    norm_kernel<64, true><<<2048, B, 0, stream>>>(t1, NTOT, ST(slot), out);
    slot++;
  }
}

// Round 2
// 2900.180 us; speedup vs baseline: 1.7607x; 1.7607x over previous
//
#include <hip/hip_runtime.h>

#define NLEFT  100000
#define NRIGHT 100000
#define NTOT   200000
#define NEDGE  1000000
#define HD     64
#define BNEPS  1e-5f

// ---------------- init: d_out = xs, zero stats/cursors ----------------

__global__ __launch_bounds__(256) void init_kernel(const float* __restrict__ xs,
                                                   float* __restrict__ out,
                                                   float* __restrict__ st, int nst,
                                                   int* __restrict__ cl, int* __restrict__ cr,
                                                   int* __restrict__ curl, int* __restrict__ curr) {
  size_t total = (size_t)NTOT * HD;
  for (size_t i = (size_t)blockIdx.x * blockDim.x + threadIdx.x; i < total;
       i += (size_t)gridDim.x * blockDim.x) {
    out[i] = xs[i];
    if (i < (size_t)nst)    st[i] = 0.f;
    if (i < (size_t)NLEFT)  { cl[i] = 0; curl[i] = 0; }
    if (i < (size_t)NRIGHT) { cr[i] = 0; curr[i] = 0; }
  }
}

__global__ __launch_bounds__(256) void count_kernel(const int* __restrict__ src,
                                                    const int* __restrict__ dst,
                                                    int* __restrict__ cl, int* __restrict__ cr) {
  for (int e = blockIdx.x * blockDim.x + threadIdx.x; e < NEDGE;
       e += gridDim.x * blockDim.x) {
    atomicAdd(&cl[src[e]], 1);
    atomicAdd(&cr[dst[e]], 1);
  }
}

// ---------------- exclusive scan (counts -> offsets), 3 kernels ----------------

__global__ __launch_bounds__(256) void scan1_kernel(const int* __restrict__ cnt, int n,
                                                    int* __restrict__ partial) {
  __shared__ int tmp[256];
  int i = blockIdx.x * 256 + threadIdx.x;
  tmp[threadIdx.x] = (i < n) ? cnt[i] : 0;
  __syncthreads();
  for (int s = 128; s > 0; s >>= 1) {
    if (threadIdx.x < s) tmp[threadIdx.x] += tmp[threadIdx.x + s];
    __syncthreads();
  }
  if (threadIdx.x == 0) partial[blockIdx.x] = tmp[0];
}

__global__ __launch_bounds__(1024) void scan2_kernel(int* __restrict__ partial, int nb) {
  __shared__ int tmp[1024];
  int t = threadIdx.x;
  int v = (t < nb) ? partial[t] : 0;
  tmp[t] = v;
  __syncthreads();
  for (int off = 1; off < 1024; off <<= 1) {
    int x = tmp[t];
    int add = (t >= off) ? tmp[t - off] : 0;
    __syncthreads();
    tmp[t] = x + add;
    __syncthreads();
  }
  if (t < nb) partial[t] = tmp[t] - v;  // exclusive
}

__global__ __launch_bounds__(256) void scan3_kernel(const int* __restrict__ cnt, int n,
                                                    const int* __restrict__ partial,
                                                    int* __restrict__ offs) {
  __shared__ int tmp[256];
  int t = threadIdx.x;
  int i = blockIdx.x * 256 + t;
  int v = (i < n) ? cnt[i] : 0;
  tmp[t] = v;
  __syncthreads();
  for (int off = 1; off < 256; off <<= 1) {
    int x = tmp[t];
    int add = (t >= off) ? tmp[t - off] : 0;
    __syncthreads();
    tmp[t] = x + add;
    __syncthreads();
  }
  if (i < n) offs[i] = tmp[t] - v + partial[blockIdx.x];
  if (i == 0) offs[n] = NEDGE;
}

// ---------------- CSR fill: adjL = dst grouped by src, adjR = src grouped by dst ----------------

__global__ __launch_bounds__(256) void fill_kernel(const int* __restrict__ src,
                                                   const int* __restrict__ dst,
                                                   const int* __restrict__ oL,
                                                   const int* __restrict__ oR,
                                                   int* __restrict__ curL, int* __restrict__ curR,
                                                   int* __restrict__ adjL, int* __restrict__ adjR) {
  for (int e = blockIdx.x * blockDim.x + threadIdx.x; e < NEDGE;
       e += gridDim.x * blockDim.x) {
    int s = src[e], d = dst[e];
    int p = atomicAdd(&curL[s], 1);
    adjL[oL[s] + p] = d;
    int q = atomicAdd(&curR[d], 1);
    adjR[oR[d] + q] = s;
  }
}

// ---------------- gscatter via CSR gather: one wave per segment, lane = column ----------------

__global__ __launch_bounds__(256) void gscatter_csr(const float* __restrict__ mat,
                                                    const int* __restrict__ offs,
                                                    const int* __restrict__ adj,
                                                    float* __restrict__ info, int nseg) {
  int lane = threadIdx.x & 63;
  int w  = blockIdx.x * 4 + (threadIdx.x >> 6);
  int nw = gridDim.x * 4;
  for (int seg = w; seg < nseg; seg += nw) {
    int b = offs[seg], e = offs[seg + 1];
    float s = 0.f, mx = -INFINITY;
    for (int j = b; j < e; j++) {
      int g = adj[j];
      float v = mat[(size_t)g * HD + lane];
      s += v;
      mx = fmaxf(mx, v);
    }
    int c = e - b;
    float mean = s / fmaxf((float)c, 1.f);
    if (c == 0) mx = 0.f;
    size_t base = (size_t)seg * 192;
    info[base + lane]       = s;
    info[base + 64 + lane]  = mean;
    info[base + 128 + lane] = mx;
  }
}

// ---------------- matmul Y[M,N] = X[M,K] @ W[K,N] + B, fused BN-stats accumulation ----------------
// weights + row tile in LDS; 4 cols/thread; grid-strided tiles; per-thread register
// stat accumulators reduced once per block at the end. In-place (Y==X) safe.

template <int K, int N>
__global__ __launch_bounds__(256) void mm_kernel(const float* __restrict__ X,
                                                 const float* __restrict__ W,
                                                 const float* __restrict__ Bv,
                                                 float* __restrict__ Y, int M,
                                                 float* __restrict__ st) {
  constexpr int NPT = 4;
  constexpr int TPR = N / NPT;       // threads per row
  constexpr int RPB = 256 / TPR;     // rows per block tile
  constexpr int LDK = K + 4;
  __shared__ float wl[K * N];
  __shared__ float bl[N];
  __shared__ float xl[RPB * LDK];
  for (int i = threadIdx.x; i < K * N; i += 256) wl[i] = W[i];
  for (int i = threadIdx.x; i < N; i += 256)     bl[i] = Bv[i];
  const int lr = threadIdx.x / TPR;
  const int cg = (threadIdx.x % TPR) * NPT;
  float s0 = 0.f, s1 = 0.f, s2 = 0.f, s3 = 0.f;
  float q0 = 0.f, q1 = 0.f, q2 = 0.f, q3 = 0.f;
  int tiles = (M + RPB - 1) / RPB;
  for (int t = blockIdx.x; t < tiles; t += gridDim.x) {
    int r0 = t * RPB;
    __syncthreads();
    for (int i = threadIdx.x; i < RPB * K; i += 256) {
      int r = i / K, c = i - r * K;
      int row = r0 + r;
      xl[r * LDK + c] = (row < M) ? X[(size_t)row * K + c] : 0.f;
    }
    __syncthreads();
    int row = r0 + lr;
    float a0 = bl[cg], a1 = bl[cg + 1], a2 = bl[cg + 2], a3 = bl[cg + 3];
#pragma unroll 16
    for (int k = 0; k < K; k++) {
      float xv = xl[lr * LDK + k];
      float4 wv = *reinterpret_cast<const float4*>(&wl[k * N + cg]);
      a0 += xv * wv.x; a1 += xv * wv.y; a2 += xv * wv.z; a3 += xv * wv.w;
    }
    if (row < M) {
      *reinterpret_cast<float4*>(&Y[(size_t)row * N + cg]) = make_float4(a0, a1, a2, a3);
      s0 += a0; s1 += a1; s2 += a2; s3 += a3;
      q0 += a0 * a0; q1 += a1 * a1; q2 += a2 * a2; q3 += a3 * a3;
    }
  }
  // block reduce stats (reuse xl as [RPB][N])
  __syncthreads();
  xl[lr * N + cg] = s0; xl[lr * N + cg + 1] = s1;
  xl[lr * N + cg + 2] = s2; xl[lr * N + cg + 3] = s3;
  __syncthreads();
  if (threadIdx.x < N) {
    float tot = 0.f;
#pragma unroll
    for (int r = 0; r < RPB; r++) tot += xl[r * N + threadIdx.x];
    atomicAdd(&st[threadIdx.x], tot);
  }
  __syncthreads();
  xl[lr * N + cg] = q0; xl[lr * N + cg + 1] = q1;
  xl[lr * N + cg + 2] = q2; xl[lr * N + cg + 3] = q3;
  __syncthreads();
  if (threadIdx.x < N) {
    float tot = 0.f;
#pragma unroll
    for (int r = 0; r < RPB; r++) tot += xl[r * N + threadIdx.x];
    atomicAdd(&st[N + threadIdx.x], tot);
  }
}

// ---------------- out-mlp first matmul with virtual concat h (K=128,N=64), fused stats ----------------

__global__ __launch_bounds__(256) void mmh_kernel(const float* __restrict__ x32,
                                                  const float* __restrict__ ri,
                                                  const float* __restrict__ li,
                                                  const float* __restrict__ rli,
                                                  const float* __restrict__ W,
                                                  const float* __restrict__ Bv,
                                                  float* __restrict__ Y,
                                                  float* __restrict__ st) {
  constexpr int K = 128, N = 64, NPT = 4, TPR = 16, RPB = 16, LDK = K + 4;
  __shared__ float wl[K * N];
  __shared__ float bl[N];
  __shared__ float xl[RPB * LDK];
  for (int i = threadIdx.x; i < K * N; i += 256) wl[i] = W[i];
  for (int i = threadIdx.x; i < N; i += 256)     bl[i] = Bv[i];
  const int M = NTOT;
  const int lr = threadIdx.x / TPR;
  const int cg = (threadIdx.x % TPR) * NPT;
  float s0 = 0.f, s1 = 0.f, s2 = 0.f, s3 = 0.f;
  float q0 = 0.f, q1 = 0.f, q2 = 0.f, q3 = 0.f;
  int tiles = (M + RPB - 1) / RPB;
  for (int t = blockIdx.x; t < tiles; t += gridDim.x) {
    int r0 = t * RPB;
    __syncthreads();
    for (int i = threadIdx.x; i < RPB * K; i += 256) {
      int r = i / K, c = i - r * K;
      int row = r0 + r;
      float v = 0.f;
      if (row < M) {
        int cb = c >> 5, cc = c & 31;
        if (row < NLEFT) {
          v = (cb == 1) ? ri[(size_t)row * 32 + cc] : x32[(size_t)row * 32 + cc];
        } else {
          int rr = row - NLEFT;
          if (cb <= 1)      v = x32[(size_t)row * 32 + cc];
          else if (cb == 2) v = li[(size_t)rr * 32 + cc];
          else              v = rli[(size_t)rr * 32 + cc];
        }
      }
      xl[r * LDK + c] = v;
    }
    __syncthreads();
    int row = r0 + lr;
    float a0 = bl[cg], a1 = bl[cg + 1], a2 = bl[cg + 2], a3 = bl[cg + 3];
#pragma unroll 16
    for (int k = 0; k < K; k++) {
      float xv = xl[lr * LDK + k];
      float4 wv = *reinterpret_cast<const float4*>(&wl[k * N + cg]);
      a0 += xv * wv.x; a1 += xv * wv.y; a2 += xv * wv.z; a3 += xv * wv.w;
    }
    if (row < M) {
      *reinterpret_cast<float4*>(&Y[(size_t)row * N + cg]) = make_float4(a0, a1, a2, a3);
      s0 += a0; s1 += a1; s2 += a2; s3 += a3;
      q0 += a0 * a0; q1 += a1 * a1; q2 += a2 * a2; q3 += a3 * a3;
    }
  }
  __syncthreads();
  xl[lr * N + cg] = s0; xl[lr * N + cg + 1] = s1;
  xl[lr * N + cg + 2] = s2; xl[lr * N + cg + 3] = s3;
  __syncthreads();
  if (threadIdx.x < N) {
    float tot = 0.f;
#pragma unroll
    for (int r = 0; r < RPB; r++) tot += xl[r * N + threadIdx.x];
    atomicAdd(&st[threadIdx.x], tot);
  }
  __syncthreads();
  xl[lr * N + cg] = q0; xl[lr * N + cg + 1] = q1;
  xl[lr * N + cg + 2] = q2; xl[lr * N + cg + 3] = q3;
  __syncthreads();
  if (threadIdx.x < N) {
    float tot = 0.f;
#pragma unroll
    for (int r = 0; r < RPB; r++) tot += xl[r * N + threadIdx.x];
    atomicAdd(&st[N + threadIdx.x], tot);
  }
}

// ---------------- normalize(+relu)(+residual add) ----------------

template <int C, bool ADD>
__global__ __launch_bounds__(256) void norm_kernel(float* __restrict__ X, int M,
                                                   const float* __restrict__ st,
                                                   float* __restrict__ D) {
  __shared__ float mean[C], scal[C];
  if (threadIdx.x < C) {
    float m = st[threadIdx.x] / (float)M;
    float v = st[C + threadIdx.x] / (float)M - m * m;
    mean[threadIdx.x] = m;
    scal[threadIdx.x] = rsqrtf(fmaxf(v, 0.f) + BNEPS);
  }
  __syncthreads();
  size_t total = (size_t)M * C;
  for (size_t i = (size_t)blockIdx.x * 256 + threadIdx.x; i < total;
       i += (size_t)gridDim.x * 256) {
    int c = (int)(i & (C - 1));
    float y = (X[i] - mean[c]) * scal[c];
    y = y > 0.f ? y : 0.f;
    if (ADD) D[i] += y; else X[i] = y;
  }
}

// ---------------- orchestration ----------------

static inline int imin(int a, int b) { return a < b ? a : b; }
static inline int tiles_of(int M, int RPB) { return (M + RPB - 1) / RPB; }

extern "C" void kernel_launch(void* const* d_in, const int* in_sizes, int n_in,
                              void* d_out, int out_size, void* d_ws, size_t ws_size,
                              hipStream_t stream) {
  const float* xs      = (const float*)d_in[0];
  const float* nn1_w1  = (const float*)d_in[1];
  const float* nn1_b1  = (const float*)d_in[2];
  const float* nn1_w2  = (const float*)d_in[3];
  const float* nn1_b2  = (const float*)d_in[4];
  const float* nn2_w1  = (const float*)d_in[5];
  const float* nn2_b1  = (const float*)d_in[6];
  const float* nn2_w2  = (const float*)d_in[7];
  const float* nn2_b2  = (const float*)d_in[8];
  const float* l1_w    = (const float*)d_in[9];
  const float* l1_b    = (const float*)d_in[10];
  const float* l2_w    = (const float*)d_in[11];
  const float* l2_b    = (const float*)d_in[12];
  const float* l3_w    = (const float*)d_in[13];
  const float* l3_b    = (const float*)d_in[14];
  const float* l4_w    = (const float*)d_in[15];
  const float* l4_b    = (const float*)d_in[16];
  const float* out_w1  = (const float*)d_in[17];
  const float* out_b1  = (const float*)d_in[18];
  const float* out_w2  = (const float*)d_in[19];
  const float* out_b2  = (const float*)d_in[20];
  const int*   src     = (const int*)d_in[21];
  const int*   dst     = (const int*)d_in[22];

  float* out = (float*)d_out;

  // workspace carve
  float* ws    = (float*)d_ws;
  float* info  = ws;                                    // 100000*192
  float* t1    = info  + (size_t)NLEFT * 192;           // 200000*64
  float* rin   = t1    + (size_t)NTOT * 64;             // 100000*64
  float* x32   = rin   + (size_t)NLEFT * 64;            // 200000*32
  float* ri32  = x32   + (size_t)NTOT * 32;             // 100000*32
  float* li32  = ri32  + (size_t)NLEFT * 32;            // 100000*32
  float* rli32 = li32  + (size_t)NRIGHT * 32;           // 100000*32
  float* stats = rli32 + (size_t)NRIGHT * 32;           // 20*128
  int*   cntL  = (int*)(stats + 20 * 128);              // counts / offsets / csr
  int*   cntR  = cntL + NLEFT;
  int*   oL    = cntR + NRIGHT;                         // NLEFT+1
  int*   oR    = oL + (NLEFT + 1);                      // NRIGHT+1
  int*   curL  = oR + (NRIGHT + 1);
  int*   curR  = curL + NLEFT;
  int*   part  = curR + NRIGHT;                         // scan partials (<=512)
  int*   adjL  = part + 1024;                           // NEDGE
  int*   adjR  = adjL + NEDGE;                          // NEDGE

  dim3 B(256);
  const int NB1 = (NLEFT + 255) / 256;  // 391 scan blocks

  init_kernel<<<2048, B, 0, stream>>>(xs, out, stats, 20 * 128, cntL, cntR, curL, curR);
  count_kernel<<<2048, B, 0, stream>>>(src, dst, cntL, cntR);
  // offsets for src-grouped (left segments)
  scan1_kernel<<<NB1, B, 0, stream>>>(cntL, NLEFT, part);
  scan2_kernel<<<1, 1024, 0, stream>>>(part, NB1);
  scan3_kernel<<<NB1, B, 0, stream>>>(cntL, NLEFT, part, oL);
  // offsets for dst-grouped (right segments)
  scan1_kernel<<<NB1, B, 0, stream>>>(cntR, NRIGHT, part);
  scan2_kernel<<<1, 1024, 0, stream>>>(part, NB1);
  scan3_kernel<<<NB1, B, 0, stream>>>(cntR, NRIGHT, part, oR);
  fill_kernel<<<2048, B, 0, stream>>>(src, dst, oL, oR, curL, curR, adjL, adjR);

  int slot = 0;
  auto ST = [&](int s) { return stats + (size_t)s * 128; };

  for (int l = 0; l < 2; l++) {
    const float* p_nn1_w1 = nn1_w1 + (size_t)l * 64 * 64;
    const float* p_nn1_b1 = nn1_b1 + (size_t)l * 64;
    const float* p_nn1_w2 = nn1_w2 + (size_t)l * 64 * 64;
    const float* p_nn1_b2 = nn1_b2 + (size_t)l * 64;
    const float* p_nn2_w1 = nn2_w1 + (size_t)l * 192 * 64;
    const float* p_nn2_b1 = nn2_b1 + (size_t)l * 64;
    const float* p_nn2_w2 = nn2_w2 + (size_t)l * 64 * 64;
    const float* p_nn2_b2 = nn2_b2 + (size_t)l * 64;
    const float* p_l1_w   = l1_w   + (size_t)l * 64 * 32;
    const float* p_l1_b   = l1_b   + (size_t)l * 32;
    const float* p_l2_w   = l2_w   + (size_t)l * 192 * 32;
    const float* p_l2_b   = l2_b   + (size_t)l * 32;
    const float* p_l3_w   = l3_w   + (size_t)l * 192 * 32;
    const float* p_l3_b   = l3_b   + (size_t)l * 32;
    const float* p_l4_w   = l4_w   + (size_t)l * 192 * 32;
    const float* p_l4_b   = l4_b   + (size_t)l * 32;
    const float* p_out_w1 = out_w1 + (size_t)l * 128 * 64;
    const float* p_out_b1 = out_b1 + (size_t)l * 64;
    const float* p_out_w2 = out_w2 + (size_t)l * 64 * 64;
    const float* p_out_b2 = out_b2 + (size_t)l * 64;

    auto bn64 = [&](float* buf, int M) {
      norm_kernel<64, false><<<2048, B, 0, stream>>>(buf, M, ST(slot), nullptr);
      slot++;
    };
    auto bn32 = [&](float* buf, int M) {
      norm_kernel<32, false><<<2048, B, 0, stream>>>(buf, M, ST(slot), nullptr);
      slot++;
    };

    // a) right_info = gscatter(xs_right[dst], src, NLEFT): segments by src, gather dst rows
    gscatter_csr<<<4096, B, 0, stream>>>(out + (size_t)NLEFT * 64, oL, adjL, info, NLEFT);

    // b) ri = lin_bn_relu(right_info, l2)
    mm_kernel<192, 32><<<imin(tiles_of(NLEFT, 32), 2048), B, 0, stream>>>(info, p_l2_w, p_l2_b, ri32, NLEFT, ST(slot));
    bn32(ri32, NLEFT);

    // c) right_info_new = mlp2(right_info, nn2)
    mm_kernel<192, 64><<<imin(tiles_of(NLEFT, 16), 2048), B, 0, stream>>>(info, p_nn2_w1, p_nn2_b1, rin, NLEFT, ST(slot));
    bn64(rin, NLEFT);
    mm_kernel<64, 64><<<imin(tiles_of(NLEFT, 16), 2048), B, 0, stream>>>(rin, p_nn2_w2, p_nn2_b2, rin, NLEFT, ST(slot));
    bn64(rin, NLEFT);

    // d) rl_info = gscatter(right_info_new[src], dst, NRIGHT): segments by dst, gather src rows
    gscatter_csr<<<4096, B, 0, stream>>>(rin, oR, adjR, info, NRIGHT);

    // e) rli = lin_bn_relu(rl_info, l4)
    mm_kernel<192, 32><<<imin(tiles_of(NRIGHT, 32), 2048), B, 0, stream>>>(info, p_l4_w, p_l4_b, rli32, NRIGHT, ST(slot));
    bn32(rli32, NRIGHT);

    // f) x_left_new = mlp2(xs, nn1)
    mm_kernel<64, 64><<<imin(tiles_of(NTOT, 16), 2048), B, 0, stream>>>(out, p_nn1_w1, p_nn1_b1, t1, NTOT, ST(slot));
    bn64(t1, NTOT);
    mm_kernel<64, 64><<<imin(tiles_of(NTOT, 16), 2048), B, 0, stream>>>(t1, p_nn1_w2, p_nn1_b2, t1, NTOT, ST(slot));
    bn64(t1, NTOT);

    // g) left_info = gscatter(x_left_new[src], dst, NRIGHT)
    gscatter_csr<<<4096, B, 0, stream>>>(t1, oR, adjR, info, NRIGHT);

    // h) li = lin_bn_relu(left_info, l3)
    mm_kernel<192, 32><<<imin(tiles_of(NRIGHT, 32), 2048), B, 0, stream>>>(info, p_l3_w, p_l3_b, li32, NRIGHT, ST(slot));
    bn32(li32, NRIGHT);

    // i) x = lin_bn_relu(xs, l1)
    mm_kernel<64, 32><<<imin(tiles_of(NTOT, 32), 2048), B, 0, stream>>>(out, p_l1_w, p_l1_b, x32, NTOT, ST(slot));
    bn32(x32, NTOT);

    // j) out-mlp on virtual h, then residual add into d_out
    mmh_kernel<<<imin(tiles_of(NTOT, 16), 2048), B, 0, stream>>>(x32, ri32, li32, rli32, p_out_w1, p_out_b1, t1, ST(slot));
    bn64(t1, NTOT);
    mm_kernel<64, 64><<<imin(tiles_of(NTOT, 16), 2048), B, 0, stream>>>(t1, p_out_w2, p_out_b2, t1, NTOT, ST(slot));
    norm_kernel<64, true><<<2048, B, 0, stream>>>(t1, NTOT, ST(slot), out);
    slot++;
  }
}

// Round 3
// 2041.095 us; speedup vs baseline: 2.5018x; 1.4209x over previous
//
#include <hip/hip_runtime.h>

#define NLEFT  100000
#define NRIGHT 100000
#define NTOT   200000
#define NEDGE  1000000
#define HD     64
#define BNEPS  1e-5f

typedef __attribute__((ext_vector_type(8))) short bfrag8;
typedef __attribute__((ext_vector_type(4))) float facc4;

__device__ inline unsigned short f2bf(float f) {
  unsigned u = __float_as_uint(f);
  u = u + 0x7fffu + ((u >> 16) & 1u);   // RNE
  return (unsigned short)(u >> 16);
}

// ---------------- init: d_out = xs, zero stats/cursors ----------------

__global__ __launch_bounds__(256) void init_kernel(const float* __restrict__ xs,
                                                   float* __restrict__ out,
                                                   float* __restrict__ st, int nst,
                                                   int* __restrict__ cl, int* __restrict__ cr,
                                                   int* __restrict__ curl, int* __restrict__ curr) {
  size_t total = (size_t)NTOT * HD;
  for (size_t i = (size_t)blockIdx.x * blockDim.x + threadIdx.x; i < total;
       i += (size_t)gridDim.x * blockDim.x) {
    out[i] = xs[i];
    if (i < (size_t)nst)    st[i] = 0.f;
    if (i < (size_t)NLEFT)  { cl[i] = 0; curl[i] = 0; }
    if (i < (size_t)NRIGHT) { cr[i] = 0; curr[i] = 0; }
  }
}

__global__ __launch_bounds__(256) void count_kernel(const int* __restrict__ src,
                                                    const int* __restrict__ dst,
                                                    int* __restrict__ cl, int* __restrict__ cr) {
  for (int e = blockIdx.x * blockDim.x + threadIdx.x; e < NEDGE;
       e += gridDim.x * blockDim.x) {
    atomicAdd(&cl[src[e]], 1);
    atomicAdd(&cr[dst[e]], 1);
  }
}

// ---------------- exclusive scan (counts -> offsets) ----------------

__global__ __launch_bounds__(256) void scan1_kernel(const int* __restrict__ cnt, int n,
                                                    int* __restrict__ partial) {
  __shared__ int tmp[256];
  int i = blockIdx.x * 256 + threadIdx.x;
  tmp[threadIdx.x] = (i < n) ? cnt[i] : 0;
  __syncthreads();
  for (int s = 128; s > 0; s >>= 1) {
    if (threadIdx.x < s) tmp[threadIdx.x] += tmp[threadIdx.x + s];
    __syncthreads();
  }
  if (threadIdx.x == 0) partial[blockIdx.x] = tmp[0];
}

__global__ __launch_bounds__(1024) void scan2_kernel(int* __restrict__ partial, int nb) {
  __shared__ int tmp[1024];
  int t = threadIdx.x;
  int v = (t < nb) ? partial[t] : 0;
  tmp[t] = v;
  __syncthreads();
  for (int off = 1; off < 1024; off <<= 1) {
    int x = tmp[t];
    int add = (t >= off) ? tmp[t - off] : 0;
    __syncthreads();
    tmp[t] = x + add;
    __syncthreads();
  }
  if (t < nb) partial[t] = tmp[t] - v;
}

__global__ __launch_bounds__(256) void scan3_kernel(const int* __restrict__ cnt, int n,
                                                    const int* __restrict__ partial,
                                                    int* __restrict__ offs) {
  __shared__ int tmp[256];
  int t = threadIdx.x;
  int i = blockIdx.x * 256 + t;
  int v = (i < n) ? cnt[i] : 0;
  tmp[t] = v;
  __syncthreads();
  for (int off = 1; off < 256; off <<= 1) {
    int x = tmp[t];
    int add = (t >= off) ? tmp[t - off] : 0;
    __syncthreads();
    tmp[t] = x + add;
    __syncthreads();
  }
  if (i < n) offs[i] = tmp[t] - v + partial[blockIdx.x];
  if (i == 0) offs[n] = NEDGE;
}

// ---------------- CSR fill ----------------

__global__ __launch_bounds__(256) void fill_kernel(const int* __restrict__ src,
                                                   const int* __restrict__ dst,
                                                   const int* __restrict__ oL,
                                                   const int* __restrict__ oR,
                                                   int* __restrict__ curL, int* __restrict__ curR,
                                                   int* __restrict__ adjL, int* __restrict__ adjR) {
  for (int e = blockIdx.x * blockDim.x + threadIdx.x; e < NEDGE;
       e += gridDim.x * blockDim.x) {
    int s = src[e], d = dst[e];
    int p = atomicAdd(&curL[s], 1);
    adjL[oL[s] + p] = d;
    int q = atomicAdd(&curR[d], 1);
    adjR[oR[d] + q] = s;
  }
}

// ---------------- gscatter via CSR gather, optional fused BN+relu on source ----------------

__global__ __launch_bounds__(256) void gscatter_csr(const float* __restrict__ mat,
                                                    const int* __restrict__ offs,
                                                    const int* __restrict__ adj,
                                                    float* __restrict__ info, int nseg,
                                                    const float* __restrict__ st, float inv_m) {
  int lane = threadIdx.x & 63;
  float nm = 0.f, ns = 1.f;
  bool donorm = (st != nullptr);
  if (donorm) {
    float m = st[lane] * inv_m;
    float v = st[64 + lane] * inv_m - m * m;
    nm = m;
    ns = rsqrtf(fmaxf(v, 0.f) + BNEPS);
  }
  int w  = blockIdx.x * 4 + (threadIdx.x >> 6);
  int nw = gridDim.x * 4;
  for (int seg = w; seg < nseg; seg += nw) {
    int b = offs[seg], e = offs[seg + 1];
    float s = 0.f, mx = -INFINITY;
    for (int j = b; j < e; j++) {
      int g = adj[j];
      float v = mat[(size_t)g * HD + lane];
      if (donorm) v = fmaxf((v - nm) * ns, 0.f);
      s += v;
      mx = fmaxf(mx, v);
    }
    int c = e - b;
    float mean = s / fmaxf((float)c, 1.f);
    if (c == 0) mx = 0.f;
    size_t base = (size_t)seg * 192;
    info[base + lane]       = s;
    info[base + 64 + lane]  = mean;
    info[base + 128 + lane] = mx;
  }
}

// ---------------- MFMA matmul: Y[M,N] = (bn_relu?)(X)[M,K] @ W[K,N] + B ----------------
// bf16 operands, fp32 accum; fused BN stats of Y into st_out; optional fused
// input normalization (from st_in sums). W transposed+converted into LDS.

template <int K, int N, int ROWS, bool NIN>
__global__ __launch_bounds__(256) void mm_mfma(const float* __restrict__ X,
                                               const float* __restrict__ W,
                                               const float* __restrict__ Bv,
                                               float* __restrict__ Y, int M,
                                               float* __restrict__ st_out,
                                               const float* __restrict__ st_in, float inv_m) {
  constexpr int LDX = K + 8;            // pad: 16B-aligned rows, bank-spread
  constexpr int RT  = ROWS / 64;        // row-tiles per wave (1 or 2)
  constexpr int CT  = N / 16;           // col-tiles
  __shared__ unsigned short xl[ROWS * LDX];
  __shared__ unsigned short wl[N * LDX];
  __shared__ float bl[N];
  __shared__ float nmean[K], nscal[K];
  __shared__ float ldsS[N], ldsQ[N];

  int tid = threadIdx.x;
  for (int i = tid; i < K * N; i += 256) {
    int k = i / N, n = i - k * N;
    wl[n * LDX + k] = f2bf(W[i]);
  }
  for (int i = tid; i < N; i += 256) bl[i] = Bv[i];
  if (NIN) {
    for (int i = tid; i < K; i += 256) {
      float m = st_in[i] * inv_m;
      float v = st_in[K + i] * inv_m - m * m;
      nmean[i] = m;
      nscal[i] = rsqrtf(fmaxf(v, 0.f) + BNEPS);
    }
  }
  if (tid < N) { ldsS[tid] = 0.f; ldsQ[tid] = 0.f; }

  int lane = tid & 63;
  int wv   = tid >> 6;
  int lr   = lane & 15;
  int lk   = (lane >> 4) * 8;
  int lj4  = (lane >> 4) * 4;
  int rowbase = wv * (RT * 16);

  float sc[CT], sq[CT];
#pragma unroll
  for (int c = 0; c < CT; c++) { sc[c] = 0.f; sq[c] = 0.f; }

  int tiles = (M + ROWS - 1) / ROWS;
  for (int t = blockIdx.x; t < tiles; t += gridDim.x) {
    int r0 = t * ROWS;
    __syncthreads();
    for (int i = tid * 4; i < ROWS * K; i += 1024) {
      int r = i / K, c = i - r * K;
      int row = r0 + r;
      float4 v = make_float4(0.f, 0.f, 0.f, 0.f);
      if (row < M) {
        v = *reinterpret_cast<const float4*>(X + (size_t)row * K + c);
        if (NIN) {
          v.x = fmaxf((v.x - nmean[c])     * nscal[c],     0.f);
          v.y = fmaxf((v.y - nmean[c + 1]) * nscal[c + 1], 0.f);
          v.z = fmaxf((v.z - nmean[c + 2]) * nscal[c + 2], 0.f);
          v.w = fmaxf((v.w - nmean[c + 3]) * nscal[c + 3], 0.f);
        }
      }
      unsigned short* p = &xl[r * LDX + c];
      p[0] = f2bf(v.x); p[1] = f2bf(v.y); p[2] = f2bf(v.z); p[3] = f2bf(v.w);
    }
    __syncthreads();

    facc4 acc[RT][CT];
#pragma unroll
    for (int rt = 0; rt < RT; rt++)
#pragma unroll
      for (int ct = 0; ct < CT; ct++) acc[rt][ct] = (facc4){0.f, 0.f, 0.f, 0.f};

#pragma unroll
    for (int kt = 0; kt < K / 32; kt++) {
      bfrag8 a[RT], b[CT];
#pragma unroll
      for (int rt = 0; rt < RT; rt++)
        a[rt] = *reinterpret_cast<const bfrag8*>(&xl[(rowbase + rt * 16 + lr) * LDX + kt * 32 + lk]);
#pragma unroll
      for (int ct = 0; ct < CT; ct++)
        b[ct] = *reinterpret_cast<const bfrag8*>(&wl[(ct * 16 + lr) * LDX + kt * 32 + lk]);
#pragma unroll
      for (int rt = 0; rt < RT; rt++)
#pragma unroll
        for (int ct = 0; ct < CT; ct++)
          acc[rt][ct] = __builtin_amdgcn_mfma_f32_16x16x32_bf16(a[rt], b[ct], acc[rt][ct], 0, 0, 0);
    }

#pragma unroll
    for (int rt = 0; rt < RT; rt++) {
#pragma unroll
      for (int ct = 0; ct < CT; ct++) {
        int col = ct * 16 + lr;
        float bcol = bl[col];
#pragma unroll
        for (int j = 0; j < 4; j++) {
          int row = r0 + rowbase + rt * 16 + lj4 + j;
          if (row < M) {
            float v = acc[rt][ct][j] + bcol;
            Y[(size_t)row * N + col] = v;
            sc[ct] += v; sq[ct] += v * v;
          }
        }
      }
    }
  }

  __syncthreads();
#pragma unroll
  for (int ct = 0; ct < CT; ct++) {
    atomicAdd(&ldsS[ct * 16 + lr], sc[ct]);
    atomicAdd(&ldsQ[ct * 16 + lr], sq[ct]);
  }
  __syncthreads();
  if (tid < N) {
    atomicAdd(&st_out[tid], ldsS[tid]);
    atomicAdd(&st_out[N + tid], ldsQ[tid]);
  }
}

// ---------------- MFMA matmul on virtual concat h (K=128,N=64), 4 normalized sources ----------------

__global__ __launch_bounds__(256) void mmh_mfma(const float* __restrict__ x32,
                                                const float* __restrict__ ri,
                                                const float* __restrict__ li,
                                                const float* __restrict__ rli,
                                                const float* __restrict__ stx,
                                                const float* __restrict__ stri,
                                                const float* __restrict__ stli,
                                                const float* __restrict__ strli,
                                                const float* __restrict__ W,
                                                const float* __restrict__ Bv,
                                                float* __restrict__ Y,
                                                float* __restrict__ st_out) {
  constexpr int K = 128, N = 64, ROWS = 128, LDX = K + 8, RT = 2, CT = 4;
  __shared__ unsigned short xl[ROWS * LDX];
  __shared__ unsigned short wl[N * LDX];
  __shared__ float bl[N];
  __shared__ float m4[4 * 32], s4[4 * 32];
  __shared__ float ldsS[N], ldsQ[N];

  int tid = threadIdx.x;
  for (int i = tid; i < K * N; i += 256) {
    int k = i / N, n = i - k * N;
    wl[n * LDX + k] = f2bf(W[i]);
  }
  for (int i = tid; i < N; i += 256) bl[i] = Bv[i];
  if (tid < 128) {
    int s = tid >> 5, c = tid & 31;
    const float* st = (s == 0) ? stx : (s == 1) ? stri : (s == 2) ? stli : strli;
    float inv = (s == 0) ? (1.f / NTOT) : (s == 1) ? (1.f / NLEFT) : (1.f / NRIGHT);
    float m = st[c] * inv;
    float v = st[32 + c] * inv - m * m;
    m4[tid] = m;
    s4[tid] = rsqrtf(fmaxf(v, 0.f) + BNEPS);
  }
  if (tid < N) { ldsS[tid] = 0.f; ldsQ[tid] = 0.f; }

  int lane = tid & 63;
  int wv   = tid >> 6;
  int lr   = lane & 15;
  int lk   = (lane >> 4) * 8;
  int lj4  = (lane >> 4) * 4;
  int rowbase = wv * 32;

  float sc[CT], sq[CT];
#pragma unroll
  for (int c = 0; c < CT; c++) { sc[c] = 0.f; sq[c] = 0.f; }

  const int M = NTOT;
  int tiles = (M + ROWS - 1) / ROWS;
  for (int t = blockIdx.x; t < tiles; t += gridDim.x) {
    int r0 = t * ROWS;
    __syncthreads();
    for (int i = tid * 4; i < ROWS * K; i += 1024) {
      int r = i / K, c = i - r * K;
      int row = r0 + r;
      float4 v = make_float4(0.f, 0.f, 0.f, 0.f);
      if (row < M) {
        int cb = c >> 5, cc = c & 31;
        const float* srcp;
        int set, srow;
        if (row < NLEFT) {
          if (cb == 1) { srcp = ri; set = 1; srow = row; }
          else         { srcp = x32; set = 0; srow = row; }
        } else {
          int rr = row - NLEFT;
          if (cb <= 1)      { srcp = x32; set = 0; srow = row; }
          else if (cb == 2) { srcp = li;  set = 2; srow = rr; }
          else              { srcp = rli; set = 3; srow = rr; }
        }
        v = *reinterpret_cast<const float4*>(srcp + (size_t)srow * 32 + cc);
        const float* mm_ = &m4[set * 32 + cc];
        const float* ss_ = &s4[set * 32 + cc];
        v.x = fmaxf((v.x - mm_[0]) * ss_[0], 0.f);
        v.y = fmaxf((v.y - mm_[1]) * ss_[1], 0.f);
        v.z = fmaxf((v.z - mm_[2]) * ss_[2], 0.f);
        v.w = fmaxf((v.w - mm_[3]) * ss_[3], 0.f);
      }
      unsigned short* p = &xl[r * LDX + c];
      p[0] = f2bf(v.x); p[1] = f2bf(v.y); p[2] = f2bf(v.z); p[3] = f2bf(v.w);
    }
    __syncthreads();

    facc4 acc[RT][CT];
#pragma unroll
    for (int rt = 0; rt < RT; rt++)
#pragma unroll
      for (int ct = 0; ct < CT; ct++) acc[rt][ct] = (facc4){0.f, 0.f, 0.f, 0.f};

#pragma unroll
    for (int kt = 0; kt < K / 32; kt++) {
      bfrag8 a[RT], b[CT];
#pragma unroll
      for (int rt = 0; rt < RT; rt++)
        a[rt] = *reinterpret_cast<const bfrag8*>(&xl[(rowbase + rt * 16 + lr) * LDX + kt * 32 + lk]);
#pragma unroll
      for (int ct = 0; ct < CT; ct++)
        b[ct] = *reinterpret_cast<const bfrag8*>(&wl[(ct * 16 + lr) * LDX + kt * 32 + lk]);
#pragma unroll
      for (int rt = 0; rt < RT; rt++)
#pragma unroll
        for (int ct = 0; ct < CT; ct++)
          acc[rt][ct] = __builtin_amdgcn_mfma_f32_16x16x32_bf16(a[rt], b[ct], acc[rt][ct], 0, 0, 0);
    }

#pragma unroll
    for (int rt = 0; rt < RT; rt++) {
#pragma unroll
      for (int ct = 0; ct < CT; ct++) {
        int col = ct * 16 + lr;
        float bcol = bl[col];
#pragma unroll
        for (int j = 0; j < 4; j++) {
          int row = r0 + rowbase + rt * 16 + lj4 + j;
          if (row < M) {
            float v = acc[rt][ct][j] + bcol;
            Y[(size_t)row * N + col] = v;
            sc[ct] += v; sq[ct] += v * v;
          }
        }
      }
    }
  }

  __syncthreads();
#pragma unroll
  for (int ct = 0; ct < CT; ct++) {
    atomicAdd(&ldsS[ct * 16 + lr], sc[ct]);
    atomicAdd(&ldsQ[ct * 16 + lr], sq[ct]);
  }
  __syncthreads();
  if (tid < N) {
    atomicAdd(&st_out[tid], ldsS[tid]);
    atomicAdd(&st_out[N + tid], ldsQ[tid]);
  }
}

// ---------------- final normalize + relu + residual add ----------------

template <int C>
__global__ __launch_bounds__(256) void norm_add_kernel(const float* __restrict__ X, int M,
                                                       const float* __restrict__ st,
                                                       float* __restrict__ D) {
  __shared__ float mean[C], scal[C];
  if (threadIdx.x < C) {
    float m = st[threadIdx.x] / (float)M;
    float v = st[C + threadIdx.x] / (float)M - m * m;
    mean[threadIdx.x] = m;
    scal[threadIdx.x] = rsqrtf(fmaxf(v, 0.f) + BNEPS);
  }
  __syncthreads();
  size_t total = (size_t)M * C;
  for (size_t i = (size_t)blockIdx.x * 256 + threadIdx.x; i < total;
       i += (size_t)gridDim.x * 256) {
    int c = (int)(i & (C - 1));
    float y = (X[i] - mean[c]) * scal[c];
    D[i] += y > 0.f ? y : 0.f;
  }
}

// ---------------- orchestration ----------------

static inline int tiles_of(int M, int R) { return (M + R - 1) / R; }

extern "C" void kernel_launch(void* const* d_in, const int* in_sizes, int n_in,
                              void* d_out, int out_size, void* d_ws, size_t ws_size,
                              hipStream_t stream) {
  const float* xs      = (const float*)d_in[0];
  const float* nn1_w1  = (const float*)d_in[1];
  const float* nn1_b1  = (const float*)d_in[2];
  const float* nn1_w2  = (const float*)d_in[3];
  const float* nn1_b2  = (const float*)d_in[4];
  const float* nn2_w1  = (const float*)d_in[5];
  const float* nn2_b1  = (const float*)d_in[6];
  const float* nn2_w2  = (const float*)d_in[7];
  const float* nn2_b2  = (const float*)d_in[8];
  const float* l1_w    = (const float*)d_in[9];
  const float* l1_b    = (const float*)d_in[10];
  const float* l2_w    = (const float*)d_in[11];
  const float* l2_b    = (const float*)d_in[12];
  const float* l3_w    = (const float*)d_in[13];
  const float* l3_b    = (const float*)d_in[14];
  const float* l4_w    = (const float*)d_in[15];
  const float* l4_b    = (const float*)d_in[16];
  const float* out_w1  = (const float*)d_in[17];
  const float* out_b1  = (const float*)d_in[18];
  const float* out_w2  = (const float*)d_in[19];
  const float* out_b2  = (const float*)d_in[20];
  const int*   src     = (const int*)d_in[21];
  const int*   dst     = (const int*)d_in[22];

  float* out = (float*)d_out;

  float* ws    = (float*)d_ws;
  float* info  = ws;
  float* t1    = info  + (size_t)NLEFT * 192;
  float* rin   = t1    + (size_t)NTOT * 64;
  float* x32   = rin   + (size_t)NLEFT * 64;
  float* ri32  = x32   + (size_t)NTOT * 32;
  float* li32  = ri32  + (size_t)NLEFT * 32;
  float* rli32 = li32  + (size_t)NRIGHT * 32;
  float* stats = rli32 + (size_t)NRIGHT * 32;
  int*   cntL  = (int*)(stats + 20 * 128);
  int*   cntR  = cntL + NLEFT;
  int*   oL    = cntR + NRIGHT;
  int*   oR    = oL + (NLEFT + 1);
  int*   curL  = oR + (NRIGHT + 1);
  int*   curR  = curL + NLEFT;
  int*   part  = curR + NRIGHT;
  int*   adjL  = part + 1024;
  int*   adjR  = adjL + NEDGE;

  dim3 B(256);
  const int NB1 = (NLEFT + 255) / 256;
  const float invL = 1.f / NLEFT, invT = 1.f / NTOT;

  init_kernel<<<2048, B, 0, stream>>>(xs, out, stats, 20 * 128, cntL, cntR, curL, curR);
  count_kernel<<<2048, B, 0, stream>>>(src, dst, cntL, cntR);
  scan1_kernel<<<NB1, B, 0, stream>>>(cntL, NLEFT, part);
  scan2_kernel<<<1, 1024, 0, stream>>>(part, NB1);
  scan3_kernel<<<NB1, B, 0, stream>>>(cntL, NLEFT, part, oL);
  scan1_kernel<<<NB1, B, 0, stream>>>(cntR, NRIGHT, part);
  scan2_kernel<<<1, 1024, 0, stream>>>(part, NB1);
  scan3_kernel<<<NB1, B, 0, stream>>>(cntR, NRIGHT, part, oR);
  fill_kernel<<<2048, B, 0, stream>>>(src, dst, oL, oR, curL, curR, adjL, adjR);

  for (int l = 0; l < 2; l++) {
    const float* p_nn1_w1 = nn1_w1 + (size_t)l * 64 * 64;
    const float* p_nn1_b1 = nn1_b1 + (size_t)l * 64;
    const float* p_nn1_w2 = nn1_w2 + (size_t)l * 64 * 64;
    const float* p_nn1_b2 = nn1_b2 + (size_t)l * 64;
    const float* p_nn2_w1 = nn2_w1 + (size_t)l * 192 * 64;
    const float* p_nn2_b1 = nn2_b1 + (size_t)l * 64;
    const float* p_nn2_w2 = nn2_w2 + (size_t)l * 64 * 64;
    const float* p_nn2_b2 = nn2_b2 + (size_t)l * 64;
    const float* p_l1_w   = l1_w   + (size_t)l * 64 * 32;
    const float* p_l1_b   = l1_b   + (size_t)l * 32;
    const float* p_l2_w   = l2_w   + (size_t)l * 192 * 32;
    const float* p_l2_b   = l2_b   + (size_t)l * 32;
    const float* p_l3_w   = l3_w   + (size_t)l * 192 * 32;
    const float* p_l3_b   = l3_b   + (size_t)l * 32;
    const float* p_l4_w   = l4_w   + (size_t)l * 192 * 32;
    const float* p_l4_b   = l4_b   + (size_t)l * 32;
    const float* p_out_w1 = out_w1 + (size_t)l * 128 * 64;
    const float* p_out_b1 = out_b1 + (size_t)l * 64;
    const float* p_out_w2 = out_w2 + (size_t)l * 64 * 64;
    const float* p_out_b2 = out_b2 + (size_t)l * 64;

    float* S = stats + (size_t)l * 10 * 128;
    auto ST = [&](int s) { return S + (size_t)s * 128; };

    // a) right_info = gscatter(out_right[dst], src, NLEFT)
    gscatter_csr<<<4096, B, 0, stream>>>(out + (size_t)NLEFT * 64, oL, adjL, info, NLEFT,
                                         nullptr, 0.f);
    // b) ri = l2(info); stats->s0
    mm_mfma<192, 32, 64, false><<<tiles_of(NLEFT, 64), B, 0, stream>>>(
        info, p_l2_w, p_l2_b, ri32, NLEFT, ST(0), nullptr, 0.f);
    // c) rin = nn2_w1(info); stats->s1 ; rin = nn2_w2(bnrelu(rin,s1)); stats->s2
    mm_mfma<192, 64, 64, false><<<tiles_of(NLEFT, 64), B, 0, stream>>>(
        info, p_nn2_w1, p_nn2_b1, rin, NLEFT, ST(1), nullptr, 0.f);
    mm_mfma<64, 64, 128, true><<<tiles_of(NLEFT, 128), B, 0, stream>>>(
        rin, p_nn2_w2, p_nn2_b2, rin, NLEFT, ST(2), ST(1), invL);
    // d) rl_info = gscatter(bnrelu(rin,s2)[src], dst, NRIGHT)
    gscatter_csr<<<4096, B, 0, stream>>>(rin, oR, adjR, info, NRIGHT, ST(2), invL);
    // e) rli = l4(info); stats->s3
    mm_mfma<192, 32, 64, false><<<tiles_of(NRIGHT, 64), B, 0, stream>>>(
        info, p_l4_w, p_l4_b, rli32, NRIGHT, ST(3), nullptr, 0.f);
    // f) t1 = nn1_w1(out); s4 ; t1 = nn1_w2(bnrelu(t1,s4)); s5
    mm_mfma<64, 64, 128, false><<<tiles_of(NTOT, 128), B, 0, stream>>>(
        out, p_nn1_w1, p_nn1_b1, t1, NTOT, ST(4), nullptr, 0.f);
    mm_mfma<64, 64, 128, true><<<tiles_of(NTOT, 128), B, 0, stream>>>(
        t1, p_nn1_w2, p_nn1_b2, t1, NTOT, ST(5), ST(4), invT);
    // g) left_info = gscatter(bnrelu(t1,s5)[src], dst, NRIGHT)
    gscatter_csr<<<4096, B, 0, stream>>>(t1, oR, adjR, info, NRIGHT, ST(5), invT);
    // h) li = l3(info); s6
    mm_mfma<192, 32, 64, false><<<tiles_of(NRIGHT, 64), B, 0, stream>>>(
        info, p_l3_w, p_l3_b, li32, NRIGHT, ST(6), nullptr, 0.f);
    // i) x32 = l1(out); s7
    mm_mfma<64, 32, 128, false><<<tiles_of(NTOT, 128), B, 0, stream>>>(
        out, p_l1_w, p_l1_b, x32, NTOT, ST(7), nullptr, 0.f);
    // j) t1 = out_w1(h); s8 ; t1 = out_w2(bnrelu(t1,s8)); s9 ; out += relu(bn(t1,s9))
    mmh_mfma<<<tiles_of(NTOT, 128), B, 0, stream>>>(
        x32, ri32, li32, rli32, ST(7), ST(0), ST(6), ST(3),
        p_out_w1, p_out_b1, t1, ST(8));
    mm_mfma<64, 64, 128, true><<<tiles_of(NTOT, 128), B, 0, stream>>>(
        t1, p_out_w2, p_out_b2, t1, NTOT, ST(9), ST(8), invT);
    norm_add_kernel<64><<<2048, B, 0, stream>>>(t1, NTOT, ST(9), out);
  }
}

// Round 5
// 1673.303 us; speedup vs baseline: 3.0516x; 1.2198x over previous
//
#include <hip/hip_runtime.h>

#define NLEFT  100000
#define NRIGHT 100000
#define NTOT   200000
#define NEDGE  1000000
#define HD     64
#define BNEPS  1e-5f

typedef __attribute__((ext_vector_type(8))) short bfrag8;
typedef __attribute__((ext_vector_type(4))) float facc4;

__device__ inline unsigned short f2bf(float f) {
  unsigned u = __float_as_uint(f);
  u = u + 0x7fffu + ((u >> 16) & 1u);   // RNE
  return (unsigned short)(u >> 16);
}
__device__ inline float bf2f(unsigned short u) {
  return __uint_as_float((unsigned)u << 16);
}

// ---------------- init: d_out = xs (+bf16 mirror), zero stats/cursors ----------------

__global__ __launch_bounds__(256) void init_kernel(const float* __restrict__ xs,
                                                   float* __restrict__ out,
                                                   unsigned short* __restrict__ outbf,
                                                   float* __restrict__ st, int nst,
                                                   int* __restrict__ cl, int* __restrict__ cr,
                                                   int* __restrict__ curl, int* __restrict__ curr) {
  size_t ng = (size_t)NTOT * HD / 4;
  for (size_t i = (size_t)blockIdx.x * blockDim.x + threadIdx.x; i < ng;
       i += (size_t)gridDim.x * blockDim.x) {
    float4 v = reinterpret_cast<const float4*>(xs)[i];
    reinterpret_cast<float4*>(out)[i] = v;
    ushort4 p;
    p.x = f2bf(v.x); p.y = f2bf(v.y); p.z = f2bf(v.z); p.w = f2bf(v.w);
    reinterpret_cast<ushort4*>(outbf)[i] = p;
  }
  for (int i = blockIdx.x * blockDim.x + threadIdx.x; i < NLEFT;
       i += gridDim.x * blockDim.x) {
    cl[i] = 0; curl[i] = 0; cr[i] = 0; curr[i] = 0;
    if (i < nst) st[i] = 0.f;
  }
}

__global__ __launch_bounds__(256) void count_kernel(const int* __restrict__ src,
                                                    const int* __restrict__ dst,
                                                    int* __restrict__ cl, int* __restrict__ cr) {
  for (int e = blockIdx.x * blockDim.x + threadIdx.x; e < NEDGE;
       e += gridDim.x * blockDim.x) {
    atomicAdd(&cl[src[e]], 1);
    atomicAdd(&cr[dst[e]], 1);
  }
}

// ---------------- exclusive scan (counts -> offsets) ----------------

__global__ __launch_bounds__(256) void scan1_kernel(const int* __restrict__ cnt, int n,
                                                    int* __restrict__ partial) {
  __shared__ int tmp[256];
  int i = blockIdx.x * 256 + threadIdx.x;
  tmp[threadIdx.x] = (i < n) ? cnt[i] : 0;
  __syncthreads();
  for (int s = 128; s > 0; s >>= 1) {
    if (threadIdx.x < s) tmp[threadIdx.x] += tmp[threadIdx.x + s];
    __syncthreads();
  }
  if (threadIdx.x == 0) partial[blockIdx.x] = tmp[0];
}

__global__ __launch_bounds__(1024) void scan2_kernel(int* __restrict__ partial, int nb) {
  __shared__ int tmp[1024];
  int t = threadIdx.x;
  int v = (t < nb) ? partial[t] : 0;
  tmp[t] = v;
  __syncthreads();
  for (int off = 1; off < 1024; off <<= 1) {
    int x = tmp[t];
    int add = (t >= off) ? tmp[t - off] : 0;
    __syncthreads();
    tmp[t] = x + add;
    __syncthreads();
  }
  if (t < nb) partial[t] = tmp[t] - v;
}

__global__ __launch_bounds__(256) void scan3_kernel(const int* __restrict__ cnt, int n,
                                                    const int* __restrict__ partial,
                                                    int* __restrict__ offs) {
  __shared__ int tmp[256];
  int t = threadIdx.x;
  int i = blockIdx.x * 256 + t;
  int v = (i < n) ? cnt[i] : 0;
  tmp[t] = v;
  __syncthreads();
  for (int off = 1; off < 256; off <<= 1) {
    int x = tmp[t];
    int add = (t >= off) ? tmp[t - off] : 0;
    __syncthreads();
    tmp[t] = x + add;
    __syncthreads();
  }
  if (i < n) offs[i] = tmp[t] - v + partial[blockIdx.x];
  if (i == 0) offs[n] = NEDGE;
}

// ---------------- CSR fill ----------------

__global__ __launch_bounds__(256) void fill_kernel(const int* __restrict__ src,
                                                   const int* __restrict__ dst,
                                                   const int* __restrict__ oL,
                                                   const int* __restrict__ oR,
                                                   int* __restrict__ curL, int* __restrict__ curR,
                                                   int* __restrict__ adjL, int* __restrict__ adjR) {
  for (int e = blockIdx.x * blockDim.x + threadIdx.x; e < NEDGE;
       e += gridDim.x * blockDim.x) {
    int s = src[e], d = dst[e];
    int p = atomicAdd(&curL[s], 1);
    adjL[oL[s] + p] = d;
    int q = atomicAdd(&curR[d], 1);
    adjR[oR[d] + q] = s;
  }
}

// ---------------- gscatter: CSR gather, bf16 src/dst, 2 neighbors/iter ----------------
// wave splits into two 32-lane halves; each half handles alternate neighbors;
// each lane covers 2 columns (packed bf16x2). Combine halves via shfl_xor(32).

__global__ __launch_bounds__(256) void gscatter_csr(const unsigned short* __restrict__ mat,
                                                    const int* __restrict__ offs,
                                                    const int* __restrict__ adj,
                                                    unsigned short* __restrict__ info, int nseg,
                                                    const float* __restrict__ st, float inv_m) {
  int lane = threadIdx.x & 63;
  int half = lane >> 5;
  int c0   = (lane & 31) * 2;
  float nm0 = 0.f, nm1 = 0.f, ns0 = 1.f, ns1 = 1.f;
  bool donorm = (st != nullptr);
  if (donorm) {
    float m0 = st[c0] * inv_m,      m1 = st[c0 + 1] * inv_m;
    float v0 = st[64 + c0] * inv_m - m0 * m0;
    float v1 = st[64 + c0 + 1] * inv_m - m1 * m1;
    nm0 = m0; nm1 = m1;
    ns0 = rsqrtf(fmaxf(v0, 0.f) + BNEPS);
    ns1 = rsqrtf(fmaxf(v1, 0.f) + BNEPS);
  }
  int w  = blockIdx.x * 4 + (threadIdx.x >> 6);
  int nw = gridDim.x * 4;
  for (int seg = w; seg < nseg; seg += nw) {
    int b = offs[seg], e = offs[seg + 1];
    float s0 = 0.f, s1 = 0.f, m0 = -INFINITY, m1 = -INFINITY;
    for (int j = b + half; j < e; j += 2) {
      int g = adj[j];
      unsigned pk = *reinterpret_cast<const unsigned*>(&mat[(size_t)g * HD + c0]);
      float v0 = __uint_as_float(pk << 16);
      float v1 = __uint_as_float(pk & 0xffff0000u);
      if (donorm) {
        v0 = fmaxf((v0 - nm0) * ns0, 0.f);
        v1 = fmaxf((v1 - nm1) * ns1, 0.f);
      }
      s0 += v0; s1 += v1;
      m0 = fmaxf(m0, v0); m1 = fmaxf(m1, v1);
    }
    s0 += __shfl_xor(s0, 32);
    s1 += __shfl_xor(s1, 32);
    m0 = fmaxf(m0, __shfl_xor(m0, 32));
    m1 = fmaxf(m1, __shfl_xor(m1, 32));
    int c = e - b;
    float inv = 1.f / fmaxf((float)c, 1.f);
    if (c == 0) { m0 = 0.f; m1 = 0.f; }
    size_t base = (size_t)seg * 192;
    if (half == 0) {
      unsigned sp = (unsigned)f2bf(s0) | ((unsigned)f2bf(s1) << 16);
      unsigned mp = (unsigned)f2bf(m0) | ((unsigned)f2bf(m1) << 16);
      *reinterpret_cast<unsigned*>(&info[base + c0])       = sp;
      *reinterpret_cast<unsigned*>(&info[base + 128 + c0]) = mp;
    } else {
      unsigned ap = (unsigned)f2bf(s0 * inv) | ((unsigned)f2bf(s1 * inv) << 16);
      *reinterpret_cast<unsigned*>(&info[base + 64 + c0]) = ap;
    }
  }
}

// ---------------- MFMA matmul: Y[M,N]bf16 = (bn_relu?)(X)[M,K]bf16 @ W[K,N] + B ----------------

template <int K, int N, int ROWS, bool NIN>
__global__ __launch_bounds__(256) void mm_mfma(const unsigned short* __restrict__ X,
                                               const float* __restrict__ W,
                                               const float* __restrict__ Bv,
                                               unsigned short* __restrict__ Y, int M,
                                               float* __restrict__ st_out,
                                               const float* __restrict__ st_in, float inv_m) {
  constexpr int LDX = K + 8;
  constexpr int RT  = ROWS / 64;
  constexpr int CT  = N / 16;
  __shared__ unsigned short xl[ROWS * LDX];
  __shared__ unsigned short wl[N * LDX];
  __shared__ float bl[N];
  __shared__ float nmean[K], nscal[K];
  __shared__ float ldsS[N], ldsQ[N];

  int tid = threadIdx.x;
  for (int i = tid; i < K * N; i += 256) {
    int k = i / N, n = i - k * N;
    wl[n * LDX + k] = f2bf(W[i]);
  }
  for (int i = tid; i < N; i += 256) bl[i] = Bv[i];
  if (NIN) {
    for (int i = tid; i < K; i += 256) {
      float m = st_in[i] * inv_m;
      float v = st_in[K + i] * inv_m - m * m;
      nmean[i] = m;
      nscal[i] = rsqrtf(fmaxf(v, 0.f) + BNEPS);
    }
  }
  if (tid < N) { ldsS[tid] = 0.f; ldsQ[tid] = 0.f; }

  int lane = tid & 63;
  int wv   = tid >> 6;
  int lr   = lane & 15;
  int lk   = (lane >> 4) * 8;
  int lj4  = (lane >> 4) * 4;
  int rowbase = wv * (RT * 16);

  float sc[CT], sq[CT];
#pragma unroll
  for (int c = 0; c < CT; c++) { sc[c] = 0.f; sq[c] = 0.f; }

  int tiles = (M + ROWS - 1) / ROWS;
  for (int t = blockIdx.x; t < tiles; t += gridDim.x) {
    int r0 = t * ROWS;
    __syncthreads();
    for (int i = tid * 8; i < ROWS * K; i += 2048) {
      int r = i / K, c = i - r * K;
      int row = r0 + r;
      bfrag8 v = {0, 0, 0, 0, 0, 0, 0, 0};
      if (row < M) {
        v = *reinterpret_cast<const bfrag8*>(X + (size_t)row * K + c);
        if (NIN) {
#pragma unroll
          for (int j = 0; j < 8; j++) {
            float f = bf2f((unsigned short)v[j]);
            f = fmaxf((f - nmean[c + j]) * nscal[c + j], 0.f);
            v[j] = (short)f2bf(f);
          }
        }
      }
      *reinterpret_cast<bfrag8*>(&xl[r * LDX + c]) = v;
    }
    __syncthreads();

    facc4 acc[RT][CT];
#pragma unroll
    for (int rt = 0; rt < RT; rt++)
#pragma unroll
      for (int ct = 0; ct < CT; ct++) acc[rt][ct] = (facc4){0.f, 0.f, 0.f, 0.f};

#pragma unroll
    for (int kt = 0; kt < K / 32; kt++) {
      bfrag8 a[RT], b[CT];
#pragma unroll
      for (int rt = 0; rt < RT; rt++)
        a[rt] = *reinterpret_cast<const bfrag8*>(&xl[(rowbase + rt * 16 + lr) * LDX + kt * 32 + lk]);
#pragma unroll
      for (int ct = 0; ct < CT; ct++)
        b[ct] = *reinterpret_cast<const bfrag8*>(&wl[(ct * 16 + lr) * LDX + kt * 32 + lk]);
#pragma unroll
      for (int rt = 0; rt < RT; rt++)
#pragma unroll
        for (int ct = 0; ct < CT; ct++)
          acc[rt][ct] = __builtin_amdgcn_mfma_f32_16x16x32_bf16(a[rt], b[ct], acc[rt][ct], 0, 0, 0);
    }

#pragma unroll
    for (int rt = 0; rt < RT; rt++) {
#pragma unroll
      for (int ct = 0; ct < CT; ct++) {
        int col = ct * 16 + lr;
        float bcol = bl[col];
#pragma unroll
        for (int j = 0; j < 4; j++) {
          int row = r0 + rowbase + rt * 16 + lj4 + j;
          if (row < M) {
            float v = acc[rt][ct][j] + bcol;
            Y[(size_t)row * N + col] = f2bf(v);
            sc[ct] += v; sq[ct] += v * v;
          }
        }
      }
    }
  }

  __syncthreads();
#pragma unroll
  for (int ct = 0; ct < CT; ct++) {
    atomicAdd(&ldsS[ct * 16 + lr], sc[ct]);
    atomicAdd(&ldsQ[ct * 16 + lr], sq[ct]);
  }
  __syncthreads();
  if (tid < N) {
    atomicAdd(&st_out[tid], ldsS[tid]);
    atomicAdd(&st_out[N + tid], ldsQ[tid]);
  }
}

// ---------------- MFMA matmul on virtual concat h (K=128,N=64), 4 bf16 sources ----------------

__global__ __launch_bounds__(256) void mmh_mfma(const unsigned short* __restrict__ x32,
                                                const unsigned short* __restrict__ ri,
                                                const unsigned short* __restrict__ li,
                                                const unsigned short* __restrict__ rli,
                                                const float* __restrict__ stx,
                                                const float* __restrict__ stri,
                                                const float* __restrict__ stli,
                                                const float* __restrict__ strli,
                                                const float* __restrict__ W,
                                                const float* __restrict__ Bv,
                                                unsigned short* __restrict__ Y,
                                                float* __restrict__ st_out) {
  constexpr int K = 128, N = 64, ROWS = 128, LDX = K + 8, RT = 2, CT = 4;
  __shared__ unsigned short xl[ROWS * LDX];
  __shared__ unsigned short wl[N * LDX];
  __shared__ float bl[N];
  __shared__ float m4[4 * 32], s4[4 * 32];
  __shared__ float ldsS[N], ldsQ[N];

  int tid = threadIdx.x;
  for (int i = tid; i < K * N; i += 256) {
    int k = i / N, n = i - k * N;
    wl[n * LDX + k] = f2bf(W[i]);
  }
  for (int i = tid; i < N; i += 256) bl[i] = Bv[i];
  if (tid < 128) {
    int s = tid >> 5, c = tid & 31;
    const float* st = (s == 0) ? stx : (s == 1) ? stri : (s == 2) ? stli : strli;
    float inv = (s == 0) ? (1.f / NTOT) : (s == 1) ? (1.f / NLEFT) : (1.f / NRIGHT);
    float m = st[c] * inv;
    float v = st[32 + c] * inv - m * m;
    m4[tid] = m;
    s4[tid] = rsqrtf(fmaxf(v, 0.f) + BNEPS);
  }
  if (tid < N) { ldsS[tid] = 0.f; ldsQ[tid] = 0.f; }

  int lane = tid & 63;
  int wv   = tid >> 6;
  int lr   = lane & 15;
  int lk   = (lane >> 4) * 8;
  int lj4  = (lane >> 4) * 4;
  int rowbase = wv * 32;

  float sc[CT], sq[CT];
#pragma unroll
  for (int c = 0; c < CT; c++) { sc[c] = 0.f; sq[c] = 0.f; }

  const int M = NTOT;
  int tiles = (M + ROWS - 1) / ROWS;
  for (int t = blockIdx.x; t < tiles; t += gridDim.x) {
    int r0 = t * ROWS;
    __syncthreads();
    for (int i = tid * 8; i < ROWS * K; i += 2048) {
      int r = i / K, c = i - r * K;
      int row = r0 + r;
      bfrag8 v = {0, 0, 0, 0, 0, 0, 0, 0};
      if (row < M) {
        int cb = c >> 5, cc = c & 31;
        const unsigned short* srcp;
        int set, srow;
        if (row < NLEFT) {
          if (cb == 1) { srcp = ri;  set = 1; srow = row; }
          else         { srcp = x32; set = 0; srow = row; }
        } else {
          int rr = row - NLEFT;
          if (cb <= 1)      { srcp = x32; set = 0; srow = row; }
          else if (cb == 2) { srcp = li;  set = 2; srow = rr; }
          else              { srcp = rli; set = 3; srow = rr; }
        }
        v = *reinterpret_cast<const bfrag8*>(srcp + (size_t)srow * 32 + cc);
        const float* mm_ = &m4[set * 32 + cc];
        const float* ss_ = &s4[set * 32 + cc];
#pragma unroll
        for (int j = 0; j < 8; j++) {
          float f = bf2f((unsigned short)v[j]);
          f = fmaxf((f - mm_[j]) * ss_[j], 0.f);
          v[j] = (short)f2bf(f);
        }
      }
      *reinterpret_cast<bfrag8*>(&xl[r * LDX + c]) = v;
    }
    __syncthreads();

    facc4 acc[RT][CT];
#pragma unroll
    for (int rt = 0; rt < RT; rt++)
#pragma unroll
      for (int ct = 0; ct < CT; ct++) acc[rt][ct] = (facc4){0.f, 0.f, 0.f, 0.f};

#pragma unroll
    for (int kt = 0; kt < K / 32; kt++) {
      bfrag8 a[RT], b[CT];
#pragma unroll
      for (int rt = 0; rt < RT; rt++)
        a[rt] = *reinterpret_cast<const bfrag8*>(&xl[(rowbase + rt * 16 + lr) * LDX + kt * 32 + lk]);
#pragma unroll
      for (int ct = 0; ct < CT; ct++)
        b[ct] = *reinterpret_cast<const bfrag8*>(&wl[(ct * 16 + lr) * LDX + kt * 32 + lk]);
#pragma unroll
      for (int rt = 0; rt < RT; rt++)
#pragma unroll
        for (int ct = 0; ct < CT; ct++)
          acc[rt][ct] = __builtin_amdgcn_mfma_f32_16x16x32_bf16(a[rt], b[ct], acc[rt][ct], 0, 0, 0);
    }

#pragma unroll
    for (int rt = 0; rt < RT; rt++) {
#pragma unroll
      for (int ct = 0; ct < CT; ct++) {
        int col = ct * 16 + lr;
        float bcol = bl[col];
#pragma unroll
        for (int j = 0; j < 4; j++) {
          int row = r0 + rowbase + rt * 16 + lj4 + j;
          if (row < M) {
            float v = acc[rt][ct][j] + bcol;
            Y[(size_t)row * N + col] = f2bf(v);
            sc[ct] += v; sq[ct] += v * v;
          }
        }
      }
    }
  }

  __syncthreads();
#pragma unroll
  for (int ct = 0; ct < CT; ct++) {
    atomicAdd(&ldsS[ct * 16 + lr], sc[ct]);
    atomicAdd(&ldsQ[ct * 16 + lr], sq[ct]);
  }
  __syncthreads();
  if (tid < N) {
    atomicAdd(&st_out[tid], ldsS[tid]);
    atomicAdd(&st_out[N + tid], ldsQ[tid]);
  }
}

// ---------------- final normalize + relu + residual add (+bf16 mirror refresh) ----------------

__global__ __launch_bounds__(256) void norm_add_kernel(const unsigned short* __restrict__ X, int M,
                                                       const float* __restrict__ st,
                                                       float* __restrict__ D,
                                                       unsigned short* __restrict__ Dbf) {
  __shared__ float mean[64], scal[64];
  if (threadIdx.x < 64) {
    float m = st[threadIdx.x] / (float)M;
    float v = st[64 + threadIdx.x] / (float)M - m * m;
    mean[threadIdx.x] = m;
    scal[threadIdx.x] = rsqrtf(fmaxf(v, 0.f) + BNEPS);
  }
  __syncthreads();
  size_t ngrp = (size_t)M * 64 / 8;
  for (size_t i = (size_t)blockIdx.x * 256 + threadIdx.x; i < ngrp;
       i += (size_t)gridDim.x * 256) {
    size_t base = i * 8;
    int c = (int)(base & 63);
    bfrag8 xv = *reinterpret_cast<const bfrag8*>(&X[base]);
    float4 d0 = *reinterpret_cast<float4*>(&D[base]);
    float4 d1 = *reinterpret_cast<float4*>(&D[base + 4]);
    float o[8];
#pragma unroll
    for (int j = 0; j < 8; j++) {
      float y = (bf2f((unsigned short)xv[j]) - mean[c + j]) * scal[c + j];
      y = y > 0.f ? y : 0.f;
      float dv = (j < 4) ? (&d0.x)[j] : (&d1.x)[j - 4];
      o[j] = dv + y;
    }
    d0 = make_float4(o[0], o[1], o[2], o[3]);
    d1 = make_float4(o[4], o[5], o[6], o[7]);
    *reinterpret_cast<float4*>(&D[base])     = d0;
    *reinterpret_cast<float4*>(&D[base + 4]) = d1;
    bfrag8 pb;
#pragma unroll
    for (int j = 0; j < 8; j++) pb[j] = (short)f2bf(o[j]);
    *reinterpret_cast<bfrag8*>(&Dbf[base]) = pb;
  }
}

// ---------------- orchestration ----------------

static inline int tiles_of(int M, int R) { return (M + R - 1) / R; }

extern "C" void kernel_launch(void* const* d_in, const int* in_sizes, int n_in,
                              void* d_out, int out_size, void* d_ws, size_t ws_size,
                              hipStream_t stream) {
  const float* xs      = (const float*)d_in[0];
  const float* nn1_w1  = (const float*)d_in[1];
  const float* nn1_b1  = (const float*)d_in[2];
  const float* nn1_w2  = (const float*)d_in[3];
  const float* nn1_b2  = (const float*)d_in[4];
  const float* nn2_w1  = (const float*)d_in[5];
  const float* nn2_b1  = (const float*)d_in[6];
  const float* nn2_w2  = (const float*)d_in[7];
  const float* nn2_b2  = (const float*)d_in[8];
  const float* l1_w    = (const float*)d_in[9];
  const float* l1_b    = (const float*)d_in[10];
  const float* l2_w    = (const float*)d_in[11];
  const float* l2_b    = (const float*)d_in[12];
  const float* l3_w    = (const float*)d_in[13];
  const float* l3_b    = (const float*)d_in[14];
  const float* l4_w    = (const float*)d_in[15];
  const float* l4_b    = (const float*)d_in[16];
  const float* out_w1  = (const float*)d_in[17];
  const float* out_b1  = (const float*)d_in[18];
  const float* out_w2  = (const float*)d_in[19];
  const float* out_b2  = (const float*)d_in[20];
  const int*   src     = (const int*)d_in[21];
  const int*   dst     = (const int*)d_in[22];

  float* out = (float*)d_out;

  // workspace carve — bf16 activation buffers first (all 16B-aligned)
  unsigned short* u     = (unsigned short*)d_ws;
  unsigned short* info  = u;                                   // 100000*192
  unsigned short* t1    = info  + (size_t)NLEFT * 192;         // 200000*64
  unsigned short* rin   = t1    + (size_t)NTOT * 64;           // 100000*64
  unsigned short* x32   = rin   + (size_t)NLEFT * 64;          // 200000*32
  unsigned short* ri32  = x32   + (size_t)NTOT * 32;           // 100000*32
  unsigned short* li32  = ri32  + (size_t)NLEFT * 32;
  unsigned short* rli32 = li32  + (size_t)NRIGHT * 32;
  unsigned short* outbf = rli32 + (size_t)NRIGHT * 32;         // 200000*64
  float* stats = (float*)(outbf + (size_t)NTOT * 64);          // 20*128
  int*   cntL  = (int*)(stats + 20 * 128);
  int*   cntR  = cntL + NLEFT;
  int*   oL    = cntR + NRIGHT;
  int*   oR    = oL + (NLEFT + 1);
  int*   curL  = oR + (NRIGHT + 1);
  int*   curR  = curL + NLEFT;
  int*   part  = curR + NRIGHT;
  int*   adjL  = part + 1024;
  int*   adjR  = adjL + NEDGE;

  dim3 B(256);
  const int NB1 = (NLEFT + 255) / 256;
  const float invL = 1.f / NLEFT, invT = 1.f / NTOT;

  init_kernel<<<2048, B, 0, stream>>>(xs, out, outbf, stats, 20 * 128, cntL, cntR, curL, curR);
  count_kernel<<<2048, B, 0, stream>>>(src, dst, cntL, cntR);
  scan1_kernel<<<NB1, B, 0, stream>>>(cntL, NLEFT, part);
  scan2_kernel<<<1, 1024, 0, stream>>>(part, NB1);
  scan3_kernel<<<NB1, B, 0, stream>>>(cntL, NLEFT, part, oL);
  scan1_kernel<<<NB1, B, 0, stream>>>(cntR, NRIGHT, part);
  scan2_kernel<<<1, 1024, 0, stream>>>(part, NB1);
  scan3_kernel<<<NB1, B, 0, stream>>>(cntR, NRIGHT, part, oR);
  fill_kernel<<<2048, B, 0, stream>>>(src, dst, oL, oR, curL, curR, adjL, adjR);

  for (int l = 0; l < 2; l++) {
    const float* p_nn1_w1 = nn1_w1 + (size_t)l * 64 * 64;
    const float* p_nn1_b1 = nn1_b1 + (size_t)l * 64;
    const float* p_nn1_w2 = nn1_w2 + (size_t)l * 64 * 64;
    const float* p_nn1_b2 = nn1_b2 + (size_t)l * 64;
    const float* p_nn2_w1 = nn2_w1 + (size_t)l * 192 * 64;
    const float* p_nn2_b1 = nn2_b1 + (size_t)l * 64;
    const float* p_nn2_w2 = nn2_w2 + (size_t)l * 64 * 64;
    const float* p_nn2_b2 = nn2_b2 + (size_t)l * 64;
    const float* p_l1_w   = l1_w   + (size_t)l * 64 * 32;
    const float* p_l1_b   = l1_b   + (size_t)l * 32;
    const float* p_l2_w   = l2_w   + (size_t)l * 192 * 32;
    const float* p_l2_b   = l2_b   + (size_t)l * 32;
    const float* p_l3_w   = l3_w   + (size_t)l * 192 * 32;
    const float* p_l3_b   = l3_b   + (size_t)l * 32;
    const float* p_l4_w   = l4_w   + (size_t)l * 192 * 32;
    const float* p_l4_b   = l4_b   + (size_t)l * 32;
    const float* p_out_w1 = out_w1 + (size_t)l * 128 * 64;
    const float* p_out_b1 = out_b1 + (size_t)l * 64;
    const float* p_out_w2 = out_w2 + (size_t)l * 64 * 64;
    const float* p_out_b2 = out_b2 + (size_t)l * 64;

    float* S = stats + (size_t)l * 10 * 128;
    auto ST = [&](int s) { return S + (size_t)s * 128; };

    // a) right_info = gscatter(out_right[dst], src, NLEFT)
    gscatter_csr<<<4096, B, 0, stream>>>(outbf + (size_t)NLEFT * 64, oL, adjL, info, NLEFT,
                                         nullptr, 0.f);
    // b) ri = l2(info); stats->s0
    mm_mfma<192, 32, 64, false><<<tiles_of(NLEFT, 64), B, 0, stream>>>(
        info, p_l2_w, p_l2_b, ri32, NLEFT, ST(0), nullptr, 0.f);
    // c) rin = nn2_w1(info); s1 ; rin = nn2_w2(bnrelu(rin,s1)); s2
    mm_mfma<192, 64, 64, false><<<tiles_of(NLEFT, 64), B, 0, stream>>>(
        info, p_nn2_w1, p_nn2_b1, rin, NLEFT, ST(1), nullptr, 0.f);
    mm_mfma<64, 64, 128, true><<<tiles_of(NLEFT, 128), B, 0, stream>>>(
        rin, p_nn2_w2, p_nn2_b2, rin, NLEFT, ST(2), ST(1), invL);
    // d) rl_info = gscatter(bnrelu(rin,s2)[src], dst, NRIGHT)
    gscatter_csr<<<4096, B, 0, stream>>>(rin, oR, adjR, info, NRIGHT, ST(2), invL);
    // e) rli = l4(info); s3
    mm_mfma<192, 32, 64, false><<<tiles_of(NRIGHT, 64), B, 0, stream>>>(
        info, p_l4_w, p_l4_b, rli32, NRIGHT, ST(3), nullptr, 0.f);
    // f) t1 = nn1_w1(out); s4 ; t1 = nn1_w2(bnrelu(t1,s4)); s5
    mm_mfma<64, 64, 128, false><<<tiles_of(NTOT, 128), B, 0, stream>>>(
        outbf, p_nn1_w1, p_nn1_b1, t1, NTOT, ST(4), nullptr, 0.f);
    mm_mfma<64, 64, 128, true><<<tiles_of(NTOT, 128), B, 0, stream>>>(
        t1, p_nn1_w2, p_nn1_b2, t1, NTOT, ST(5), ST(4), invT);
    // g) left_info = gscatter(bnrelu(t1,s5)[src], dst, NRIGHT)
    gscatter_csr<<<4096, B, 0, stream>>>(t1, oR, adjR, info, NRIGHT, ST(5), invT);
    // h) li = l3(info); s6
    mm_mfma<192, 32, 64, false><<<tiles_of(NRIGHT, 64), B, 0, stream>>>(
        info, p_l3_w, p_l3_b, li32, NRIGHT, ST(6), nullptr, 0.f);
    // i) x32 = l1(out); s7
    mm_mfma<64, 32, 128, false><<<tiles_of(NTOT, 128), B, 0, stream>>>(
        outbf, p_l1_w, p_l1_b, x32, NTOT, ST(7), nullptr, 0.f);
    // j) t1 = out_w1(h); s8 ; t1 = out_w2(bnrelu(t1,s8)); s9 ; out += relu(bn(t1,s9))
    mmh_mfma<<<tiles_of(NTOT, 128), B, 0, stream>>>(
        x32, ri32, li32, rli32, ST(7), ST(0), ST(6), ST(3),
        p_out_w1, p_out_b1, t1, ST(8));
    mm_mfma<64, 64, 128, true><<<tiles_of(NTOT, 128), B, 0, stream>>>(
        t1, p_out_w2, p_out_b2, t1, NTOT, ST(9), ST(8), invT);
    norm_add_kernel<<<2048, B, 0, stream>>>(t1, NTOT, ST(9), out, outbf);
  }
}

// Round 6
// 1540.902 us; speedup vs baseline: 3.3138x; 1.0859x over previous
//
#include <hip/hip_runtime.h>

#define NLEFT  100000
#define NRIGHT 100000
#define NTOT   200000
#define NEDGE  1000000
#define HD     64
#define BNEPS  1e-5f

typedef __attribute__((ext_vector_type(8))) short bfrag8;
typedef __attribute__((ext_vector_type(4))) float facc4;

__device__ inline unsigned short f2bf(float f) {
  unsigned u = __float_as_uint(f);
  u = u + 0x7fffu + ((u >> 16) & 1u);   // RNE
  return (unsigned short)(u >> 16);
}
__device__ inline float bf2f(unsigned short u) {
  return __uint_as_float((unsigned)u << 16);
}

// ---------------- init: d_out = xs (+bf16 mirror), zero stats/cursors ----------------

__global__ __launch_bounds__(256) void init_kernel(const float* __restrict__ xs,
                                                   float* __restrict__ out,
                                                   unsigned short* __restrict__ outbf,
                                                   float* __restrict__ st, int nst,
                                                   int* __restrict__ cl, int* __restrict__ cr,
                                                   int* __restrict__ curl, int* __restrict__ curr) {
  size_t ng = (size_t)NTOT * HD / 4;
  for (size_t i = (size_t)blockIdx.x * blockDim.x + threadIdx.x; i < ng;
       i += (size_t)gridDim.x * blockDim.x) {
    float4 v = reinterpret_cast<const float4*>(xs)[i];
    reinterpret_cast<float4*>(out)[i] = v;
    ushort4 p;
    p.x = f2bf(v.x); p.y = f2bf(v.y); p.z = f2bf(v.z); p.w = f2bf(v.w);
    reinterpret_cast<ushort4*>(outbf)[i] = p;
  }
  for (int i = blockIdx.x * blockDim.x + threadIdx.x; i < NLEFT;
       i += gridDim.x * blockDim.x) {
    cl[i] = 0; curl[i] = 0; cr[i] = 0; curr[i] = 0;
    if (i < nst) st[i] = 0.f;
  }
}

__global__ __launch_bounds__(256) void count_kernel(const int* __restrict__ src,
                                                    const int* __restrict__ dst,
                                                    int* __restrict__ cl, int* __restrict__ cr) {
  for (int e = blockIdx.x * blockDim.x + threadIdx.x; e < NEDGE;
       e += gridDim.x * blockDim.x) {
    atomicAdd(&cl[src[e]], 1);
    atomicAdd(&cr[dst[e]], 1);
  }
}

// ---------------- exclusive scan (counts -> offsets) ----------------

__global__ __launch_bounds__(256) void scan1_kernel(const int* __restrict__ cnt, int n,
                                                    int* __restrict__ partial) {
  __shared__ int tmp[256];
  int i = blockIdx.x * 256 + threadIdx.x;
  tmp[threadIdx.x] = (i < n) ? cnt[i] : 0;
  __syncthreads();
  for (int s = 128; s > 0; s >>= 1) {
    if (threadIdx.x < s) tmp[threadIdx.x] += tmp[threadIdx.x + s];
    __syncthreads();
  }
  if (threadIdx.x == 0) partial[blockIdx.x] = tmp[0];
}

__global__ __launch_bounds__(1024) void scan2_kernel(int* __restrict__ partial, int nb) {
  __shared__ int tmp[1024];
  int t = threadIdx.x;
  int v = (t < nb) ? partial[t] : 0;
  tmp[t] = v;
  __syncthreads();
  for (int off = 1; off < 1024; off <<= 1) {
    int x = tmp[t];
    int add = (t >= off) ? tmp[t - off] : 0;
    __syncthreads();
    tmp[t] = x + add;
    __syncthreads();
  }
  if (t < nb) partial[t] = tmp[t] - v;
}

__global__ __launch_bounds__(256) void scan3_kernel(const int* __restrict__ cnt, int n,
                                                    const int* __restrict__ partial,
                                                    int* __restrict__ offs) {
  __shared__ int tmp[256];
  int t = threadIdx.x;
  int i = blockIdx.x * 256 + t;
  int v = (i < n) ? cnt[i] : 0;
  tmp[t] = v;
  __syncthreads();
  for (int off = 1; off < 256; off <<= 1) {
    int x = tmp[t];
    int add = (t >= off) ? tmp[t - off] : 0;
    __syncthreads();
    tmp[t] = x + add;
    __syncthreads();
  }
  if (i < n) offs[i] = tmp[t] - v + partial[blockIdx.x];
  if (i == 0) offs[n] = NEDGE;
}

// ---------------- CSR fill ----------------

__global__ __launch_bounds__(256) void fill_kernel(const int* __restrict__ src,
                                                   const int* __restrict__ dst,
                                                   const int* __restrict__ oL,
                                                   const int* __restrict__ oR,
                                                   int* __restrict__ curL, int* __restrict__ curR,
                                                   int* __restrict__ adjL, int* __restrict__ adjR) {
  for (int e = blockIdx.x * blockDim.x + threadIdx.x; e < NEDGE;
       e += gridDim.x * blockDim.x) {
    int s = src[e], d = dst[e];
    int p = atomicAdd(&curL[s], 1);
    adjL[oL[s] + p] = d;
    int q = atomicAdd(&curR[d], 1);
    adjR[oR[d] + q] = s;
  }
}

// ---------------- fused gather(gscatter) + MFMA ----------------
// Block = 512 threads (8 waves); one 64-segment tile per block.
// Phase 1: each wave gathers 8 segments (sum/mean/max, optional bnrelu on
// source) into LDS X tile [64][192] bf16. Phase 2: MFMA with up to two
// weight sets (N1+N2 cols), dual outputs + fused BN stats.

template <int N1, int N2, bool SRCNORM>
__global__ __launch_bounds__(512) void gmm_mfma(const unsigned short* __restrict__ mat,
                                                const int* __restrict__ offs,
                                                const int* __restrict__ adj,
                                                int nseg,
                                                const float* __restrict__ st_src, float inv_src,
                                                const float* __restrict__ W1,
                                                const float* __restrict__ B1,
                                                unsigned short* __restrict__ Y1,
                                                float* __restrict__ st1,
                                                const float* __restrict__ W2,
                                                const float* __restrict__ B2,
                                                unsigned short* __restrict__ Y2,
                                                float* __restrict__ st2) {
  constexpr int K   = 192;
  constexpr int LDX = 200;
  constexpr int NT  = N1 + N2;
  constexpr int CTT = NT / 16;      // total col-tiles (2 or 6)
  constexpr int CTW = CTT / 2;      // col-tiles per wave (1 or 3)
  __shared__ alignas(16) unsigned short xl[64 * LDX];
  __shared__ alignas(16) unsigned short wl[NT * LDX];
  __shared__ float bl[NT];
  __shared__ float ldsS[NT], ldsQ[NT];

  int tid = threadIdx.x;
  for (int i = tid; i < K * N1; i += 512) {
    int k = i / N1, n = i - k * N1;
    wl[n * LDX + k] = f2bf(W1[i]);
  }
  if constexpr (N2 > 0) {
    for (int i = tid; i < K * N2; i += 512) {
      int k = i / N2, n = i - k * N2;
      wl[(N1 + n) * LDX + k] = f2bf(W2[i]);
    }
  }
  for (int i = tid; i < N1; i += 512) bl[i] = B1[i];
  if constexpr (N2 > 0)
    for (int i = tid; i < N2; i += 512) bl[N1 + i] = B2[i];
  if (tid < NT) { ldsS[tid] = 0.f; ldsQ[tid] = 0.f; }

  int wave = tid >> 6;
  int lane = tid & 63;
  int half = lane >> 5;
  int c0   = (lane & 31) * 2;

  float nm0 = 0.f, nm1 = 0.f, ns0 = 1.f, ns1 = 1.f;
  if (SRCNORM) {
    float m0 = st_src[c0] * inv_src, m1 = st_src[c0 + 1] * inv_src;
    float v0 = st_src[64 + c0] * inv_src - m0 * m0;
    float v1 = st_src[64 + c0 + 1] * inv_src - m1 * m1;
    nm0 = m0; nm1 = m1;
    ns0 = rsqrtf(fmaxf(v0, 0.f) + BNEPS);
    ns1 = rsqrtf(fmaxf(v1, 0.f) + BNEPS);
  }

  // -------- gather phase --------
  int segbase = blockIdx.x * 64 + wave * 8;
#pragma unroll 1
  for (int s = 0; s < 8; s++) {
    int seg = segbase + s;
    int row = wave * 8 + s;
    float s0 = 0.f, s1 = 0.f, m0 = -INFINITY, m1 = -INFINITY;
    int cdeg = 0;
    if (seg < nseg) {
      int b = offs[seg], e = offs[seg + 1];
      cdeg = e - b;
      for (int j = b + half; j < e; j += 2) {
        int g = adj[j];
        unsigned pk = *reinterpret_cast<const unsigned*>(&mat[(size_t)g * HD + c0]);
        float v0 = __uint_as_float(pk << 16);
        float v1 = __uint_as_float(pk & 0xffff0000u);
        if (SRCNORM) {
          v0 = fmaxf((v0 - nm0) * ns0, 0.f);
          v1 = fmaxf((v1 - nm1) * ns1, 0.f);
        }
        s0 += v0; s1 += v1;
        m0 = fmaxf(m0, v0); m1 = fmaxf(m1, v1);
      }
      s0 += __shfl_xor(s0, 32);
      s1 += __shfl_xor(s1, 32);
      m0 = fmaxf(m0, __shfl_xor(m0, 32));
      m1 = fmaxf(m1, __shfl_xor(m1, 32));
    }
    float inv = 1.f / fmaxf((float)cdeg, 1.f);
    if (cdeg == 0) { m0 = 0.f; m1 = 0.f; s0 = 0.f; s1 = 0.f; }
    if (half == 0) {
      unsigned sp = (unsigned)f2bf(s0) | ((unsigned)f2bf(s1) << 16);
      unsigned mp = (unsigned)f2bf(m0) | ((unsigned)f2bf(m1) << 16);
      *reinterpret_cast<unsigned*>(&xl[row * LDX + c0])       = sp;
      *reinterpret_cast<unsigned*>(&xl[row * LDX + 128 + c0]) = mp;
    } else {
      unsigned ap = (unsigned)f2bf(s0 * inv) | ((unsigned)f2bf(s1 * inv) << 16);
      *reinterpret_cast<unsigned*>(&xl[row * LDX + 64 + c0]) = ap;
    }
  }
  __syncthreads();

  // -------- MFMA phase --------
  int lr  = lane & 15;
  int lk  = (lane >> 4) * 8;
  int lj4 = (lane >> 4) * 4;
  int rowtile = wave & 3;
  int colgrp  = wave >> 2;
  int rowbase = rowtile * 16;

  facc4 acc[CTW];
#pragma unroll
  for (int ct = 0; ct < CTW; ct++) acc[ct] = (facc4){0.f, 0.f, 0.f, 0.f};

#pragma unroll
  for (int kt = 0; kt < K / 32; kt++) {
    bfrag8 a = *reinterpret_cast<const bfrag8*>(&xl[(rowbase + lr) * LDX + kt * 32 + lk]);
#pragma unroll
    for (int ct = 0; ct < CTW; ct++) {
      bfrag8 b = *reinterpret_cast<const bfrag8*>(
          &wl[((colgrp * CTW + ct) * 16 + lr) * LDX + kt * 32 + lk]);
      acc[ct] = __builtin_amdgcn_mfma_f32_16x16x32_bf16(a, b, acc[ct], 0, 0, 0);
    }
  }

#pragma unroll
  for (int ct = 0; ct < CTW; ct++) {
    int col = (colgrp * CTW + ct) * 16 + lr;
    float bias = bl[col];
    float s = 0.f, q = 0.f;
#pragma unroll
    for (int j = 0; j < 4; j++) {
      int grow = blockIdx.x * 64 + rowbase + lj4 + j;
      if (grow < nseg) {
        float v = acc[ct][j] + bias;
        if (col < N1) Y1[(size_t)grow * N1 + col] = f2bf(v);
        else          Y2[(size_t)grow * N2 + (col - N1)] = f2bf(v);
        s += v; q += v * v;
      }
    }
    atomicAdd(&ldsS[col], s);
    atomicAdd(&ldsQ[col], q);
  }
  __syncthreads();
  if (tid < NT) {
    if (tid < N1) {
      atomicAdd(&st1[tid], ldsS[tid]);
      atomicAdd(&st1[N1 + tid], ldsQ[tid]);
    } else {
      atomicAdd(&st2[tid - N1], ldsS[tid]);
      atomicAdd(&st2[N2 + (tid - N1)], ldsQ[tid]);
    }
  }
}

// ---------------- MFMA matmul: Y[M,N]bf16 = (bn_relu?)(X)[M,K]bf16 @ W[K,N] + B ----------------

template <int K, int N, int ROWS, bool NIN>
__global__ __launch_bounds__(256) void mm_mfma(const unsigned short* __restrict__ X,
                                               const float* __restrict__ W,
                                               const float* __restrict__ Bv,
                                               unsigned short* __restrict__ Y, int M,
                                               float* __restrict__ st_out,
                                               const float* __restrict__ st_in, float inv_m) {
  constexpr int LDX = K + 8;
  constexpr int RT  = ROWS / 64;
  constexpr int CT  = N / 16;
  __shared__ alignas(16) unsigned short xl[ROWS * LDX];
  __shared__ alignas(16) unsigned short wl[N * LDX];
  __shared__ float bl[N];
  __shared__ float nmean[K], nscal[K];
  __shared__ float ldsS[N], ldsQ[N];

  int tid = threadIdx.x;
  for (int i = tid; i < K * N; i += 256) {
    int k = i / N, n = i - k * N;
    wl[n * LDX + k] = f2bf(W[i]);
  }
  for (int i = tid; i < N; i += 256) bl[i] = Bv[i];
  if (NIN) {
    for (int i = tid; i < K; i += 256) {
      float m = st_in[i] * inv_m;
      float v = st_in[K + i] * inv_m - m * m;
      nmean[i] = m;
      nscal[i] = rsqrtf(fmaxf(v, 0.f) + BNEPS);
    }
  }
  if (tid < N) { ldsS[tid] = 0.f; ldsQ[tid] = 0.f; }

  int lane = tid & 63;
  int wv   = tid >> 6;
  int lr   = lane & 15;
  int lk   = (lane >> 4) * 8;
  int lj4  = (lane >> 4) * 4;
  int rowbase = wv * (RT * 16);

  float sc[CT], sq[CT];
#pragma unroll
  for (int c = 0; c < CT; c++) { sc[c] = 0.f; sq[c] = 0.f; }

  int tiles = (M + ROWS - 1) / ROWS;
  for (int t = blockIdx.x; t < tiles; t += gridDim.x) {
    int r0 = t * ROWS;
    __syncthreads();
    for (int i = tid * 8; i < ROWS * K; i += 2048) {
      int r = i / K, c = i - r * K;
      int row = r0 + r;
      bfrag8 v = {0, 0, 0, 0, 0, 0, 0, 0};
      if (row < M) {
        v = *reinterpret_cast<const bfrag8*>(X + (size_t)row * K + c);
        if (NIN) {
#pragma unroll
          for (int j = 0; j < 8; j++) {
            float f = bf2f((unsigned short)v[j]);
            f = fmaxf((f - nmean[c + j]) * nscal[c + j], 0.f);
            v[j] = (short)f2bf(f);
          }
        }
      }
      *reinterpret_cast<bfrag8*>(&xl[r * LDX + c]) = v;
    }
    __syncthreads();

    facc4 acc[RT][CT];
#pragma unroll
    for (int rt = 0; rt < RT; rt++)
#pragma unroll
      for (int ct = 0; ct < CT; ct++) acc[rt][ct] = (facc4){0.f, 0.f, 0.f, 0.f};

#pragma unroll
    for (int kt = 0; kt < K / 32; kt++) {
      bfrag8 a[RT], b[CT];
#pragma unroll
      for (int rt = 0; rt < RT; rt++)
        a[rt] = *reinterpret_cast<const bfrag8*>(&xl[(rowbase + rt * 16 + lr) * LDX + kt * 32 + lk]);
#pragma unroll
      for (int ct = 0; ct < CT; ct++)
        b[ct] = *reinterpret_cast<const bfrag8*>(&wl[(ct * 16 + lr) * LDX + kt * 32 + lk]);
#pragma unroll
      for (int rt = 0; rt < RT; rt++)
#pragma unroll
        for (int ct = 0; ct < CT; ct++)
          acc[rt][ct] = __builtin_amdgcn_mfma_f32_16x16x32_bf16(a[rt], b[ct], acc[rt][ct], 0, 0, 0);
    }

#pragma unroll
    for (int rt = 0; rt < RT; rt++) {
#pragma unroll
      for (int ct = 0; ct < CT; ct++) {
        int col = ct * 16 + lr;
        float bcol = bl[col];
#pragma unroll
        for (int j = 0; j < 4; j++) {
          int row = r0 + rowbase + rt * 16 + lj4 + j;
          if (row < M) {
            float v = acc[rt][ct][j] + bcol;
            Y[(size_t)row * N + col] = f2bf(v);
            sc[ct] += v; sq[ct] += v * v;
          }
        }
      }
    }
  }

  __syncthreads();
#pragma unroll
  for (int ct = 0; ct < CT; ct++) {
    atomicAdd(&ldsS[ct * 16 + lr], sc[ct]);
    atomicAdd(&ldsQ[ct * 16 + lr], sq[ct]);
  }
  __syncthreads();
  if (tid < N) {
    atomicAdd(&st_out[tid], ldsS[tid]);
    atomicAdd(&st_out[N + tid], ldsQ[tid]);
  }
}

// ---------------- dual-output MFMA matmul (shared input, two weight sets) ----------------
// Y1[M,N1] (+st1), Y2[M,N2] (+st2) from one staged X[M,K=64]. No input norm.

__global__ __launch_bounds__(256) void mm2_mfma(const unsigned short* __restrict__ X,
                                                const float* __restrict__ W1,
                                                const float* __restrict__ B1,
                                                unsigned short* __restrict__ Y1,
                                                float* __restrict__ st1,
                                                const float* __restrict__ W2,
                                                const float* __restrict__ B2,
                                                unsigned short* __restrict__ Y2,
                                                float* __restrict__ st2,
                                                int M) {
  constexpr int K = 64, N1 = 64, N2 = 32, NT = 96, ROWS = 128;
  constexpr int LDX = K + 8, RT = 2, CT = 6;
  __shared__ alignas(16) unsigned short xl[ROWS * LDX];
  __shared__ alignas(16) unsigned short wl[NT * LDX];
  __shared__ float bl[NT];
  __shared__ float ldsS[NT], ldsQ[NT];

  int tid = threadIdx.x;
  for (int i = tid; i < K * N1; i += 256) {
    int k = i / N1, n = i - k * N1;
    wl[n * LDX + k] = f2bf(W1[i]);
  }
  for (int i = tid; i < K * N2; i += 256) {
    int k = i / N2, n = i - k * N2;
    wl[(N1 + n) * LDX + k] = f2bf(W2[i]);
  }
  for (int i = tid; i < N1; i += 256) bl[i] = B1[i];
  for (int i = tid; i < N2; i += 256) bl[N1 + i] = B2[i];
  if (tid < NT) { ldsS[tid] = 0.f; ldsQ[tid] = 0.f; }

  int lane = tid & 63;
  int wv   = tid >> 6;
  int lr   = lane & 15;
  int lk   = (lane >> 4) * 8;
  int lj4  = (lane >> 4) * 4;
  int rowbase = wv * 32;

  float sc[CT], sq[CT];
#pragma unroll
  for (int c = 0; c < CT; c++) { sc[c] = 0.f; sq[c] = 0.f; }

  int tiles = (M + ROWS - 1) / ROWS;
  for (int t = blockIdx.x; t < tiles; t += gridDim.x) {
    int r0 = t * ROWS;
    __syncthreads();
    for (int i = tid * 8; i < ROWS * K; i += 2048) {
      int r = i / K, c = i - r * K;
      int row = r0 + r;
      bfrag8 v = {0, 0, 0, 0, 0, 0, 0, 0};
      if (row < M) v = *reinterpret_cast<const bfrag8*>(X + (size_t)row * K + c);
      *reinterpret_cast<bfrag8*>(&xl[r * LDX + c]) = v;
    }
    __syncthreads();

    facc4 acc[RT][CT];
#pragma unroll
    for (int rt = 0; rt < RT; rt++)
#pragma unroll
      for (int ct = 0; ct < CT; ct++) acc[rt][ct] = (facc4){0.f, 0.f, 0.f, 0.f};

#pragma unroll
    for (int kt = 0; kt < K / 32; kt++) {
      bfrag8 a[RT], b[CT];
#pragma unroll
      for (int rt = 0; rt < RT; rt++)
        a[rt] = *reinterpret_cast<const bfrag8*>(&xl[(rowbase + rt * 16 + lr) * LDX + kt * 32 + lk]);
#pragma unroll
      for (int ct = 0; ct < CT; ct++)
        b[ct] = *reinterpret_cast<const bfrag8*>(&wl[(ct * 16 + lr) * LDX + kt * 32 + lk]);
#pragma unroll
      for (int rt = 0; rt < RT; rt++)
#pragma unroll
        for (int ct = 0; ct < CT; ct++)
          acc[rt][ct] = __builtin_amdgcn_mfma_f32_16x16x32_bf16(a[rt], b[ct], acc[rt][ct], 0, 0, 0);
    }

#pragma unroll
    for (int rt = 0; rt < RT; rt++) {
#pragma unroll
      for (int ct = 0; ct < CT; ct++) {
        int col = ct * 16 + lr;
        float bcol = bl[col];
#pragma unroll
        for (int j = 0; j < 4; j++) {
          int row = r0 + rowbase + rt * 16 + lj4 + j;
          if (row < M) {
            float v = acc[rt][ct][j] + bcol;
            if (col < N1) Y1[(size_t)row * N1 + col] = f2bf(v);
            else          Y2[(size_t)row * N2 + (col - N1)] = f2bf(v);
            sc[ct] += v; sq[ct] += v * v;
          }
        }
      }
    }
  }

  __syncthreads();
#pragma unroll
  for (int ct = 0; ct < CT; ct++) {
    atomicAdd(&ldsS[ct * 16 + lr], sc[ct]);
    atomicAdd(&ldsQ[ct * 16 + lr], sq[ct]);
  }
  __syncthreads();
  if (tid < NT) {
    if (tid < N1) {
      atomicAdd(&st1[tid], ldsS[tid]);
      atomicAdd(&st1[N1 + tid], ldsQ[tid]);
    } else {
      atomicAdd(&st2[tid - N1], ldsS[tid]);
      atomicAdd(&st2[N2 + (tid - N1)], ldsQ[tid]);
    }
  }
}

// ---------------- final normalize + relu + residual add (+bf16 mirror refresh) ----------------

__global__ __launch_bounds__(256) void norm_add_kernel(const unsigned short* __restrict__ X, int M,
                                                       const float* __restrict__ st,
                                                       float* __restrict__ D,
                                                       unsigned short* __restrict__ Dbf) {
  __shared__ float mean[64], scal[64];
  if (threadIdx.x < 64) {
    float m = st[threadIdx.x] / (float)M;
    float v = st[64 + threadIdx.x] / (float)M - m * m;
    mean[threadIdx.x] = m;
    scal[threadIdx.x] = rsqrtf(fmaxf(v, 0.f) + BNEPS);
  }
  __syncthreads();
  size_t ngrp = (size_t)M * 64 / 8;
  for (size_t i = (size_t)blockIdx.x * 256 + threadIdx.x; i < ngrp;
       i += (size_t)gridDim.x * 256) {
    size_t base = i * 8;
    int c = (int)(base & 63);
    bfrag8 xv = *reinterpret_cast<const bfrag8*>(&X[base]);
    float4 d0 = *reinterpret_cast<float4*>(&D[base]);
    float4 d1 = *reinterpret_cast<float4*>(&D[base + 4]);
    float o[8];
#pragma unroll
    for (int j = 0; j < 8; j++) {
      float y = (bf2f((unsigned short)xv[j]) - mean[c + j]) * scal[c + j];
      y = y > 0.f ? y : 0.f;
      float dv = (j < 4) ? (&d0.x)[j] : (&d1.x)[j - 4];
      o[j] = dv + y;
    }
    d0 = make_float4(o[0], o[1], o[2], o[3]);
    d1 = make_float4(o[4], o[5], o[6], o[7]);
    *reinterpret_cast<float4*>(&D[base])     = d0;
    *reinterpret_cast<float4*>(&D[base + 4]) = d1;
    bfrag8 pb;
#pragma unroll
    for (int j = 0; j < 8; j++) pb[j] = (short)f2bf(o[j]);
    *reinterpret_cast<bfrag8*>(&Dbf[base]) = pb;
  }
}

// ---------------- orchestration ----------------

static inline int tiles_of(int M, int R) { return (M + R - 1) / R; }

extern "C" void kernel_launch(void* const* d_in, const int* in_sizes, int n_in,
                              void* d_out, int out_size, void* d_ws, size_t ws_size,
                              hipStream_t stream) {
  const float* xs      = (const float*)d_in[0];
  const float* nn1_w1  = (const float*)d_in[1];
  const float* nn1_b1  = (const float*)d_in[2];
  const float* nn1_w2  = (const float*)d_in[3];
  const float* nn1_b2  = (const float*)d_in[4];
  const float* nn2_w1  = (const float*)d_in[5];
  const float* nn2_b1  = (const float*)d_in[6];
  const float* nn2_w2  = (const float*)d_in[7];
  const float* nn2_b2  = (const float*)d_in[8];
  const float* l1_w    = (const float*)d_in[9];
  const float* l1_b    = (const float*)d_in[10];
  const float* l2_w    = (const float*)d_in[11];
  const float* l2_b    = (const float*)d_in[12];
  const float* l3_w    = (const float*)d_in[13];
  const float* l3_b    = (const float*)d_in[14];
  const float* l4_w    = (const float*)d_in[15];
  const float* l4_b    = (const float*)d_in[16];
  const float* out_w1  = (const float*)d_in[17];
  const float* out_b1  = (const float*)d_in[18];
  const float* out_w2  = (const float*)d_in[19];
  const float* out_b2  = (const float*)d_in[20];
  const int*   src     = (const int*)d_in[21];
  const int*   dst     = (const int*)d_in[22];

  float* out = (float*)d_out;

  // workspace carve — bf16 activation buffers first (all 16B-aligned)
  unsigned short* u     = (unsigned short*)d_ws;
  unsigned short* t1    = u;                                   // 200000*64
  unsigned short* rin   = t1    + (size_t)NTOT * 64;           // 100000*64
  unsigned short* x32   = rin   + (size_t)NLEFT * 64;          // 200000*32
  unsigned short* ri32  = x32   + (size_t)NTOT * 32;           // 100000*32
  unsigned short* li32  = ri32  + (size_t)NLEFT * 32;
  unsigned short* rli32 = li32  + (size_t)NRIGHT * 32;
  unsigned short* outbf = rli32 + (size_t)NRIGHT * 32;         // 200000*64
  float* stats = (float*)(outbf + (size_t)NTOT * 64);          // 20*128
  int*   cntL  = (int*)(stats + 20 * 128);
  int*   cntR  = cntL + NLEFT;
  int*   oL    = cntR + NRIGHT;
  int*   oR    = oL + (NLEFT + 1);
  int*   curL  = oR + (NRIGHT + 1);
  int*   curR  = curL + NLEFT;
  int*   part  = curR + NRIGHT;
  int*   adjL  = part + 1024;
  int*   adjR  = adjL + NEDGE;

  dim3 B(256);
  const int NB1 = (NLEFT + 255) / 256;
  const float invL = 1.f / NLEFT, invT = 1.f / NTOT;
  const int GSEG = tiles_of(NLEFT, 64);   // 1563 blocks for gmm

  init_kernel<<<2048, B, 0, stream>>>(xs, out, outbf, stats, 20 * 128, cntL, cntR, curL, curR);
  count_kernel<<<2048, B, 0, stream>>>(src, dst, cntL, cntR);
  scan1_kernel<<<NB1, B, 0, stream>>>(cntL, NLEFT, part);
  scan2_kernel<<<1, 1024, 0, stream>>>(part, NB1);
  scan3_kernel<<<NB1, B, 0, stream>>>(cntL, NLEFT, part, oL);
  scan1_kernel<<<NB1, B, 0, stream>>>(cntR, NRIGHT, part);
  scan2_kernel<<<1, 1024, 0, stream>>>(part, NB1);
  scan3_kernel<<<NB1, B, 0, stream>>>(cntR, NRIGHT, part, oR);
  fill_kernel<<<2048, B, 0, stream>>>(src, dst, oL, oR, curL, curR, adjL, adjR);

  for (int l = 0; l < 2; l++) {
    const float* p_nn1_w1 = nn1_w1 + (size_t)l * 64 * 64;
    const float* p_nn1_b1 = nn1_b1 + (size_t)l * 64;
    const float* p_nn1_w2 = nn1_w2 + (size_t)l * 64 * 64;
    const float* p_nn1_b2 = nn1_b2 + (size_t)l * 64;
    const float* p_nn2_w1 = nn2_w1 + (size_t)l * 192 * 64;
    const float* p_nn2_b1 = nn2_b1 + (size_t)l * 64;
    const float* p_nn2_w2 = nn2_w2 + (size_t)l * 64 * 64;
    const float* p_nn2_b2 = nn2_b2 + (size_t)l * 64;
    const float* p_l1_w   = l1_w   + (size_t)l * 64 * 32;
    const float* p_l1_b   = l1_b   + (size_t)l * 32;
    const float* p_l2_w   = l2_w   + (size_t)l * 192 * 32;
    const float* p_l2_b   = l2_b   + (size_t)l * 32;
    const float* p_l3_w   = l3_w   + (size_t)l * 192 * 32;
    const float* p_l3_b   = l3_b   + (size_t)l * 32;
    const float* p_l4_w   = l4_w   + (size_t)l * 192 * 32;
    const float* p_l4_b   = l4_b   + (size_t)l * 32;
    const float* p_out_w1 = out_w1 + (size_t)l * 128 * 64;
    const float* p_out_b1 = out_b1 + (size_t)l * 64;
    const float* p_out_w2 = out_w2 + (size_t)l * 64 * 64;
    const float* p_out_b2 = out_b2 + (size_t)l * 64;

    float* S = stats + (size_t)l * 10 * 128;
    auto ST = [&](int s) { return S + (size_t)s * 128; };

    // a+b+c1) gather right_info; ri=l2(info)->s0; rin=nn2_w1(info)->s1 (fused)
    gmm_mfma<32, 64, false><<<GSEG, 512, 0, stream>>>(
        outbf + (size_t)NLEFT * 64, oL, adjL, NLEFT, nullptr, 0.f,
        p_l2_w, p_l2_b, ri32, ST(0),
        p_nn2_w1, p_nn2_b1, rin, ST(1));
    // c2) rin = nn2_w2(bnrelu(rin,s1)); s2
    mm_mfma<64, 64, 128, true><<<tiles_of(NLEFT, 128), B, 0, stream>>>(
        rin, p_nn2_w2, p_nn2_b2, rin, NLEFT, ST(2), ST(1), invL);
    // d+e) gather rl_info from bnrelu(rin,s2); rli=l4(info)->s3 (fused)
    gmm_mfma<32, 0, true><<<GSEG, 512, 0, stream>>>(
        rin, oR, adjR, NRIGHT, ST(2), invL,
        p_l4_w, p_l4_b, rli32, ST(3),
        nullptr, nullptr, nullptr, nullptr);
    // f1+i) t1 = nn1_w1(outbf)->s4 ; x32 = l1(outbf)->s7 (fused dual output)
    mm2_mfma<<<tiles_of(NTOT, 128), B, 0, stream>>>(
        outbf, p_nn1_w1, p_nn1_b1, t1, ST(4),
        p_l1_w, p_l1_b, x32, ST(7), NTOT);
    // f2) t1 = nn1_w2(bnrelu(t1,s4)); s5
    mm_mfma<64, 64, 128, true><<<tiles_of(NTOT, 128), B, 0, stream>>>(
        t1, p_nn1_w2, p_nn1_b2, t1, NTOT, ST(5), ST(4), invT);
    // g+h) gather left_info from bnrelu(t1,s5); li=l3(info)->s6 (fused)
    gmm_mfma<32, 0, true><<<GSEG, 512, 0, stream>>>(
        t1, oR, adjR, NRIGHT, ST(5), invT,
        p_l3_w, p_l3_b, li32, ST(6),
        nullptr, nullptr, nullptr, nullptr);
    // j) t1 = out_w1(h virtual concat); s8  — mmh via mm2-style? keep mmh path:
    //    reuse mm_mfma-style fused-concat kernel below
    // (mmh unchanged)
    {
      extern __global__ void mmh_dummy();  // (placeholder comment; real launch below)
    }
    // mmh: virtual concat -> t1, stats s8
    // (declared after; launched here)
    void mmh_launch();  // no-op declaration to keep structure clear
    // actual launch:
    {
      // forward declaration resolved below by definition order
    }
    // j1) mmh
    // j2) out_w2; j3) norm_add
    // --- launches ---
    // (mmh_mfma defined below main for clarity)
    extern void launch_mmh(const unsigned short*, const unsigned short*, const unsigned short*,
                           const unsigned short*, const float*, const float*, const float*,
                           const float*, const float*, const float*, unsigned short*, float*,
                           hipStream_t);
    launch_mmh(x32, ri32, li32, rli32, ST(7), ST(0), ST(6), ST(3),
               p_out_w1, p_out_b1, t1, ST(8), stream);
    mm_mfma<64, 64, 128, true><<<tiles_of(NTOT, 128), B, 0, stream>>>(
        t1, p_out_w2, p_out_b2, t1, NTOT, ST(9), ST(8), invT);
    norm_add_kernel<<<2048, B, 0, stream>>>(t1, NTOT, ST(9), out, outbf);
  }
}

// ---------------- MFMA matmul on virtual concat h (K=128,N=64), 4 bf16 sources ----------------

__global__ __launch_bounds__(256) void mmh_mfma(const unsigned short* __restrict__ x32,
                                                const unsigned short* __restrict__ ri,
                                                const unsigned short* __restrict__ li,
                                                const unsigned short* __restrict__ rli,
                                                const float* __restrict__ stx,
                                                const float* __restrict__ stri,
                                                const float* __restrict__ stli,
                                                const float* __restrict__ strli,
                                                const float* __restrict__ W,
                                                const float* __restrict__ Bv,
                                                unsigned short* __restrict__ Y,
                                                float* __restrict__ st_out) {
  constexpr int K = 128, N = 64, ROWS = 128, LDX = K + 8, RT = 2, CT = 4;
  __shared__ alignas(16) unsigned short xl[ROWS * LDX];
  __shared__ alignas(16) unsigned short wl[N * LDX];
  __shared__ float bl[N];
  __shared__ float m4[4 * 32], s4[4 * 32];
  __shared__ float ldsS[N], ldsQ[N];

  int tid = threadIdx.x;
  for (int i = tid; i < K * N; i += 256) {
    int k = i / N, n = i - k * N;
    wl[n * LDX + k] = f2bf(W[i]);
  }
  for (int i = tid; i < N; i += 256) bl[i] = Bv[i];
  if (tid < 128) {
    int s = tid >> 5, c = tid & 31;
    const float* st = (s == 0) ? stx : (s == 1) ? stri : (s == 2) ? stli : strli;
    float inv = (s == 0) ? (1.f / NTOT) : (s == 1) ? (1.f / NLEFT) : (1.f / NRIGHT);
    float m = st[c] * inv;
    float v = st[32 + c] * inv - m * m;
    m4[tid] = m;
    s4[tid] = rsqrtf(fmaxf(v, 0.f) + BNEPS);
  }
  if (tid < N) { ldsS[tid] = 0.f; ldsQ[tid] = 0.f; }

  int lane = tid & 63;
  int wv   = tid >> 6;
  int lr   = lane & 15;
  int lk   = (lane >> 4) * 8;
  int lj4  = (lane >> 4) * 4;
  int rowbase = wv * 32;

  float sc[CT], sq[CT];
#pragma unroll
  for (int c = 0; c < CT; c++) { sc[c] = 0.f; sq[c] = 0.f; }

  const int M = NTOT;
  int tiles = (M + ROWS - 1) / ROWS;
  for (int t = blockIdx.x; t < tiles; t += gridDim.x) {
    int r0 = t * ROWS;
    __syncthreads();
    for (int i = tid * 8; i < ROWS * K; i += 2048) {
      int r = i / K, c = i - r * K;
      int row = r0 + r;
      bfrag8 v = {0, 0, 0, 0, 0, 0, 0, 0};
      if (row < M) {
        int cb = c >> 5, cc = c & 31;
        const unsigned short* srcp;
        int set, srow;
        if (row < NLEFT) {
          if (cb == 1) { srcp = ri;  set = 1; srow = row; }
          else         { srcp = x32; set = 0; srow = row; }
        } else {
          int rr = row - NLEFT;
          if (cb <= 1)      { srcp = x32; set = 0; srow = row; }
          else if (cb == 2) { srcp = li;  set = 2; srow = rr; }
          else              { srcp = rli; set = 3; srow = rr; }
        }
        v = *reinterpret_cast<const bfrag8*>(srcp + (size_t)srow * 32 + cc);
        const float* mm_ = &m4[set * 32 + cc];
        const float* ss_ = &s4[set * 32 + cc];
#pragma unroll
        for (int j = 0; j < 8; j++) {
          float f = bf2f((unsigned short)v[j]);
          f = fmaxf((f - mm_[j]) * ss_[j], 0.f);
          v[j] = (short)f2bf(f);
        }
      }
      *reinterpret_cast<bfrag8*>(&xl[r * LDX + c]) = v;
    }
    __syncthreads();

    facc4 acc[RT][CT];
#pragma unroll
    for (int rt = 0; rt < RT; rt++)
#pragma unroll
      for (int ct = 0; ct < CT; ct++) acc[rt][ct] = (facc4){0.f, 0.f, 0.f, 0.f};

#pragma unroll
    for (int kt = 0; kt < K / 32; kt++) {
      bfrag8 a[RT], b[CT];
#pragma unroll
      for (int rt = 0; rt < RT; rt++)
        a[rt] = *reinterpret_cast<const bfrag8*>(&xl[(rowbase + rt * 16 + lr) * LDX + kt * 32 + lk]);
#pragma unroll
      for (int ct = 0; ct < CT; ct++)
        b[ct] = *reinterpret_cast<const bfrag8*>(&wl[(ct * 16 + lr) * LDX + kt * 32 + lk]);
#pragma unroll
      for (int rt = 0; rt < RT; rt++)
#pragma unroll
        for (int ct = 0; ct < CT; ct++)
          acc[rt][ct] = __builtin_amdgcn_mfma_f32_16x16x32_bf16(a[rt], b[ct], acc[rt][ct], 0, 0, 0);
    }

#pragma unroll
    for (int rt = 0; rt < RT; rt++) {
#pragma unroll
      for (int ct = 0; ct < CT; ct++) {
        int col = ct * 16 + lr;
        float bcol = bl[col];
#pragma unroll
        for (int j = 0; j < 4; j++) {
          int row = r0 + rowbase + rt * 16 + lj4 + j;
          if (row < M) {
            float v = acc[rt][ct][j] + bcol;
            Y[(size_t)row * N + col] = f2bf(v);
            sc[ct] += v; sq[ct] += v * v;
          }
        }
      }
    }
  }

  __syncthreads();
#pragma unroll
  for (int ct = 0; ct < CT; ct++) {
    atomicAdd(&ldsS[ct * 16 + lr], sc[ct]);
    atomicAdd(&ldsQ[ct * 16 + lr], sq[ct]);
  }
  __syncthreads();
  if (tid < N) {
    atomicAdd(&st_out[tid], ldsS[tid]);
    atomicAdd(&st_out[N + tid], ldsQ[tid]);
  }
}

void launch_mmh(const unsigned short* x32, const unsigned short* ri,
                const unsigned short* li, const unsigned short* rli,
                const float* stx, const float* stri, const float* stli,
                const float* strli, const float* W, const float* Bv,
                unsigned short* Y, float* st_out, hipStream_t stream) {
  mmh_mfma<<<tiles_of(NTOT, 128), dim3(256), 0, stream>>>(
      x32, ri, li, rli, stx, stri, stli, strli, W, Bv, Y, st_out);
}

// Round 8
// 1495.974 us; speedup vs baseline: 3.4134x; 1.0300x over previous
//
#include <hip/hip_runtime.h>

#define NLEFT  100000
#define NRIGHT 100000
#define NTOT   200000
#define NEDGE  1000000
#define HD     64
#define BNEPS  1e-5f

typedef __attribute__((ext_vector_type(8))) short bfrag8;
typedef __attribute__((ext_vector_type(4))) float facc4;

__device__ inline unsigned short f2bf(float f) {
  unsigned u = __float_as_uint(f);
  u = u + 0x7fffu + ((u >> 16) & 1u);   // RNE
  return (unsigned short)(u >> 16);
}
__device__ inline float bf2f(unsigned short u) {
  return __uint_as_float((unsigned)u << 16);
}

// ---------------- init: d_out = xs (+bf16 mirror), zero stats/cursors ----------------

__global__ __launch_bounds__(256) void init_kernel(const float* __restrict__ xs,
                                                   float* __restrict__ out,
                                                   unsigned short* __restrict__ outbf,
                                                   float* __restrict__ st, int nst,
                                                   int* __restrict__ cl, int* __restrict__ cr,
                                                   int* __restrict__ curl, int* __restrict__ curr) {
  size_t ng = (size_t)NTOT * HD / 4;
  for (size_t i = (size_t)blockIdx.x * blockDim.x + threadIdx.x; i < ng;
       i += (size_t)gridDim.x * blockDim.x) {
    float4 v = reinterpret_cast<const float4*>(xs)[i];
    reinterpret_cast<float4*>(out)[i] = v;
    ushort4 p;
    p.x = f2bf(v.x); p.y = f2bf(v.y); p.z = f2bf(v.z); p.w = f2bf(v.w);
    reinterpret_cast<ushort4*>(outbf)[i] = p;
  }
  for (int i = blockIdx.x * blockDim.x + threadIdx.x; i < NLEFT;
       i += gridDim.x * blockDim.x) {
    cl[i] = 0; curl[i] = 0; cr[i] = 0; curr[i] = 0;
    if (i < nst) st[i] = 0.f;
  }
}

__global__ __launch_bounds__(256) void count_kernel(const int* __restrict__ src,
                                                    const int* __restrict__ dst,
                                                    int* __restrict__ cl, int* __restrict__ cr) {
  for (int e = blockIdx.x * blockDim.x + threadIdx.x; e < NEDGE;
       e += gridDim.x * blockDim.x) {
    atomicAdd(&cl[src[e]], 1);
    atomicAdd(&cr[dst[e]], 1);
  }
}

// ---------------- exclusive scan (counts -> offsets) ----------------

__global__ __launch_bounds__(256) void scan1_kernel(const int* __restrict__ cnt, int n,
                                                    int* __restrict__ partial) {
  __shared__ int tmp[256];
  int i = blockIdx.x * 256 + threadIdx.x;
  tmp[threadIdx.x] = (i < n) ? cnt[i] : 0;
  __syncthreads();
  for (int s = 128; s > 0; s >>= 1) {
    if (threadIdx.x < s) tmp[threadIdx.x] += tmp[threadIdx.x + s];
    __syncthreads();
  }
  if (threadIdx.x == 0) partial[blockIdx.x] = tmp[0];
}

__global__ __launch_bounds__(1024) void scan2_kernel(int* __restrict__ partial, int nb) {
  __shared__ int tmp[1024];
  int t = threadIdx.x;
  int v = (t < nb) ? partial[t] : 0;
  tmp[t] = v;
  __syncthreads();
  for (int off = 1; off < 1024; off <<= 1) {
    int x = tmp[t];
    int add = (t >= off) ? tmp[t - off] : 0;
    __syncthreads();
    tmp[t] = x + add;
    __syncthreads();
  }
  if (t < nb) partial[t] = tmp[t] - v;
}

__global__ __launch_bounds__(256) void scan3_kernel(const int* __restrict__ cnt, int n,
                                                    const int* __restrict__ partial,
                                                    int* __restrict__ offs) {
  __shared__ int tmp[256];
  int t = threadIdx.x;
  int i = blockIdx.x * 256 + t;
  int v = (i < n) ? cnt[i] : 0;
  tmp[t] = v;
  __syncthreads();
  for (int off = 1; off < 256; off <<= 1) {
    int x = tmp[t];
    int add = (t >= off) ? tmp[t - off] : 0;
    __syncthreads();
    tmp[t] = x + add;
    __syncthreads();
  }
  if (i < n) offs[i] = tmp[t] - v + partial[blockIdx.x];
  if (i == 0) offs[n] = NEDGE;
}

// ---------------- CSR fill ----------------

__global__ __launch_bounds__(256) void fill_kernel(const int* __restrict__ src,
                                                   const int* __restrict__ dst,
                                                   const int* __restrict__ oL,
                                                   const int* __restrict__ oR,
                                                   int* __restrict__ curL, int* __restrict__ curR,
                                                   int* __restrict__ adjL, int* __restrict__ adjR) {
  for (int e = blockIdx.x * blockDim.x + threadIdx.x; e < NEDGE;
       e += gridDim.x * blockDim.x) {
    int s = src[e], d = dst[e];
    int p = atomicAdd(&curL[s], 1);
    adjL[oL[s] + p] = d;
    int q = atomicAdd(&curR[d], 1);
    adjR[oR[d] + q] = s;
  }
}

// ---------------- fused gather + MFMA ----------------
// Block = 512 threads (8 waves); 32-segment tile per block.
// Gather: each wave handles 4 segments; per segment the edge loop runs in
// chunks of 8 per 32-lane half (all 8 adj->mat chains issued before
// accumulation -> MLP ~16/wave). Writes sum/mean/max bf16 into LDS X tile.
// MFMA: 6 waves (dual) / 4 waves (single) consume the tile; dual weight
// sets, dual outputs, fused BN stats.

template <int N1, int N2, bool SRCNORM>
__global__ __launch_bounds__(512) void gmm_mfma(const unsigned short* __restrict__ mat,
                                                const int* __restrict__ offs,
                                                const int* __restrict__ adj,
                                                int nseg,
                                                const float* __restrict__ st_src, float inv_src,
                                                const float* __restrict__ W1,
                                                const float* __restrict__ B1,
                                                unsigned short* __restrict__ Y1,
                                                float* __restrict__ st1,
                                                const float* __restrict__ W2,
                                                const float* __restrict__ B2,
                                                unsigned short* __restrict__ Y2,
                                                float* __restrict__ st2) {
  constexpr int K    = 192;
  constexpr int LDX  = 200;
  constexpr int SEGS = 32;
  constexpr int NT   = N1 + N2;
  constexpr int CTT  = NT / 16;               // total col-tiles (2 or 6)
  constexpr int CTW  = (CTT >= 6) ? 2 : 1;    // col-tiles per wave
  constexpr int NGRP = CTT / CTW;             // col groups (2 or 3)
  constexpr int NWM  = 2 * NGRP;              // waves active in MFMA (4 or 6)
  __shared__ alignas(16) unsigned short xl[SEGS * LDX];
  __shared__ alignas(16) unsigned short wl[NT * LDX];
  __shared__ float bl[NT];
  __shared__ float ldsS[NT], ldsQ[NT];

  int tid = threadIdx.x;
  for (int i = tid; i < K * N1; i += 512) {
    int k = i / N1, n = i - k * N1;
    wl[n * LDX + k] = f2bf(W1[i]);
  }
  if constexpr (N2 > 0) {
    for (int i = tid; i < K * N2; i += 512) {
      int k = i / N2, n = i - k * N2;
      wl[(N1 + n) * LDX + k] = f2bf(W2[i]);
    }
  }
  for (int i = tid; i < N1; i += 512) bl[i] = B1[i];
  if constexpr (N2 > 0)
    for (int i = tid; i < N2; i += 512) bl[N1 + i] = B2[i];
  if (tid < NT) { ldsS[tid] = 0.f; ldsQ[tid] = 0.f; }

  int wave = tid >> 6;
  int lane = tid & 63;
  int half = lane >> 5;
  int c0   = (lane & 31) * 2;

  float nm0 = 0.f, nm1 = 0.f, ns0 = 1.f, ns1 = 1.f;
  if (SRCNORM) {
    float m0 = st_src[c0] * inv_src, m1 = st_src[c0 + 1] * inv_src;
    float v0 = st_src[64 + c0] * inv_src - m0 * m0;
    float v1 = st_src[64 + c0 + 1] * inv_src - m1 * m1;
    nm0 = m0; nm1 = m1;
    ns0 = rsqrtf(fmaxf(v0, 0.f) + BNEPS);
    ns1 = rsqrtf(fmaxf(v1, 0.f) + BNEPS);
  }

  // -------- gather phase: 4 segments per wave, 8-deep batched loads --------
  int segbase = blockIdx.x * SEGS + wave * 4;
  for (int s = 0; s < 4; s++) {
    int seg = segbase + s;
    int row = wave * 4 + s;
    float s0 = 0.f, s1 = 0.f, m0 = -INFINITY, m1 = -INFINITY;
    int cdeg = 0;
    if (seg < nseg) {
      int b = offs[seg], e = offs[seg + 1];
      cdeg = e - b;
      for (int jb = b + half; jb < e; jb += 16) {
        unsigned pk[8];
#pragma unroll
        for (int t = 0; t < 8; t++) {
          int j = jb + 2 * t;
          pk[t] = 0;
          if (j < e) {
            int g = adj[j];
            pk[t] = *reinterpret_cast<const unsigned*>(&mat[(size_t)g * HD + c0]);
          }
        }
#pragma unroll
        for (int t = 0; t < 8; t++) {
          int j = jb + 2 * t;
          if (j < e) {
            float v0 = __uint_as_float(pk[t] << 16);
            float v1 = __uint_as_float(pk[t] & 0xffff0000u);
            if (SRCNORM) {
              v0 = fmaxf((v0 - nm0) * ns0, 0.f);
              v1 = fmaxf((v1 - nm1) * ns1, 0.f);
            }
            s0 += v0; s1 += v1;
            m0 = fmaxf(m0, v0); m1 = fmaxf(m1, v1);
          }
        }
      }
      s0 += __shfl_xor(s0, 32);
      s1 += __shfl_xor(s1, 32);
      m0 = fmaxf(m0, __shfl_xor(m0, 32));
      m1 = fmaxf(m1, __shfl_xor(m1, 32));
    }
    float inv = 1.f / fmaxf((float)cdeg, 1.f);
    if (cdeg == 0) { m0 = 0.f; m1 = 0.f; s0 = 0.f; s1 = 0.f; }
    if (half == 0) {
      unsigned sp = (unsigned)f2bf(s0) | ((unsigned)f2bf(s1) << 16);
      unsigned mp = (unsigned)f2bf(m0) | ((unsigned)f2bf(m1) << 16);
      *reinterpret_cast<unsigned*>(&xl[row * LDX + c0])       = sp;
      *reinterpret_cast<unsigned*>(&xl[row * LDX + 128 + c0]) = mp;
    } else {
      unsigned ap = (unsigned)f2bf(s0 * inv) | ((unsigned)f2bf(s1 * inv) << 16);
      *reinterpret_cast<unsigned*>(&xl[row * LDX + 64 + c0]) = ap;
    }
  }
  __syncthreads();

  // -------- MFMA phase (waves 0..NWM-1) --------
  if (wave < NWM) {
    int lr  = lane & 15;
    int lk  = (lane >> 4) * 8;
    int lj4 = (lane >> 4) * 4;
    int rowtile = wave & 1;
    int colgrp  = wave >> 1;
    int rowbase = rowtile * 16;

    facc4 acc[CTW];
#pragma unroll
    for (int ct = 0; ct < CTW; ct++) acc[ct] = (facc4){0.f, 0.f, 0.f, 0.f};

#pragma unroll
    for (int kt = 0; kt < K / 32; kt++) {
      bfrag8 a = *reinterpret_cast<const bfrag8*>(&xl[(rowbase + lr) * LDX + kt * 32 + lk]);
#pragma unroll
      for (int ct = 0; ct < CTW; ct++) {
        bfrag8 b = *reinterpret_cast<const bfrag8*>(
            &wl[((colgrp * CTW + ct) * 16 + lr) * LDX + kt * 32 + lk]);
        acc[ct] = __builtin_amdgcn_mfma_f32_16x16x32_bf16(a, b, acc[ct], 0, 0, 0);
      }
    }

#pragma unroll
    for (int ct = 0; ct < CTW; ct++) {
      int col = (colgrp * CTW + ct) * 16 + lr;
      float bias = bl[col];
      float s = 0.f, q = 0.f;
#pragma unroll
      for (int j = 0; j < 4; j++) {
        int grow = blockIdx.x * SEGS + rowbase + lj4 + j;
        if (grow < nseg) {
          float v = acc[ct][j] + bias;
          if (col < N1) Y1[(size_t)grow * N1 + col] = f2bf(v);
          else          Y2[(size_t)grow * N2 + (col - N1)] = f2bf(v);
          s += v; q += v * v;
        }
      }
      atomicAdd(&ldsS[col], s);
      atomicAdd(&ldsQ[col], q);
    }
  }
  __syncthreads();
  if (tid < NT) {
    if (tid < N1) {
      atomicAdd(&st1[tid], ldsS[tid]);
      atomicAdd(&st1[N1 + tid], ldsQ[tid]);
    } else {
      atomicAdd(&st2[tid - N1], ldsS[tid]);
      atomicAdd(&st2[N2 + (tid - N1)], ldsQ[tid]);
    }
  }
}

// ---------------- MFMA matmul: Y[M,N]bf16 = (bn_relu?)(X)[M,K]bf16 @ W[K,N] + B ----------------

template <int K, int N, int ROWS, bool NIN>
__global__ __launch_bounds__(256) void mm_mfma(const unsigned short* __restrict__ X,
                                               const float* __restrict__ W,
                                               const float* __restrict__ Bv,
                                               unsigned short* __restrict__ Y, int M,
                                               float* __restrict__ st_out,
                                               const float* __restrict__ st_in, float inv_m) {
  constexpr int LDX = K + 8;
  constexpr int RT  = ROWS / 64;
  constexpr int CT  = N / 16;
  __shared__ alignas(16) unsigned short xl[ROWS * LDX];
  __shared__ alignas(16) unsigned short wl[N * LDX];
  __shared__ float bl[N];
  __shared__ float nmean[K], nscal[K];
  __shared__ float ldsS[N], ldsQ[N];

  int tid = threadIdx.x;
  for (int i = tid; i < K * N; i += 256) {
    int k = i / N, n = i - k * N;
    wl[n * LDX + k] = f2bf(W[i]);
  }
  for (int i = tid; i < N; i += 256) bl[i] = Bv[i];
  if (NIN) {
    for (int i = tid; i < K; i += 256) {
      float m = st_in[i] * inv_m;
      float v = st_in[K + i] * inv_m - m * m;
      nmean[i] = m;
      nscal[i] = rsqrtf(fmaxf(v, 0.f) + BNEPS);
    }
  }
  if (tid < N) { ldsS[tid] = 0.f; ldsQ[tid] = 0.f; }

  int lane = tid & 63;
  int wv   = tid >> 6;
  int lr   = lane & 15;
  int lk   = (lane >> 4) * 8;
  int lj4  = (lane >> 4) * 4;
  int rowbase = wv * (RT * 16);

  float sc[CT], sq[CT];
#pragma unroll
  for (int c = 0; c < CT; c++) { sc[c] = 0.f; sq[c] = 0.f; }

  int tiles = (M + ROWS - 1) / ROWS;
  for (int t = blockIdx.x; t < tiles; t += gridDim.x) {
    int r0 = t * ROWS;
    __syncthreads();
    for (int i = tid * 8; i < ROWS * K; i += 2048) {
      int r = i / K, c = i - r * K;
      int row = r0 + r;
      bfrag8 v = {0, 0, 0, 0, 0, 0, 0, 0};
      if (row < M) {
        v = *reinterpret_cast<const bfrag8*>(X + (size_t)row * K + c);
        if (NIN) {
#pragma unroll
          for (int j = 0; j < 8; j++) {
            float f = bf2f((unsigned short)v[j]);
            f = fmaxf((f - nmean[c + j]) * nscal[c + j], 0.f);
            v[j] = (short)f2bf(f);
          }
        }
      }
      *reinterpret_cast<bfrag8*>(&xl[r * LDX + c]) = v;
    }
    __syncthreads();

    facc4 acc[RT][CT];
#pragma unroll
    for (int rt = 0; rt < RT; rt++)
#pragma unroll
      for (int ct = 0; ct < CT; ct++) acc[rt][ct] = (facc4){0.f, 0.f, 0.f, 0.f};

#pragma unroll
    for (int kt = 0; kt < K / 32; kt++) {
      bfrag8 a[RT], b[CT];
#pragma unroll
      for (int rt = 0; rt < RT; rt++)
        a[rt] = *reinterpret_cast<const bfrag8*>(&xl[(rowbase + rt * 16 + lr) * LDX + kt * 32 + lk]);
#pragma unroll
      for (int ct = 0; ct < CT; ct++)
        b[ct] = *reinterpret_cast<const bfrag8*>(&wl[(ct * 16 + lr) * LDX + kt * 32 + lk]);
#pragma unroll
      for (int rt = 0; rt < RT; rt++)
#pragma unroll
        for (int ct = 0; ct < CT; ct++)
          acc[rt][ct] = __builtin_amdgcn_mfma_f32_16x16x32_bf16(a[rt], b[ct], acc[rt][ct], 0, 0, 0);
    }

#pragma unroll
    for (int rt = 0; rt < RT; rt++) {
#pragma unroll
      for (int ct = 0; ct < CT; ct++) {
        int col = ct * 16 + lr;
        float bcol = bl[col];
#pragma unroll
        for (int j = 0; j < 4; j++) {
          int row = r0 + rowbase + rt * 16 + lj4 + j;
          if (row < M) {
            float v = acc[rt][ct][j] + bcol;
            Y[(size_t)row * N + col] = f2bf(v);
            sc[ct] += v; sq[ct] += v * v;
          }
        }
      }
    }
  }

  __syncthreads();
#pragma unroll
  for (int ct = 0; ct < CT; ct++) {
    atomicAdd(&ldsS[ct * 16 + lr], sc[ct]);
    atomicAdd(&ldsQ[ct * 16 + lr], sq[ct]);
  }
  __syncthreads();
  if (tid < N) {
    atomicAdd(&st_out[tid], ldsS[tid]);
    atomicAdd(&st_out[N + tid], ldsQ[tid]);
  }
}

// ---------------- dual-output MFMA matmul (shared input, two weight sets) ----------------

__global__ __launch_bounds__(256) void mm2_mfma(const unsigned short* __restrict__ X,
                                                const float* __restrict__ W1,
                                                const float* __restrict__ B1,
                                                unsigned short* __restrict__ Y1,
                                                float* __restrict__ st1,
                                                const float* __restrict__ W2,
                                                const float* __restrict__ B2,
                                                unsigned short* __restrict__ Y2,
                                                float* __restrict__ st2,
                                                int M) {
  constexpr int K = 64, N1 = 64, N2 = 32, NT = 96, ROWS = 128;
  constexpr int LDX = K + 8, RT = 2, CT = 6;
  __shared__ alignas(16) unsigned short xl[ROWS * LDX];
  __shared__ alignas(16) unsigned short wl[NT * LDX];
  __shared__ float bl[NT];
  __shared__ float ldsS[NT], ldsQ[NT];

  int tid = threadIdx.x;
  for (int i = tid; i < K * N1; i += 256) {
    int k = i / N1, n = i - k * N1;
    wl[n * LDX + k] = f2bf(W1[i]);
  }
  for (int i = tid; i < K * N2; i += 256) {
    int k = i / N2, n = i - k * N2;
    wl[(N1 + n) * LDX + k] = f2bf(W2[i]);
  }
  for (int i = tid; i < N1; i += 256) bl[i] = B1[i];
  for (int i = tid; i < N2; i += 256) bl[N1 + i] = B2[i];
  if (tid < NT) { ldsS[tid] = 0.f; ldsQ[tid] = 0.f; }

  int lane = tid & 63;
  int wv   = tid >> 6;
  int lr   = lane & 15;
  int lk   = (lane >> 4) * 8;
  int lj4  = (lane >> 4) * 4;
  int rowbase = wv * 32;

  float sc[CT], sq[CT];
#pragma unroll
  for (int c = 0; c < CT; c++) { sc[c] = 0.f; sq[c] = 0.f; }

  int tiles = (M + ROWS - 1) / ROWS;
  for (int t = blockIdx.x; t < tiles; t += gridDim.x) {
    int r0 = t * ROWS;
    __syncthreads();
    for (int i = tid * 8; i < ROWS * K; i += 2048) {
      int r = i / K, c = i - r * K;
      int row = r0 + r;
      bfrag8 v = {0, 0, 0, 0, 0, 0, 0, 0};
      if (row < M) v = *reinterpret_cast<const bfrag8*>(X + (size_t)row * K + c);
      *reinterpret_cast<bfrag8*>(&xl[r * LDX + c]) = v;
    }
    __syncthreads();

    facc4 acc[RT][CT];
#pragma unroll
    for (int rt = 0; rt < RT; rt++)
#pragma unroll
      for (int ct = 0; ct < CT; ct++) acc[rt][ct] = (facc4){0.f, 0.f, 0.f, 0.f};

#pragma unroll
    for (int kt = 0; kt < K / 32; kt++) {
      bfrag8 a[RT], b[CT];
#pragma unroll
      for (int rt = 0; rt < RT; rt++)
        a[rt] = *reinterpret_cast<const bfrag8*>(&xl[(rowbase + rt * 16 + lr) * LDX + kt * 32 + lk]);
#pragma unroll
      for (int ct = 0; ct < CT; ct++)
        b[ct] = *reinterpret_cast<const bfrag8*>(&wl[(ct * 16 + lr) * LDX + kt * 32 + lk]);
#pragma unroll
      for (int rt = 0; rt < RT; rt++)
#pragma unroll
        for (int ct = 0; ct < CT; ct++)
          acc[rt][ct] = __builtin_amdgcn_mfma_f32_16x16x32_bf16(a[rt], b[ct], acc[rt][ct], 0, 0, 0);
    }

#pragma unroll
    for (int rt = 0; rt < RT; rt++) {
#pragma unroll
      for (int ct = 0; ct < CT; ct++) {
        int col = ct * 16 + lr;
        float bcol = bl[col];
#pragma unroll
        for (int j = 0; j < 4; j++) {
          int row = r0 + rowbase + rt * 16 + lj4 + j;
          if (row < M) {
            float v = acc[rt][ct][j] + bcol;
            if (col < N1) Y1[(size_t)row * N1 + col] = f2bf(v);
            else          Y2[(size_t)row * N2 + (col - N1)] = f2bf(v);
            sc[ct] += v; sq[ct] += v * v;
          }
        }
      }
    }
  }

  __syncthreads();
#pragma unroll
  for (int ct = 0; ct < CT; ct++) {
    atomicAdd(&ldsS[ct * 16 + lr], sc[ct]);
    atomicAdd(&ldsQ[ct * 16 + lr], sq[ct]);
  }
  __syncthreads();
  if (tid < NT) {
    if (tid < N1) {
      atomicAdd(&st1[tid], ldsS[tid]);
      atomicAdd(&st1[N1 + tid], ldsQ[tid]);
    } else {
      atomicAdd(&st2[tid - N1], ldsS[tid]);
      atomicAdd(&st2[N2 + (tid - N1)], ldsQ[tid]);
    }
  }
}

// ---------------- MFMA matmul on virtual concat h (K=128,N=64), 4 bf16 sources ----------------

__global__ __launch_bounds__(256) void mmh_mfma(const unsigned short* __restrict__ x32,
                                                const unsigned short* __restrict__ ri,
                                                const unsigned short* __restrict__ li,
                                                const unsigned short* __restrict__ rli,
                                                const float* __restrict__ stx,
                                                const float* __restrict__ stri,
                                                const float* __restrict__ stli,
                                                const float* __restrict__ strli,
                                                const float* __restrict__ W,
                                                const float* __restrict__ Bv,
                                                unsigned short* __restrict__ Y,
                                                float* __restrict__ st_out) {
  constexpr int K = 128, N = 64, ROWS = 128, LDX = K + 8, RT = 2, CT = 4;
  __shared__ alignas(16) unsigned short xl[ROWS * LDX];
  __shared__ alignas(16) unsigned short wl[N * LDX];
  __shared__ float bl[N];
  __shared__ float m4[4 * 32], s4[4 * 32];
  __shared__ float ldsS[N], ldsQ[N];

  int tid = threadIdx.x;
  for (int i = tid; i < K * N; i += 256) {
    int k = i / N, n = i - k * N;
    wl[n * LDX + k] = f2bf(W[i]);
  }
  for (int i = tid; i < N; i += 256) bl[i] = Bv[i];
  if (tid < 128) {
    int s = tid >> 5, c = tid & 31;
    const float* st = (s == 0) ? stx : (s == 1) ? stri : (s == 2) ? stli : strli;
    float inv = (s == 0) ? (1.f / NTOT) : (s == 1) ? (1.f / NLEFT) : (1.f / NRIGHT);
    float m = st[c] * inv;
    float v = st[32 + c] * inv - m * m;
    m4[tid] = m;
    s4[tid] = rsqrtf(fmaxf(v, 0.f) + BNEPS);
  }
  if (tid < N) { ldsS[tid] = 0.f; ldsQ[tid] = 0.f; }

  int lane = tid & 63;
  int wv   = tid >> 6;
  int lr   = lane & 15;
  int lk   = (lane >> 4) * 8;
  int lj4  = (lane >> 4) * 4;
  int rowbase = wv * 32;

  float sc[CT], sq[CT];
#pragma unroll
  for (int c = 0; c < CT; c++) { sc[c] = 0.f; sq[c] = 0.f; }

  const int M = NTOT;
  int tiles = (M + ROWS - 1) / ROWS;
  for (int t = blockIdx.x; t < tiles; t += gridDim.x) {
    int r0 = t * ROWS;
    __syncthreads();
    for (int i = tid * 8; i < ROWS * K; i += 2048) {
      int r = i / K, c = i - r * K;
      int row = r0 + r;
      bfrag8 v = {0, 0, 0, 0, 0, 0, 0, 0};
      if (row < M) {
        int cb = c >> 5, cc = c & 31;
        const unsigned short* srcp;
        int set, srow;
        if (row < NLEFT) {
          if (cb == 1) { srcp = ri;  set = 1; srow = row; }
          else         { srcp = x32; set = 0; srow = row; }
        } else {
          int rr = row - NLEFT;
          if (cb <= 1)      { srcp = x32; set = 0; srow = row; }
          else if (cb == 2) { srcp = li;  set = 2; srow = rr; }
          else              { srcp = rli; set = 3; srow = rr; }
        }
        v = *reinterpret_cast<const bfrag8*>(srcp + (size_t)srow * 32 + cc);
        const float* mm_ = &m4[set * 32 + cc];
        const float* ss_ = &s4[set * 32 + cc];
#pragma unroll
        for (int j = 0; j < 8; j++) {
          float f = bf2f((unsigned short)v[j]);
          f = fmaxf((f - mm_[j]) * ss_[j], 0.f);
          v[j] = (short)f2bf(f);
        }
      }
      *reinterpret_cast<bfrag8*>(&xl[r * LDX + c]) = v;
    }
    __syncthreads();

    facc4 acc[RT][CT];
#pragma unroll
    for (int rt = 0; rt < RT; rt++)
#pragma unroll
      for (int ct = 0; ct < CT; ct++) acc[rt][ct] = (facc4){0.f, 0.f, 0.f, 0.f};

#pragma unroll
    for (int kt = 0; kt < K / 32; kt++) {
      bfrag8 a[RT], b[CT];
#pragma unroll
      for (int rt = 0; rt < RT; rt++)
        a[rt] = *reinterpret_cast<const bfrag8*>(&xl[(rowbase + rt * 16 + lr) * LDX + kt * 32 + lk]);
#pragma unroll
      for (int ct = 0; ct < CT; ct++)
        b[ct] = *reinterpret_cast<const bfrag8*>(&wl[(ct * 16 + lr) * LDX + kt * 32 + lk]);
#pragma unroll
      for (int rt = 0; rt < RT; rt++)
#pragma unroll
        for (int ct = 0; ct < CT; ct++)
          acc[rt][ct] = __builtin_amdgcn_mfma_f32_16x16x32_bf16(a[rt], b[ct], acc[rt][ct], 0, 0, 0);
    }

#pragma unroll
    for (int rt = 0; rt < RT; rt++) {
#pragma unroll
      for (int ct = 0; ct < CT; ct++) {
        int col = ct * 16 + lr;
        float bcol = bl[col];
#pragma unroll
        for (int j = 0; j < 4; j++) {
          int row = r0 + rowbase + rt * 16 + lj4 + j;
          if (row < M) {
            float v = acc[rt][ct][j] + bcol;
            Y[(size_t)row * N + col] = f2bf(v);
            sc[ct] += v; sq[ct] += v * v;
          }
        }
      }
    }
  }

  __syncthreads();
#pragma unroll
  for (int ct = 0; ct < CT; ct++) {
    atomicAdd(&ldsS[ct * 16 + lr], sc[ct]);
    atomicAdd(&ldsQ[ct * 16 + lr], sq[ct]);
  }
  __syncthreads();
  if (tid < N) {
    atomicAdd(&st_out[tid], ldsS[tid]);
    atomicAdd(&st_out[N + tid], ldsQ[tid]);
  }
}

// ---------------- final normalize + relu + residual add (+bf16 mirror refresh) ----------------

__global__ __launch_bounds__(256) void norm_add_kernel(const unsigned short* __restrict__ X, int M,
                                                       const float* __restrict__ st,
                                                       float* __restrict__ D,
                                                       unsigned short* __restrict__ Dbf) {
  __shared__ float mean[64], scal[64];
  if (threadIdx.x < 64) {
    float m = st[threadIdx.x] / (float)M;
    float v = st[64 + threadIdx.x] / (float)M - m * m;
    mean[threadIdx.x] = m;
    scal[threadIdx.x] = rsqrtf(fmaxf(v, 0.f) + BNEPS);
  }
  __syncthreads();
  size_t ngrp = (size_t)M * 64 / 8;
  for (size_t i = (size_t)blockIdx.x * 256 + threadIdx.x; i < ngrp;
       i += (size_t)gridDim.x * 256) {
    size_t base = i * 8;
    int c = (int)(base & 63);
    bfrag8 xv = *reinterpret_cast<const bfrag8*>(&X[base]);
    float4 d0 = *reinterpret_cast<float4*>(&D[base]);
    float4 d1 = *reinterpret_cast<float4*>(&D[base + 4]);
    float o[8];
#pragma unroll
    for (int j = 0; j < 8; j++) {
      float y = (bf2f((unsigned short)xv[j]) - mean[c + j]) * scal[c + j];
      y = y > 0.f ? y : 0.f;
      float dv = (j < 4) ? (&d0.x)[j] : (&d1.x)[j - 4];
      o[j] = dv + y;
    }
    d0 = make_float4(o[0], o[1], o[2], o[3]);
    d1 = make_float4(o[4], o[5], o[6], o[7]);
    *reinterpret_cast<float4*>(&D[base])     = d0;
    *reinterpret_cast<float4*>(&D[base + 4]) = d1;
    bfrag8 pb;
#pragma unroll
    for (int j = 0; j < 8; j++) pb[j] = (short)f2bf(o[j]);
    *reinterpret_cast<bfrag8*>(&Dbf[base]) = pb;
  }
}

// ---------------- orchestration ----------------

static inline int tiles_of(int M, int R) { return (M + R - 1) / R; }

extern "C" void kernel_launch(void* const* d_in, const int* in_sizes, int n_in,
                              void* d_out, int out_size, void* d_ws, size_t ws_size,
                              hipStream_t stream) {
  const float* xs      = (const float*)d_in[0];
  const float* nn1_w1  = (const float*)d_in[1];
  const float* nn1_b1  = (const float*)d_in[2];
  const float* nn1_w2  = (const float*)d_in[3];
  const float* nn1_b2  = (const float*)d_in[4];
  const float* nn2_w1  = (const float*)d_in[5];
  const float* nn2_b1  = (const float*)d_in[6];
  const float* nn2_w2  = (const float*)d_in[7];
  const float* nn2_b2  = (const float*)d_in[8];
  const float* l1_w    = (const float*)d_in[9];
  const float* l1_b    = (const float*)d_in[10];
  const float* l2_w    = (const float*)d_in[11];
  const float* l2_b    = (const float*)d_in[12];
  const float* l3_w    = (const float*)d_in[13];
  const float* l3_b    = (const float*)d_in[14];
  const float* l4_w    = (const float*)d_in[15];
  const float* l4_b    = (const float*)d_in[16];
  const float* out_w1  = (const float*)d_in[17];
  const float* out_b1  = (const float*)d_in[18];
  const float* out_w2  = (const float*)d_in[19];
  const float* out_b2  = (const float*)d_in[20];
  const int*   src     = (const int*)d_in[21];
  const int*   dst     = (const int*)d_in[22];

  float* out = (float*)d_out;

  unsigned short* u     = (unsigned short*)d_ws;
  unsigned short* t1    = u;                                   // 200000*64
  unsigned short* rin   = t1    + (size_t)NTOT * 64;           // 100000*64
  unsigned short* x32   = rin   + (size_t)NLEFT * 64;          // 200000*32
  unsigned short* ri32  = x32   + (size_t)NTOT * 32;           // 100000*32
  unsigned short* li32  = ri32  + (size_t)NLEFT * 32;
  unsigned short* rli32 = li32  + (size_t)NRIGHT * 32;
  unsigned short* outbf = rli32 + (size_t)NRIGHT * 32;         // 200000*64
  float* stats = (float*)(outbf + (size_t)NTOT * 64);          // 20*128
  int*   cntL  = (int*)(stats + 20 * 128);
  int*   cntR  = cntL + NLEFT;
  int*   oL    = cntR + NRIGHT;
  int*   oR    = oL + (NLEFT + 1);
  int*   curL  = oR + (NRIGHT + 1);
  int*   curR  = curL + NLEFT;
  int*   part  = curR + NRIGHT;
  int*   adjL  = part + 1024;
  int*   adjR  = adjL + NEDGE;

  dim3 B(256);
  const int NB1 = (NLEFT + 255) / 256;
  const float invL = 1.f / NLEFT, invT = 1.f / NTOT;
  const int GSEG = tiles_of(NLEFT, 32);   // 3125 blocks

  init_kernel<<<2048, B, 0, stream>>>(xs, out, outbf, stats, 20 * 128, cntL, cntR, curL, curR);
  count_kernel<<<2048, B, 0, stream>>>(src, dst, cntL, cntR);
  scan1_kernel<<<NB1, B, 0, stream>>>(cntL, NLEFT, part);
  scan2_kernel<<<1, 1024, 0, stream>>>(part, NB1);
  scan3_kernel<<<NB1, B, 0, stream>>>(cntL, NLEFT, part, oL);
  scan1_kernel<<<NB1, B, 0, stream>>>(cntR, NRIGHT, part);
  scan2_kernel<<<1, 1024, 0, stream>>>(part, NB1);
  scan3_kernel<<<NB1, B, 0, stream>>>(cntR, NRIGHT, part, oR);
  fill_kernel<<<2048, B, 0, stream>>>(src, dst, oL, oR, curL, curR, adjL, adjR);

  for (int l = 0; l < 2; l++) {
    const float* p_nn1_w1 = nn1_w1 + (size_t)l * 64 * 64;
    const float* p_nn1_b1 = nn1_b1 + (size_t)l * 64;
    const float* p_nn1_w2 = nn1_w2 + (size_t)l * 64 * 64;
    const float* p_nn1_b2 = nn1_b2 + (size_t)l * 64;
    const float* p_nn2_w1 = nn2_w1 + (size_t)l * 192 * 64;
    const float* p_nn2_b1 = nn2_b1 + (size_t)l * 64;
    const float* p_nn2_w2 = nn2_w2 + (size_t)l * 64 * 64;
    const float* p_nn2_b2 = nn2_b2 + (size_t)l * 64;
    const float* p_l1_w   = l1_w   + (size_t)l * 64 * 32;
    const float* p_l1_b   = l1_b   + (size_t)l * 32;
    const float* p_l2_w   = l2_w   + (size_t)l * 192 * 32;
    const float* p_l2_b   = l2_b   + (size_t)l * 32;
    const float* p_l3_w   = l3_w   + (size_t)l * 192 * 32;
    const float* p_l3_b   = l3_b   + (size_t)l * 32;
    const float* p_l4_w   = l4_w   + (size_t)l * 192 * 32;
    const float* p_l4_b   = l4_b   + (size_t)l * 32;
    const float* p_out_w1 = out_w1 + (size_t)l * 128 * 64;
    const float* p_out_b1 = out_b1 + (size_t)l * 64;
    const float* p_out_w2 = out_w2 + (size_t)l * 64 * 64;
    const float* p_out_b2 = out_b2 + (size_t)l * 64;

    float* S = stats + (size_t)l * 10 * 128;
    auto ST = [&](int s) { return S + (size_t)s * 128; };

    // a+b+c1) gather right_info; ri=l2(info)->s0; rin=nn2_w1(info)->s1 (fused)
    gmm_mfma<32, 64, false><<<GSEG, 512, 0, stream>>>(
        outbf + (size_t)NLEFT * 64, oL, adjL, NLEFT, nullptr, 0.f,
        p_l2_w, p_l2_b, ri32, ST(0),
        p_nn2_w1, p_nn2_b1, rin, ST(1));
    // c2) rin = nn2_w2(bnrelu(rin,s1)); s2
    mm_mfma<64, 64, 128, true><<<tiles_of(NLEFT, 128), B, 0, stream>>>(
        rin, p_nn2_w2, p_nn2_b2, rin, NLEFT, ST(2), ST(1), invL);
    // d+e) gather rl_info from bnrelu(rin,s2); rli=l4(info)->s3 (fused)
    gmm_mfma<32, 0, true><<<GSEG, 512, 0, stream>>>(
        rin, oR, adjR, NRIGHT, ST(2), invL,
        p_l4_w, p_l4_b, rli32, ST(3),
        nullptr, nullptr, nullptr, nullptr);
    // f1+i) t1 = nn1_w1(outbf)->s4 ; x32 = l1(outbf)->s7 (fused dual output)
    mm2_mfma<<<tiles_of(NTOT, 128), B, 0, stream>>>(
        outbf, p_nn1_w1, p_nn1_b1, t1, ST(4),
        p_l1_w, p_l1_b, x32, ST(7), NTOT);
    // f2) t1 = nn1_w2(bnrelu(t1,s4)); s5
    mm_mfma<64, 64, 128, true><<<tiles_of(NTOT, 128), B, 0, stream>>>(
        t1, p_nn1_w2, p_nn1_b2, t1, NTOT, ST(5), ST(4), invT);
    // g+h) gather left_info from bnrelu(t1,s5); li=l3(info)->s6 (fused)
    gmm_mfma<32, 0, true><<<GSEG, 512, 0, stream>>>(
        t1, oR, adjR, NRIGHT, ST(5), invT,
        p_l3_w, p_l3_b, li32, ST(6),
        nullptr, nullptr, nullptr, nullptr);
    // j1) t1 = out_w1(h virtual concat); s8
    mmh_mfma<<<tiles_of(NTOT, 128), B, 0, stream>>>(
        x32, ri32, li32, rli32, ST(7), ST(0), ST(6), ST(3),
        p_out_w1, p_out_b1, t1, ST(8));
    // j2) t1 = out_w2(bnrelu(t1,s8)); s9
    mm_mfma<64, 64, 128, true><<<tiles_of(NTOT, 128), B, 0, stream>>>(
        t1, p_out_w2, p_out_b2, t1, NTOT, ST(9), ST(8), invT);
    // j3) out += relu(bn(t1,s9)); refresh bf16 mirror
    norm_add_kernel<<<2048, B, 0, stream>>>(t1, NTOT, ST(9), out, outbf);
  }
}

// Round 9
// 1289.529 us; speedup vs baseline: 3.9598x; 1.1601x over previous
//
#include <hip/hip_runtime.h>

#define NLEFT  100000
#define NRIGHT 100000
#define NTOT   200000
#define NEDGE  1000000
#define HD     64
#define BNEPS  1e-5f

typedef __attribute__((ext_vector_type(8))) short bfrag8;
typedef __attribute__((ext_vector_type(4))) float facc4;

__device__ inline unsigned short f2bf(float f) {
  unsigned u = __float_as_uint(f);
  u = u + 0x7fffu + ((u >> 16) & 1u);   // RNE
  return (unsigned short)(u >> 16);
}
__device__ inline float bf2f(unsigned short u) {
  return __uint_as_float((unsigned)u << 16);
}

// ---- converted-weight region layout (ushorts, per layer; see wconv_kernel) ----
#define WC_G1    0        // [96][192]  l2^T rows 0-31, nn2_w1^T rows 32-95
#define WC_G2    18432    // [32][192]  l4^T
#define WC_G3    24576    // [32][192]  l3^T
#define WC_NN2W2 30720    // [64][64]
#define WC_M2    34816    // [96][64]   nn1_w1^T rows 0-63, l1^T rows 64-95
#define WC_NN1W2 40960    // [64][64]
#define WC_OUTW1 45056    // [64][128]
#define WC_OUTW2 53248    // [64][64]
#define WC_PER_L 57344

// ---------------- init: d_out = xs (+bf16 mirror), zero stats/cursors ----------------

__global__ __launch_bounds__(256) void init_kernel(const float* __restrict__ xs,
                                                   float* __restrict__ out,
                                                   unsigned short* __restrict__ outbf,
                                                   float* __restrict__ st, int nst,
                                                   int* __restrict__ cl, int* __restrict__ cr,
                                                   int* __restrict__ curl, int* __restrict__ curr) {
  size_t ng = (size_t)NTOT * HD / 4;
  for (size_t i = (size_t)blockIdx.x * blockDim.x + threadIdx.x; i < ng;
       i += (size_t)gridDim.x * blockDim.x) {
    float4 v = reinterpret_cast<const float4*>(xs)[i];
    reinterpret_cast<float4*>(out)[i] = v;
    ushort4 p;
    p.x = f2bf(v.x); p.y = f2bf(v.y); p.z = f2bf(v.z); p.w = f2bf(v.w);
    reinterpret_cast<ushort4*>(outbf)[i] = p;
  }
  for (int i = blockIdx.x * blockDim.x + threadIdx.x; i < NLEFT;
       i += gridDim.x * blockDim.x) {
    cl[i] = 0; curl[i] = 0; cr[i] = 0; curr[i] = 0;
    if (i < nst) st[i] = 0.f;
  }
}

__global__ __launch_bounds__(256) void count_kernel(const int* __restrict__ src,
                                                    const int* __restrict__ dst,
                                                    int* __restrict__ cl, int* __restrict__ cr) {
  for (int e = blockIdx.x * blockDim.x + threadIdx.x; e < NEDGE;
       e += gridDim.x * blockDim.x) {
    atomicAdd(&cl[src[e]], 1);
    atomicAdd(&cr[dst[e]], 1);
  }
}

// ---------------- weight convert+transpose: fp32 [K][N] -> bf16 [N][K] ----------------

__global__ __launch_bounds__(256) void wconv_kernel(const float* __restrict__ l2w,
                                                    const float* __restrict__ nn2w1,
                                                    const float* __restrict__ l4w,
                                                    const float* __restrict__ l3w,
                                                    const float* __restrict__ nn2w2,
                                                    const float* __restrict__ nn1w1,
                                                    const float* __restrict__ l1w,
                                                    const float* __restrict__ nn1w2,
                                                    const float* __restrict__ outw1,
                                                    const float* __restrict__ outw2,
                                                    unsigned short* __restrict__ dst) {
  for (int idx = blockIdx.x * 256 + threadIdx.x; idx < 2 * WC_PER_L;
       idx += gridDim.x * 256) {
    int l = idx / WC_PER_L;
    int r = idx - l * WC_PER_L;
    const float* src; int N, n, k;
    if (r < WC_G2) {                       // [96][192]
      n = r / 192; k = r - n * 192;
      if (n < 32) { src = l2w + (size_t)l * 192 * 32; N = 32; }
      else        { src = nn2w1 + (size_t)l * 192 * 64; N = 64; n -= 32; }
    } else if (r < WC_G3) {
      int rr = r - WC_G2; n = rr / 192; k = rr - n * 192;
      src = l4w + (size_t)l * 192 * 32; N = 32;
    } else if (r < WC_NN2W2) {
      int rr = r - WC_G3; n = rr / 192; k = rr - n * 192;
      src = l3w + (size_t)l * 192 * 32; N = 32;
    } else if (r < WC_M2) {
      int rr = r - WC_NN2W2; n = rr / 64; k = rr - n * 64;
      src = nn2w2 + (size_t)l * 64 * 64; N = 64;
    } else if (r < WC_NN1W2) {
      int rr = r - WC_M2; n = rr / 64; k = rr - n * 64;
      if (n < 64) { src = nn1w1 + (size_t)l * 64 * 64; N = 64; }
      else        { src = l1w + (size_t)l * 64 * 32; N = 32; n -= 64; }
    } else if (r < WC_OUTW1) {
      int rr = r - WC_NN1W2; n = rr / 64; k = rr - n * 64;
      src = nn1w2 + (size_t)l * 64 * 64; N = 64;
    } else if (r < WC_OUTW2) {
      int rr = r - WC_OUTW1; n = rr / 128; k = rr - n * 128;
      src = outw1 + (size_t)l * 128 * 64; N = 64;
    } else {
      int rr = r - WC_OUTW2; n = rr / 64; k = rr - n * 64;
      src = outw2 + (size_t)l * 64 * 64; N = 64;
    }
    dst[idx] = f2bf(src[(size_t)k * N + n]);
  }
}

// ---------------- exclusive scan (counts -> offsets) ----------------

__global__ __launch_bounds__(256) void scan1_kernel(const int* __restrict__ cnt, int n,
                                                    int* __restrict__ partial) {
  __shared__ int tmp[256];
  int i = blockIdx.x * 256 + threadIdx.x;
  tmp[threadIdx.x] = (i < n) ? cnt[i] : 0;
  __syncthreads();
  for (int s = 128; s > 0; s >>= 1) {
    if (threadIdx.x < s) tmp[threadIdx.x] += tmp[threadIdx.x + s];
    __syncthreads();
  }
  if (threadIdx.x == 0) partial[blockIdx.x] = tmp[0];
}

__global__ __launch_bounds__(1024) void scan2_kernel(int* __restrict__ partial, int nb) {
  __shared__ int tmp[1024];
  int t = threadIdx.x;
  int v = (t < nb) ? partial[t] : 0;
  tmp[t] = v;
  __syncthreads();
  for (int off = 1; off < 1024; off <<= 1) {
    int x = tmp[t];
    int add = (t >= off) ? tmp[t - off] : 0;
    __syncthreads();
    tmp[t] = x + add;
    __syncthreads();
  }
  if (t < nb) partial[t] = tmp[t] - v;
}

__global__ __launch_bounds__(256) void scan3_kernel(const int* __restrict__ cnt, int n,
                                                    const int* __restrict__ partial,
                                                    int* __restrict__ offs) {
  __shared__ int tmp[256];
  int t = threadIdx.x;
  int i = blockIdx.x * 256 + t;
  int v = (i < n) ? cnt[i] : 0;
  tmp[t] = v;
  __syncthreads();
  for (int off = 1; off < 256; off <<= 1) {
    int x = tmp[t];
    int add = (t >= off) ? tmp[t - off] : 0;
    __syncthreads();
    tmp[t] = x + add;
    __syncthreads();
  }
  if (i < n) offs[i] = tmp[t] - v + partial[blockIdx.x];
  if (i == 0) offs[n] = NEDGE;
}

// ---------------- CSR fill ----------------

__global__ __launch_bounds__(256) void fill_kernel(const int* __restrict__ src,
                                                   const int* __restrict__ dst,
                                                   const int* __restrict__ oL,
                                                   const int* __restrict__ oR,
                                                   int* __restrict__ curL, int* __restrict__ curR,
                                                   int* __restrict__ adjL, int* __restrict__ adjR) {
  for (int e = blockIdx.x * blockDim.x + threadIdx.x; e < NEDGE;
       e += gridDim.x * blockDim.x) {
    int s = src[e], d = dst[e];
    int p = atomicAdd(&curL[s], 1);
    adjL[oL[s] + p] = d;
    int q = atomicAdd(&curR[d], 1);
    adjR[oR[d] + q] = s;
  }
}

// ---------------- fused gather + MFMA (persistent, pre-converted weights) ----------------
// Block = 512 threads (8 waves); 32-segment tiles, grid-stride over tiles.
// Weights staged once per block from bf16 [NT][192] via vector loads.

template <int N1, int N2, bool SRCNORM>
__global__ __launch_bounds__(512) void gmm_mfma(const unsigned short* __restrict__ mat,
                                                const int* __restrict__ offs,
                                                const int* __restrict__ adj,
                                                int nseg,
                                                const float* __restrict__ st_src, float inv_src,
                                                const unsigned short* __restrict__ Wbf,
                                                const float* __restrict__ B1,
                                                unsigned short* __restrict__ Y1,
                                                float* __restrict__ st1,
                                                const float* __restrict__ B2,
                                                unsigned short* __restrict__ Y2,
                                                float* __restrict__ st2) {
  constexpr int K    = 192;
  constexpr int LDX  = 200;
  constexpr int SEGS = 32;
  constexpr int NT   = N1 + N2;
  constexpr int CTT  = NT / 16;
  constexpr int CTW  = (CTT >= 6) ? 2 : 1;
  constexpr int NGRP = CTT / CTW;
  constexpr int NWM  = 2 * NGRP;              // MFMA-active waves (4 or 6)
  __shared__ alignas(16) unsigned short xl[SEGS * LDX];
  __shared__ alignas(16) unsigned short wl[NT * LDX];
  __shared__ float bl[NT];
  __shared__ float ldsS[NT], ldsQ[NT];

  int tid = threadIdx.x;
  // vector weight staging from pre-converted bf16 [NT][192]
  for (int i = tid; i < NT * 24; i += 512) {
    int n = i / 24, kk = (i - n * 24) * 8;
    *reinterpret_cast<bfrag8*>(&wl[n * LDX + kk]) =
        *reinterpret_cast<const bfrag8*>(&Wbf[n * 192 + kk]);
  }
  for (int i = tid; i < N1; i += 512) bl[i] = B1[i];
  if constexpr (N2 > 0)
    for (int i = tid; i < N2; i += 512) bl[N1 + i] = B2[i];
  if (tid < NT) { ldsS[tid] = 0.f; ldsQ[tid] = 0.f; }

  int wave = tid >> 6;
  int lane = tid & 63;
  int half = lane >> 5;
  int c0   = (lane & 31) * 2;

  float nm0 = 0.f, nm1 = 0.f, ns0 = 1.f, ns1 = 1.f;
  if (SRCNORM) {
    float m0 = st_src[c0] * inv_src, m1 = st_src[c0 + 1] * inv_src;
    float v0 = st_src[64 + c0] * inv_src - m0 * m0;
    float v1 = st_src[64 + c0 + 1] * inv_src - m1 * m1;
    nm0 = m0; nm1 = m1;
    ns0 = rsqrtf(fmaxf(v0, 0.f) + BNEPS);
    ns1 = rsqrtf(fmaxf(v1, 0.f) + BNEPS);
  }

  int lr  = lane & 15;
  int lk  = (lane >> 4) * 8;
  int lj4 = (lane >> 4) * 4;
  int rowtile = wave & 1;
  int colgrp  = wave >> 1;
  int rowbase = rowtile * 16;

  float sacc[CTW], qacc[CTW];
#pragma unroll
  for (int ct = 0; ct < CTW; ct++) { sacc[ct] = 0.f; qacc[ct] = 0.f; }

  int tiles = (nseg + SEGS - 1) / SEGS;
  for (int t = blockIdx.x; t < tiles; t += gridDim.x) {
    __syncthreads();   // xl free (prev tile's MFMA done)
    // -------- gather: 4 segments per wave, 8-deep batched loads --------
    int segbase = t * SEGS + wave * 4;
    for (int s = 0; s < 4; s++) {
      int seg = segbase + s;
      int row = wave * 4 + s;
      float s0 = 0.f, s1 = 0.f, m0 = -INFINITY, m1 = -INFINITY;
      int cdeg = 0;
      if (seg < nseg) {
        int b = offs[seg], e = offs[seg + 1];
        cdeg = e - b;
        for (int jb = b + half; jb < e; jb += 16) {
          unsigned pk[8];
#pragma unroll
          for (int u = 0; u < 8; u++) {
            int j = jb + 2 * u;
            pk[u] = 0;
            if (j < e) {
              int g = adj[j];
              pk[u] = *reinterpret_cast<const unsigned*>(&mat[(size_t)g * HD + c0]);
            }
          }
#pragma unroll
          for (int u = 0; u < 8; u++) {
            int j = jb + 2 * u;
            if (j < e) {
              float v0 = __uint_as_float(pk[u] << 16);
              float v1 = __uint_as_float(pk[u] & 0xffff0000u);
              if (SRCNORM) {
                v0 = fmaxf((v0 - nm0) * ns0, 0.f);
                v1 = fmaxf((v1 - nm1) * ns1, 0.f);
              }
              s0 += v0; s1 += v1;
              m0 = fmaxf(m0, v0); m1 = fmaxf(m1, v1);
            }
          }
        }
        s0 += __shfl_xor(s0, 32);
        s1 += __shfl_xor(s1, 32);
        m0 = fmaxf(m0, __shfl_xor(m0, 32));
        m1 = fmaxf(m1, __shfl_xor(m1, 32));
      }
      float inv = 1.f / fmaxf((float)cdeg, 1.f);
      if (cdeg == 0) { m0 = 0.f; m1 = 0.f; s0 = 0.f; s1 = 0.f; }
      if (half == 0) {
        unsigned sp = (unsigned)f2bf(s0) | ((unsigned)f2bf(s1) << 16);
        unsigned mp = (unsigned)f2bf(m0) | ((unsigned)f2bf(m1) << 16);
        *reinterpret_cast<unsigned*>(&xl[row * LDX + c0])       = sp;
        *reinterpret_cast<unsigned*>(&xl[row * LDX + 128 + c0]) = mp;
      } else {
        unsigned ap = (unsigned)f2bf(s0 * inv) | ((unsigned)f2bf(s1 * inv) << 16);
        *reinterpret_cast<unsigned*>(&xl[row * LDX + 64 + c0]) = ap;
      }
    }
    __syncthreads();

    // -------- MFMA (waves 0..NWM-1) --------
    if (wave < NWM) {
      facc4 acc[CTW];
#pragma unroll
      for (int ct = 0; ct < CTW; ct++) acc[ct] = (facc4){0.f, 0.f, 0.f, 0.f};
#pragma unroll
      for (int kt = 0; kt < K / 32; kt++) {
        bfrag8 a = *reinterpret_cast<const bfrag8*>(&xl[(rowbase + lr) * LDX + kt * 32 + lk]);
#pragma unroll
        for (int ct = 0; ct < CTW; ct++) {
          bfrag8 b = *reinterpret_cast<const bfrag8*>(
              &wl[((colgrp * CTW + ct) * 16 + lr) * LDX + kt * 32 + lk]);
          acc[ct] = __builtin_amdgcn_mfma_f32_16x16x32_bf16(a, b, acc[ct], 0, 0, 0);
        }
      }
#pragma unroll
      for (int ct = 0; ct < CTW; ct++) {
        int col = (colgrp * CTW + ct) * 16 + lr;
        float bias = bl[col];
#pragma unroll
        for (int j = 0; j < 4; j++) {
          int grow = t * SEGS + rowbase + lj4 + j;
          if (grow < nseg) {
            float v = acc[ct][j] + bias;
            if (col < N1) Y1[(size_t)grow * N1 + col] = f2bf(v);
            else          Y2[(size_t)grow * N2 + (col - N1)] = f2bf(v);
            sacc[ct] += v; qacc[ct] += v * v;
          }
        }
      }
    }
  }

  __syncthreads();
  if (wave < NWM) {
#pragma unroll
    for (int ct = 0; ct < CTW; ct++) {
      int col = (colgrp * CTW + ct) * 16 + lr;
      atomicAdd(&ldsS[col], sacc[ct]);
      atomicAdd(&ldsQ[col], qacc[ct]);
    }
  }
  __syncthreads();
  if (tid < NT) {
    if (tid < N1) {
      atomicAdd(&st1[tid], ldsS[tid]);
      atomicAdd(&st1[N1 + tid], ldsQ[tid]);
    } else {
      atomicAdd(&st2[tid - N1], ldsS[tid]);
      atomicAdd(&st2[N2 + (tid - N1)], ldsQ[tid]);
    }
  }
}

// ---------------- MFMA matmul (pre-converted weights): Y = (bnrelu?)(X) @ W + B ----------------

template <int K, int N, int ROWS, bool NIN>
__global__ __launch_bounds__(256) void mm_mfma(const unsigned short* __restrict__ X,
                                               const unsigned short* __restrict__ Wbf,
                                               const float* __restrict__ Bv,
                                               unsigned short* __restrict__ Y, int M,
                                               float* __restrict__ st_out,
                                               const float* __restrict__ st_in, float inv_m) {
  constexpr int LDX = K + 8;
  constexpr int RT  = ROWS / 64;
  constexpr int CT  = N / 16;
  constexpr int KV  = K / 8;
  __shared__ alignas(16) unsigned short xl[ROWS * LDX];
  __shared__ alignas(16) unsigned short wl[N * LDX];
  __shared__ float bl[N];
  __shared__ float nmean[K], nscal[K];
  __shared__ float ldsS[N], ldsQ[N];

  int tid = threadIdx.x;
  for (int i = tid; i < N * KV; i += 256) {
    int n = i / KV, kk = (i - n * KV) * 8;
    *reinterpret_cast<bfrag8*>(&wl[n * LDX + kk]) =
        *reinterpret_cast<const bfrag8*>(&Wbf[n * K + kk]);
  }
  for (int i = tid; i < N; i += 256) bl[i] = Bv[i];
  if (NIN) {
    for (int i = tid; i < K; i += 256) {
      float m = st_in[i] * inv_m;
      float v = st_in[K + i] * inv_m - m * m;
      nmean[i] = m;
      nscal[i] = rsqrtf(fmaxf(v, 0.f) + BNEPS);
    }
  }
  if (tid < N) { ldsS[tid] = 0.f; ldsQ[tid] = 0.f; }

  int lane = tid & 63;
  int wv   = tid >> 6;
  int lr   = lane & 15;
  int lk   = (lane >> 4) * 8;
  int lj4  = (lane >> 4) * 4;
  int rowbase = wv * (RT * 16);

  float sc[CT], sq[CT];
#pragma unroll
  for (int c = 0; c < CT; c++) { sc[c] = 0.f; sq[c] = 0.f; }

  int tiles = (M + ROWS - 1) / ROWS;
  for (int t = blockIdx.x; t < tiles; t += gridDim.x) {
    int r0 = t * ROWS;
    __syncthreads();
    for (int i = tid * 8; i < ROWS * K; i += 2048) {
      int r = i / K, c = i - r * K;
      int row = r0 + r;
      bfrag8 v = {0, 0, 0, 0, 0, 0, 0, 0};
      if (row < M) {
        v = *reinterpret_cast<const bfrag8*>(X + (size_t)row * K + c);
        if (NIN) {
#pragma unroll
          for (int j = 0; j < 8; j++) {
            float f = bf2f((unsigned short)v[j]);
            f = fmaxf((f - nmean[c + j]) * nscal[c + j], 0.f);
            v[j] = (short)f2bf(f);
          }
        }
      }
      *reinterpret_cast<bfrag8*>(&xl[r * LDX + c]) = v;
    }
    __syncthreads();

    facc4 acc[RT][CT];
#pragma unroll
    for (int rt = 0; rt < RT; rt++)
#pragma unroll
      for (int ct = 0; ct < CT; ct++) acc[rt][ct] = (facc4){0.f, 0.f, 0.f, 0.f};

#pragma unroll
    for (int kt = 0; kt < K / 32; kt++) {
      bfrag8 a[RT], b[CT];
#pragma unroll
      for (int rt = 0; rt < RT; rt++)
        a[rt] = *reinterpret_cast<const bfrag8*>(&xl[(rowbase + rt * 16 + lr) * LDX + kt * 32 + lk]);
#pragma unroll
      for (int ct = 0; ct < CT; ct++)
        b[ct] = *reinterpret_cast<const bfrag8*>(&wl[(ct * 16 + lr) * LDX + kt * 32 + lk]);
#pragma unroll
      for (int rt = 0; rt < RT; rt++)
#pragma unroll
        for (int ct = 0; ct < CT; ct++)
          acc[rt][ct] = __builtin_amdgcn_mfma_f32_16x16x32_bf16(a[rt], b[ct], acc[rt][ct], 0, 0, 0);
    }

#pragma unroll
    for (int rt = 0; rt < RT; rt++) {
#pragma unroll
      for (int ct = 0; ct < CT; ct++) {
        int col = ct * 16 + lr;
        float bcol = bl[col];
#pragma unroll
        for (int j = 0; j < 4; j++) {
          int row = r0 + rowbase + rt * 16 + lj4 + j;
          if (row < M) {
            float v = acc[rt][ct][j] + bcol;
            Y[(size_t)row * N + col] = f2bf(v);
            sc[ct] += v; sq[ct] += v * v;
          }
        }
      }
    }
  }

  __syncthreads();
#pragma unroll
  for (int ct = 0; ct < CT; ct++) {
    atomicAdd(&ldsS[ct * 16 + lr], sc[ct]);
    atomicAdd(&ldsQ[ct * 16 + lr], sq[ct]);
  }
  __syncthreads();
  if (tid < N) {
    atomicAdd(&st_out[tid], ldsS[tid]);
    atomicAdd(&st_out[N + tid], ldsQ[tid]);
  }
}

// ---------------- dual-output MFMA matmul (pre-converted combined [96][64] weights) ----------------

__global__ __launch_bounds__(256) void mm2_mfma(const unsigned short* __restrict__ X,
                                                const unsigned short* __restrict__ Wbf,
                                                const float* __restrict__ B1,
                                                unsigned short* __restrict__ Y1,
                                                float* __restrict__ st1,
                                                const float* __restrict__ B2,
                                                unsigned short* __restrict__ Y2,
                                                float* __restrict__ st2,
                                                int M) {
  constexpr int K = 64, N1 = 64, N2 = 32, NT = 96, ROWS = 128;
  constexpr int LDX = K + 8, RT = 2, CT = 6, KV = K / 8;
  __shared__ alignas(16) unsigned short xl[ROWS * LDX];
  __shared__ alignas(16) unsigned short wl[NT * LDX];
  __shared__ float bl[NT];
  __shared__ float ldsS[NT], ldsQ[NT];

  int tid = threadIdx.x;
  for (int i = tid; i < NT * KV; i += 256) {
    int n = i / KV, kk = (i - n * KV) * 8;
    *reinterpret_cast<bfrag8*>(&wl[n * LDX + kk]) =
        *reinterpret_cast<const bfrag8*>(&Wbf[n * K + kk]);
  }
  for (int i = tid; i < N1; i += 256) bl[i] = B1[i];
  for (int i = tid; i < N2; i += 256) bl[N1 + i] = B2[i];
  if (tid < NT) { ldsS[tid] = 0.f; ldsQ[tid] = 0.f; }

  int lane = tid & 63;
  int wv   = tid >> 6;
  int lr   = lane & 15;
  int lk   = (lane >> 4) * 8;
  int lj4  = (lane >> 4) * 4;
  int rowbase = wv * 32;

  float sc[CT], sq[CT];
#pragma unroll
  for (int c = 0; c < CT; c++) { sc[c] = 0.f; sq[c] = 0.f; }

  int tiles = (M + ROWS - 1) / ROWS;
  for (int t = blockIdx.x; t < tiles; t += gridDim.x) {
    int r0 = t * ROWS;
    __syncthreads();
    for (int i = tid * 8; i < ROWS * K; i += 2048) {
      int r = i / K, c = i - r * K;
      int row = r0 + r;
      bfrag8 v = {0, 0, 0, 0, 0, 0, 0, 0};
      if (row < M) v = *reinterpret_cast<const bfrag8*>(X + (size_t)row * K + c);
      *reinterpret_cast<bfrag8*>(&xl[r * LDX + c]) = v;
    }
    __syncthreads();

    facc4 acc[RT][CT];
#pragma unroll
    for (int rt = 0; rt < RT; rt++)
#pragma unroll
      for (int ct = 0; ct < CT; ct++) acc[rt][ct] = (facc4){0.f, 0.f, 0.f, 0.f};

#pragma unroll
    for (int kt = 0; kt < K / 32; kt++) {
      bfrag8 a[RT], b[CT];
#pragma unroll
      for (int rt = 0; rt < RT; rt++)
        a[rt] = *reinterpret_cast<const bfrag8*>(&xl[(rowbase + rt * 16 + lr) * LDX + kt * 32 + lk]);
#pragma unroll
      for (int ct = 0; ct < CT; ct++)
        b[ct] = *reinterpret_cast<const bfrag8*>(&wl[(ct * 16 + lr) * LDX + kt * 32 + lk]);
#pragma unroll
      for (int rt = 0; rt < RT; rt++)
#pragma unroll
        for (int ct = 0; ct < CT; ct++)
          acc[rt][ct] = __builtin_amdgcn_mfma_f32_16x16x32_bf16(a[rt], b[ct], acc[rt][ct], 0, 0, 0);
    }

#pragma unroll
    for (int rt = 0; rt < RT; rt++) {
#pragma unroll
      for (int ct = 0; ct < CT; ct++) {
        int col = ct * 16 + lr;
        float bcol = bl[col];
#pragma unroll
        for (int j = 0; j < 4; j++) {
          int row = r0 + rowbase + rt * 16 + lj4 + j;
          if (row < M) {
            float v = acc[rt][ct][j] + bcol;
            if (col < N1) Y1[(size_t)row * N1 + col] = f2bf(v);
            else          Y2[(size_t)row * N2 + (col - N1)] = f2bf(v);
            sc[ct] += v; sq[ct] += v * v;
          }
        }
      }
    }
  }

  __syncthreads();
#pragma unroll
  for (int ct = 0; ct < CT; ct++) {
    atomicAdd(&ldsS[ct * 16 + lr], sc[ct]);
    atomicAdd(&ldsQ[ct * 16 + lr], sq[ct]);
  }
  __syncthreads();
  if (tid < NT) {
    if (tid < N1) {
      atomicAdd(&st1[tid], ldsS[tid]);
      atomicAdd(&st1[N1 + tid], ldsQ[tid]);
    } else {
      atomicAdd(&st2[tid - N1], ldsS[tid]);
      atomicAdd(&st2[N2 + (tid - N1)], ldsQ[tid]);
    }
  }
}

// ---------------- MFMA matmul on virtual concat h (K=128,N=64), pre-converted weights ----------------

__global__ __launch_bounds__(256) void mmh_mfma(const unsigned short* __restrict__ x32,
                                                const unsigned short* __restrict__ ri,
                                                const unsigned short* __restrict__ li,
                                                const unsigned short* __restrict__ rli,
                                                const float* __restrict__ stx,
                                                const float* __restrict__ stri,
                                                const float* __restrict__ stli,
                                                const float* __restrict__ strli,
                                                const unsigned short* __restrict__ Wbf,
                                                const float* __restrict__ Bv,
                                                unsigned short* __restrict__ Y,
                                                float* __restrict__ st_out) {
  constexpr int K = 128, N = 64, ROWS = 128, LDX = K + 8, RT = 2, CT = 4, KV = K / 8;
  __shared__ alignas(16) unsigned short xl[ROWS * LDX];
  __shared__ alignas(16) unsigned short wl[N * LDX];
  __shared__ float bl[N];
  __shared__ float m4[4 * 32], s4[4 * 32];
  __shared__ float ldsS[N], ldsQ[N];

  int tid = threadIdx.x;
  for (int i = tid; i < N * KV; i += 256) {
    int n = i / KV, kk = (i - n * KV) * 8;
    *reinterpret_cast<bfrag8*>(&wl[n * LDX + kk]) =
        *reinterpret_cast<const bfrag8*>(&Wbf[n * K + kk]);
  }
  for (int i = tid; i < N; i += 256) bl[i] = Bv[i];
  if (tid < 128) {
    int s = tid >> 5, c = tid & 31;
    const float* st = (s == 0) ? stx : (s == 1) ? stri : (s == 2) ? stli : strli;
    float inv = (s == 0) ? (1.f / NTOT) : (s == 1) ? (1.f / NLEFT) : (1.f / NRIGHT);
    float m = st[c] * inv;
    float v = st[32 + c] * inv - m * m;
    m4[tid] = m;
    s4[tid] = rsqrtf(fmaxf(v, 0.f) + BNEPS);
  }
  if (tid < N) { ldsS[tid] = 0.f; ldsQ[tid] = 0.f; }

  int lane = tid & 63;
  int wv   = tid >> 6;
  int lr   = lane & 15;
  int lk   = (lane >> 4) * 8;
  int lj4  = (lane >> 4) * 4;
  int rowbase = wv * 32;

  float sc[CT], sq[CT];
#pragma unroll
  for (int c = 0; c < CT; c++) { sc[c] = 0.f; sq[c] = 0.f; }

  const int M = NTOT;
  int tiles = (M + ROWS - 1) / ROWS;
  for (int t = blockIdx.x; t < tiles; t += gridDim.x) {
    int r0 = t * ROWS;
    __syncthreads();
    for (int i = tid * 8; i < ROWS * K; i += 2048) {
      int r = i / K, c = i - r * K;
      int row = r0 + r;
      bfrag8 v = {0, 0, 0, 0, 0, 0, 0, 0};
      if (row < M) {
        int cb = c >> 5, cc = c & 31;
        const unsigned short* srcp;
        int set, srow;
        if (row < NLEFT) {
          if (cb == 1) { srcp = ri;  set = 1; srow = row; }
          else         { srcp = x32; set = 0; srow = row; }
        } else {
          int rr = row - NLEFT;
          if (cb <= 1)      { srcp = x32; set = 0; srow = row; }
          else if (cb == 2) { srcp = li;  set = 2; srow = rr; }
          else              { srcp = rli; set = 3; srow = rr; }
        }
        v = *reinterpret_cast<const bfrag8*>(srcp + (size_t)srow * 32 + cc);
        const float* mm_ = &m4[set * 32 + cc];
        const float* ss_ = &s4[set * 32 + cc];
#pragma unroll
        for (int j = 0; j < 8; j++) {
          float f = bf2f((unsigned short)v[j]);
          f = fmaxf((f - mm_[j]) * ss_[j], 0.f);
          v[j] = (short)f2bf(f);
        }
      }
      *reinterpret_cast<bfrag8*>(&xl[r * LDX + c]) = v;
    }
    __syncthreads();

    facc4 acc[RT][CT];
#pragma unroll
    for (int rt = 0; rt < RT; rt++)
#pragma unroll
      for (int ct = 0; ct < CT; ct++) acc[rt][ct] = (facc4){0.f, 0.f, 0.f, 0.f};

#pragma unroll
    for (int kt = 0; kt < K / 32; kt++) {
      bfrag8 a[RT], b[CT];
#pragma unroll
      for (int rt = 0; rt < RT; rt++)
        a[rt] = *reinterpret_cast<const bfrag8*>(&xl[(rowbase + rt * 16 + lr) * LDX + kt * 32 + lk]);
#pragma unroll
      for (int ct = 0; ct < CT; ct++)
        b[ct] = *reinterpret_cast<const bfrag8*>(&wl[(ct * 16 + lr) * LDX + kt * 32 + lk]);
#pragma unroll
      for (int rt = 0; rt < RT; rt++)
#pragma unroll
        for (int ct = 0; ct < CT; ct++)
          acc[rt][ct] = __builtin_amdgcn_mfma_f32_16x16x32_bf16(a[rt], b[ct], acc[rt][ct], 0, 0, 0);
    }

#pragma unroll
    for (int rt = 0; rt < RT; rt++) {
#pragma unroll
      for (int ct = 0; ct < CT; ct++) {
        int col = ct * 16 + lr;
        float bcol = bl[col];
#pragma unroll
        for (int j = 0; j < 4; j++) {
          int row = r0 + rowbase + rt * 16 + lj4 + j;
          if (row < M) {
            float v = acc[rt][ct][j] + bcol;
            Y[(size_t)row * N + col] = f2bf(v);
            sc[ct] += v; sq[ct] += v * v;
          }
        }
      }
    }
  }

  __syncthreads();
#pragma unroll
  for (int ct = 0; ct < CT; ct++) {
    atomicAdd(&ldsS[ct * 16 + lr], sc[ct]);
    atomicAdd(&ldsQ[ct * 16 + lr], sq[ct]);
  }
  __syncthreads();
  if (tid < N) {
    atomicAdd(&st_out[tid], ldsS[tid]);
    atomicAdd(&st_out[N + tid], ldsQ[tid]);
  }
}

// ---------------- final normalize + relu + residual add (+bf16 mirror refresh) ----------------

__global__ __launch_bounds__(256) void norm_add_kernel(const unsigned short* __restrict__ X, int M,
                                                       const float* __restrict__ st,
                                                       float* __restrict__ D,
                                                       unsigned short* __restrict__ Dbf) {
  __shared__ float mean[64], scal[64];
  if (threadIdx.x < 64) {
    float m = st[threadIdx.x] / (float)M;
    float v = st[64 + threadIdx.x] / (float)M - m * m;
    mean[threadIdx.x] = m;
    scal[threadIdx.x] = rsqrtf(fmaxf(v, 0.f) + BNEPS);
  }
  __syncthreads();
  size_t ngrp = (size_t)M * 64 / 8;
  for (size_t i = (size_t)blockIdx.x * 256 + threadIdx.x; i < ngrp;
       i += (size_t)gridDim.x * 256) {
    size_t base = i * 8;
    int c = (int)(base & 63);
    bfrag8 xv = *reinterpret_cast<const bfrag8*>(&X[base]);
    float4 d0 = *reinterpret_cast<float4*>(&D[base]);
    float4 d1 = *reinterpret_cast<float4*>(&D[base + 4]);
    float o[8];
#pragma unroll
    for (int j = 0; j < 8; j++) {
      float y = (bf2f((unsigned short)xv[j]) - mean[c + j]) * scal[c + j];
      y = y > 0.f ? y : 0.f;
      float dv = (j < 4) ? (&d0.x)[j] : (&d1.x)[j - 4];
      o[j] = dv + y;
    }
    d0 = make_float4(o[0], o[1], o[2], o[3]);
    d1 = make_float4(o[4], o[5], o[6], o[7]);
    *reinterpret_cast<float4*>(&D[base])     = d0;
    *reinterpret_cast<float4*>(&D[base + 4]) = d1;
    bfrag8 pb;
#pragma unroll
    for (int j = 0; j < 8; j++) pb[j] = (short)f2bf(o[j]);
    *reinterpret_cast<bfrag8*>(&Dbf[base]) = pb;
  }
}

// ---------------- orchestration ----------------

static inline int tiles_of(int M, int R) { return (M + R - 1) / R; }
static inline int imin(int a, int b) { return a < b ? a : b; }

extern "C" void kernel_launch(void* const* d_in, const int* in_sizes, int n_in,
                              void* d_out, int out_size, void* d_ws, size_t ws_size,
                              hipStream_t stream) {
  const float* xs      = (const float*)d_in[0];
  const float* nn1_w1  = (const float*)d_in[1];
  const float* nn1_b1  = (const float*)d_in[2];
  const float* nn1_w2  = (const float*)d_in[3];
  const float* nn1_b2  = (const float*)d_in[4];
  const float* nn2_w1  = (const float*)d_in[5];
  const float* nn2_b1  = (const float*)d_in[6];
  const float* nn2_w2  = (const float*)d_in[7];
  const float* nn2_b2  = (const float*)d_in[8];
  const float* l1_w    = (const float*)d_in[9];
  const float* l1_b    = (const float*)d_in[10];
  const float* l2_w    = (const float*)d_in[11];
  const float* l2_b    = (const float*)d_in[12];
  const float* l3_w    = (const float*)d_in[13];
  const float* l3_b    = (const float*)d_in[14];
  const float* l4_w    = (const float*)d_in[15];
  const float* l4_b    = (const float*)d_in[16];
  const float* out_w1  = (const float*)d_in[17];
  const float* out_b1  = (const float*)d_in[18];
  const float* out_w2  = (const float*)d_in[19];
  const float* out_b2  = (const float*)d_in[20];
  const int*   src     = (const int*)d_in[21];
  const int*   dst     = (const int*)d_in[22];

  float* out = (float*)d_out;

  unsigned short* u     = (unsigned short*)d_ws;
  unsigned short* t1    = u;                                   // 200000*64
  unsigned short* rin   = t1    + (size_t)NTOT * 64;           // 100000*64
  unsigned short* x32   = rin   + (size_t)NLEFT * 64;          // 200000*32
  unsigned short* ri32  = x32   + (size_t)NTOT * 32;           // 100000*32
  unsigned short* li32  = ri32  + (size_t)NLEFT * 32;
  unsigned short* rli32 = li32  + (size_t)NRIGHT * 32;
  unsigned short* outbf = rli32 + (size_t)NRIGHT * 32;         // 200000*64
  float* stats = (float*)(outbf + (size_t)NTOT * 64);          // 20*128
  int*   cntL  = (int*)(stats + 20 * 128);
  int*   cntR  = cntL + NLEFT;
  int*   oL    = cntR + NRIGHT;
  int*   oR    = oL + (NLEFT + 1);
  int*   curL  = oR + (NRIGHT + 1);
  int*   curR  = curL + NLEFT;
  int*   part  = curR + NRIGHT;
  int*   adjL  = part + 1024;
  int*   adjR  = adjL + NEDGE;
  unsigned short* wcvt = (unsigned short*)(adjR + NEDGE);      // 2*57344 ushorts

  dim3 B(256);
  const int NB1 = (NLEFT + 255) / 256;
  const float invL = 1.f / NLEFT, invT = 1.f / NTOT;
  const int tilesL = tiles_of(NLEFT, 32);   // 3125 segment tiles
  const int GD = imin(tilesL, 768);         // dual gmm: 3 blocks/CU resident
  const int GS = imin(tilesL, 1536);        // single gmm: 6 blocks/CU resident

  init_kernel<<<2048, B, 0, stream>>>(xs, out, outbf, stats, 20 * 128, cntL, cntR, curL, curR);
  wconv_kernel<<<448, B, 0, stream>>>(l2_w, nn2_w1, l4_w, l3_w, nn2_w2, nn1_w1, l1_w,
                                      nn1_w2, out_w1, out_w2, wcvt);
  count_kernel<<<2048, B, 0, stream>>>(src, dst, cntL, cntR);
  scan1_kernel<<<NB1, B, 0, stream>>>(cntL, NLEFT, part);
  scan2_kernel<<<1, 1024, 0, stream>>>(part, NB1);
  scan3_kernel<<<NB1, B, 0, stream>>>(cntL, NLEFT, part, oL);
  scan1_kernel<<<NB1, B, 0, stream>>>(cntR, NRIGHT, part);
  scan2_kernel<<<1, 1024, 0, stream>>>(part, NB1);
  scan3_kernel<<<NB1, B, 0, stream>>>(cntR, NRIGHT, part, oR);
  fill_kernel<<<2048, B, 0, stream>>>(src, dst, oL, oR, curL, curR, adjL, adjR);

  for (int l = 0; l < 2; l++) {
    const float* p_nn1_b1 = nn1_b1 + (size_t)l * 64;
    const float* p_nn1_b2 = nn1_b2 + (size_t)l * 64;
    const float* p_nn2_b1 = nn2_b1 + (size_t)l * 64;
    const float* p_nn2_b2 = nn2_b2 + (size_t)l * 64;
    const float* p_l1_b   = l1_b + (size_t)l * 32;
    const float* p_l2_b   = l2_b + (size_t)l * 32;
    const float* p_l3_b   = l3_b + (size_t)l * 32;
    const float* p_l4_b   = l4_b + (size_t)l * 32;
    const float* p_out_b1 = out_b1 + (size_t)l * 64;
    const float* p_out_b2 = out_b2 + (size_t)l * 64;
    const unsigned short* wc = wcvt + (size_t)l * WC_PER_L;

    float* S = stats + (size_t)l * 10 * 128;
    auto ST = [&](int s) { return S + (size_t)s * 128; };

    // a+b+c1) gather right_info; ri=l2->s0; rin=nn2_w1->s1 (fused dual, persistent)
    gmm_mfma<32, 64, false><<<GD, 512, 0, stream>>>(
        outbf + (size_t)NLEFT * 64, oL, adjL, NLEFT, nullptr, 0.f,
        wc + WC_G1, p_l2_b, ri32, ST(0), p_nn2_b1, rin, ST(1));
    // c2) rin = nn2_w2(bnrelu(rin,s1)); s2
    mm_mfma<64, 64, 128, true><<<tiles_of(NLEFT, 128), B, 0, stream>>>(
        rin, wc + WC_NN2W2, p_nn2_b2, rin, NLEFT, ST(2), ST(1), invL);
    // d+e) gather rl_info from bnrelu(rin,s2); rli=l4->s3
    gmm_mfma<32, 0, true><<<GS, 512, 0, stream>>>(
        rin, oR, adjR, NRIGHT, ST(2), invL,
        wc + WC_G2, p_l4_b, rli32, ST(3), nullptr, nullptr, nullptr);
    // f1+i) t1 = nn1_w1(outbf)->s4 ; x32 = l1(outbf)->s7 (dual output)
    mm2_mfma<<<tiles_of(NTOT, 128), B, 0, stream>>>(
        outbf, wc + WC_M2, p_nn1_b1, t1, ST(4), p_l1_b, x32, ST(7), NTOT);
    // f2) t1 = nn1_w2(bnrelu(t1,s4)); s5
    mm_mfma<64, 64, 128, true><<<tiles_of(NTOT, 128), B, 0, stream>>>(
        t1, wc + WC_NN1W2, p_nn1_b2, t1, NTOT, ST(5), ST(4), invT);
    // g+h) gather left_info from bnrelu(t1,s5); li=l3->s6
    gmm_mfma<32, 0, true><<<GS, 512, 0, stream>>>(
        t1, oR, adjR, NRIGHT, ST(5), invT,
        wc + WC_G3, p_l3_b, li32, ST(6), nullptr, nullptr, nullptr);
    // j1) t1 = out_w1(h virtual concat); s8
    mmh_mfma<<<tiles_of(NTOT, 128), B, 0, stream>>>(
        x32, ri32, li32, rli32, ST(7), ST(0), ST(6), ST(3),
        wc + WC_OUTW1, p_out_b1, t1, ST(8));
    // j2) t1 = out_w2(bnrelu(t1,s8)); s9
    mm_mfma<64, 64, 128, true><<<tiles_of(NTOT, 128), B, 0, stream>>>(
        t1, wc + WC_OUTW2, p_out_b2, t1, NTOT, ST(9), ST(8), invT);
    // j3) out += relu(bn(t1,s9)); refresh bf16 mirror
    norm_add_kernel<<<2048, B, 0, stream>>>(t1, NTOT, ST(9), out, outbf);
  }
}